// Round 1
// baseline (2695.033 us; speedup 1.0000x reference)
//
#include <hip/hip_runtime.h>
#include <hip/hip_bf16.h>
#include <math.h>

// Model dims
#define SEQ 2048
#define NBATCH 2
// DM=512, DI=1024, N=16, K=4, R=32, H=8, V=10000

typedef __attribute__((ext_vector_type(4))) float f32x4;
typedef __attribute__((ext_vector_type(8))) short bf16x8s;
typedef __attribute__((ext_vector_type(4))) short short4v;

__device__ __forceinline__ short f2bf(float f) {
  union { float f; unsigned u; } c; c.f = f;
  unsigned u = c.u;
  u += 0x7fffu + ((u >> 16) & 1u);   // RNE
  return (short)(u >> 16);
}

// ---------------- Generic MFMA bf16 GEMM:  C[M,N] = A[M,K] @ B[N,K]^T (+epilogue)
// EPI: 0 = none, 1 = +bias, 2 = +bias then softplus
#define BM 128
#define BN 128
#define BKK 32
#define LDT 40   // padded LDS row stride in bf16 elems (80B, 16B-aligned, <=2-way bank conflict)

template<int EPI>
__launch_bounds__(256)
__global__ void gemm_kernel(const float* __restrict__ A, const float* __restrict__ B,
                            float* __restrict__ C, const float* __restrict__ bias,
                            int M, int N, int K, int lda, int ldb, int ldc) {
  __shared__ short As[BM * LDT];
  __shared__ short Bs[BN * LDT];
  const int tid  = threadIdx.x;
  const int lane = tid & 63;
  const int wave = tid >> 6;
  const int m0 = blockIdx.y * BM;
  const int n0 = blockIdx.x * BN;
  const int wr = (wave >> 1) * 64;
  const int wc = (wave & 1) * 64;
  const int srow = tid >> 3;        // 0..31
  const int scol = (tid & 7) * 4;   // 0,4,...,28
  const int fr = lane & 15;
  const int fq = lane >> 4;

  f32x4 acc[4][4] = {};

  for (int k0 = 0; k0 < K; k0 += BKK) {
    const bool kok = (k0 + scol) < K;   // all K are %4==0, float4 all-or-nothing
    #pragma unroll
    for (int rr = 0; rr < BM; rr += 32) {
      int r = srow + rr;
      f32x4 v = {0.f, 0.f, 0.f, 0.f};
      if (kok) v = *(const f32x4*)(A + (size_t)(m0 + r) * lda + k0 + scol);
      short4v s = { f2bf(v[0]), f2bf(v[1]), f2bf(v[2]), f2bf(v[3]) };
      *(short4v*)(&As[r * LDT + scol]) = s;
    }
    #pragma unroll
    for (int rr = 0; rr < BN; rr += 32) {
      int r = srow + rr;
      f32x4 v = {0.f, 0.f, 0.f, 0.f};
      if (kok && (n0 + r) < N) v = *(const f32x4*)(B + (size_t)(n0 + r) * ldb + k0 + scol);
      short4v s = { f2bf(v[0]), f2bf(v[1]), f2bf(v[2]), f2bf(v[3]) };
      *(short4v*)(&Bs[r * LDT + scol]) = s;
    }
    __syncthreads();
    bf16x8s af[4], bfv[4];
    #pragma unroll
    for (int i = 0; i < 4; i++)
      af[i]  = *(const bf16x8s*)(&As[(wr + i * 16 + fr) * LDT + fq * 8]);
    #pragma unroll
    for (int i = 0; i < 4; i++)
      bfv[i] = *(const bf16x8s*)(&Bs[(wc + i * 16 + fr) * LDT + fq * 8]);
    #pragma unroll
    for (int i = 0; i < 4; i++)
      #pragma unroll
      for (int j = 0; j < 4; j++)
        acc[i][j] = __builtin_amdgcn_mfma_f32_16x16x32_bf16(af[i], bfv[j], acc[i][j], 0, 0, 0);
    __syncthreads();
  }

  #pragma unroll
  for (int j = 0; j < 4; j++) {
    int cn = n0 + wc + j * 16 + fr;
    if (cn < N) {
      float bv = 0.f;
      if (EPI >= 1) bv = bias[cn];
      #pragma unroll
      for (int i = 0; i < 4; i++) {
        #pragma unroll
        for (int r4 = 0; r4 < 4; r4++) {
          int cm = m0 + wr + i * 16 + fq * 4 + r4;
          float val = acc[i][j][r4] + bv;
          if (EPI == 2) val = fmaxf(val, 0.f) + log1pf(__expf(-fabsf(val)));
          C[(size_t)cm * ldc + cn] = val;
        }
      }
    }
  }
}

// ---------------- Tiny attention: per (n,h) a 2x2 score matrix over 64-dim heads.
__global__ void attn_kernel(const float* __restrict__ qkv, float* __restrict__ o) {
  int gw = blockIdx.x * 4 + (threadIdx.x >> 6);  // (n,h) id
  int lane = threadIdx.x & 63;
  int n = gw >> 3, h = gw & 7;
  size_t r0 = (size_t)n * 1536 + h * 64 + lane;
  size_t r1 = (size_t)(SEQ + n) * 1536 + h * 64 + lane;
  float q0 = qkv[r0], k0 = qkv[r0 + 512], v0 = qkv[r0 + 1024];
  float q1 = qkv[r1], k1 = qkv[r1 + 512], v1 = qkv[r1 + 1024];
  float s00 = q0 * k0, s01 = q0 * k1, s10 = q1 * k0, s11 = q1 * k1;
  #pragma unroll
  for (int off = 32; off > 0; off >>= 1) {
    s00 += __shfl_xor(s00, off);
    s01 += __shfl_xor(s01, off);
    s10 += __shfl_xor(s10, off);
    s11 += __shfl_xor(s11, off);
  }
  const float sc = 0.125f;  // 1/sqrt(64)
  s00 *= sc; s01 *= sc; s10 *= sc; s11 *= sc;
  float mx0 = fmaxf(s00, s01), mx1 = fmaxf(s10, s11);
  float e00 = __expf(s00 - mx0), e01 = __expf(s01 - mx0);
  float e10 = __expf(s10 - mx1), e11 = __expf(s11 - mx1);
  float i0 = 1.f / (e00 + e01), i1 = 1.f / (e10 + e11);
  size_t w0 = (size_t)n * 512 + h * 64 + lane;
  size_t w1 = (size_t)(SEQ + n) * 512 + h * 64 + lane;
  o[w0] = (e00 * v0 + e01 * v1) * i0;
  o[w1] = (e10 * v0 + e11 * v1) * i1;
}

// ---------------- LN(a+b) over last dim 512, one wave per row
__global__ void ln_res_kernel(const float* __restrict__ a, const float* __restrict__ b,
                              const float* __restrict__ g, const float* __restrict__ be,
                              float* __restrict__ out) {
  int row = blockIdx.x * 4 + (threadIdx.x >> 6);
  int lane = threadIdx.x & 63;
  const float* pa = a + (size_t)row * 512 + lane * 8;
  const float* pb = b + (size_t)row * 512 + lane * 8;
  f32x4 va0 = *(const f32x4*)pa, va1 = *(const f32x4*)(pa + 4);
  f32x4 vb0 = *(const f32x4*)pb, vb1 = *(const f32x4*)(pb + 4);
  float v[8];
  #pragma unroll
  for (int j = 0; j < 4; j++) { v[j] = va0[j] + vb0[j]; v[4 + j] = va1[j] + vb1[j]; }
  float s = 0.f, s2 = 0.f;
  #pragma unroll
  for (int j = 0; j < 8; j++) { s += v[j]; s2 += v[j] * v[j]; }
  #pragma unroll
  for (int off = 32; off > 0; off >>= 1) { s += __shfl_xor(s, off); s2 += __shfl_xor(s2, off); }
  float mu = s * (1.f / 512.f);
  float var = s2 * (1.f / 512.f) - mu * mu;
  float rs = rsqrtf(var + 1e-5f);
  float* po = out + (size_t)row * 512 + lane * 8;
  const float* pg = g + lane * 8;
  const float* pe = be + lane * 8;
  #pragma unroll
  for (int j = 0; j < 8; j++) po[j] = (v[j] - mu) * rs * pg[j] + pe[j];
}

// ---------------- depthwise causal conv (K=4) + silu.  xz: (B,S,2*DI), xa = cols [0,DI)
__global__ void conv_silu_kernel(const float* __restrict__ xz, const float* __restrict__ w,
                                 const float* __restrict__ cb, float* __restrict__ xc) {
  int idx = blockIdx.x * 256 + threadIdx.x;  // over B*S*DI
  int d = idx & 1023;
  int t = (idx >> 10) & (SEQ - 1);
  int b = idx >> 21;
  const float* base = xz + (size_t)(b * SEQ) * 2048 + d;
  float acc = cb[d];
  #pragma unroll
  for (int k = 0; k < 4; k++) {
    int tt = t - 3 + k;
    if (tt >= 0) acc += w[d * 4 + k] * base[(size_t)tt * 2048];
  }
  xc[idx] = acc / (1.f + __expf(-acc));
}

// ---------------- selective scan: 16 lanes per (b,d), one per state n
__global__ void scan_kernel(const float* __restrict__ dt, const float* __restrict__ xc,
                            const float* __restrict__ dbl, const float* __restrict__ A_log,
                            float* __restrict__ ys) {
  int tid = blockIdx.x * 256 + threadIdx.x;
  int n = tid & 15;
  int d = (tid >> 4) & 1023;
  int b = tid >> 14;
  float A = -__expf(A_log[d * 16 + n]);
  const float* dtp = dt + (size_t)b * SEQ * 1024 + d;
  const float* xcp = xc + (size_t)b * SEQ * 1024 + d;
  const float* dbp = dbl + (size_t)b * SEQ * 64;
  float* ysp = ys + (size_t)b * SEQ * 1024 + d;
  float h = 0.f;
  for (int t = 0; t < SEQ; t++) {
    float dtv = dtp[(size_t)t * 1024];
    float xv  = xcp[(size_t)t * 1024];
    float Bv  = dbp[t * 64 + 32 + n];
    float Cv  = dbp[t * 64 + 48 + n];
    h = __expf(dtv * A) * h + (dtv * xv) * Bv;
    float p = h * Cv;
    p += __shfl_xor(p, 1);
    p += __shfl_xor(p, 2);
    p += __shfl_xor(p, 4);
    p += __shfl_xor(p, 8);
    if (n == 0) ysp[(size_t)t * 1024] = p;
  }
}

// ---------------- y = (ys + xc*D) * silu(z),   z = xz[:, DI + d]
__global__ void gate_kernel(float* __restrict__ ys, const float* __restrict__ xc,
                            const float* __restrict__ Dp, const float* __restrict__ xz) {
  int idx = blockIdx.x * 256 + threadIdx.x;
  int d = idx & 1023;
  int bt = idx >> 10;
  float z = xz[(size_t)bt * 2048 + 1024 + d];
  float y = ys[idx] + xc[idx] * Dp[d];
  ys[idx] = y * (z / (1.f + __expf(-z)));
}

// ---------------- time flip for (B,S,W) f32, W = 1<<shift
__global__ void flip_kernel(const float* __restrict__ in, float* __restrict__ out, int shift) {
  int idx = blockIdx.x * 256 + threadIdx.x;
  int c = idx & ((1 << shift) - 1);
  int t = (idx >> shift) & (SEQ - 1);
  int b = idx >> (shift + 11);
  out[idx] = in[(((size_t)(b * SEQ + (SEQ - 1 - t))) << shift) + c];
}

extern "C" void kernel_launch(void* const* d_in, const int* in_sizes, int n_in,
                              void* d_out, int out_size, void* d_ws, size_t ws_size,
                              hipStream_t stream) {
  (void)in_sizes; (void)n_in; (void)out_size; (void)ws_size;
  const float* mel        = (const float*)d_in[0];
  const float* mel_w      = (const float*)d_in[1];
  const float* mel_b      = (const float*)d_in[2];
  const float* attn_in_w  = (const float*)d_in[3];
  const float* attn_in_b  = (const float*)d_in[4];
  const float* attn_out_w = (const float*)d_in[5];
  const float* attn_out_b = (const float*)d_in[6];
  const float* ln1_g = (const float*)d_in[7];
  const float* ln1_b = (const float*)d_in[8];
  const float* ln2_g = (const float*)d_in[9];
  const float* ln2_b = (const float*)d_in[10];
  const float* bim_w = (const float*)d_in[29];
  const float* bim_b = (const float*)d_in[30];
  const float* out_w = (const float*)d_in[31];
  const float* out_b = (const float*)d_in[32];

  float* ws = (float*)d_ws;
  float* ob = (float*)d_out;
  // ws layout (floats)
  float* x0     = ws;                 // 2M
  float* x1     = ws + 2097152;       // 2M
  float* x1f    = ws + 4194304;       // 2M
  float* attn_o = ws + 6291456;       // 2M
  float* xc     = ws + 8388608;       // 4M
  float* dtb    = ws + 12582912;      // 4M (reused as flipped-y for bwd)
  float* ysb    = ws + 16777216;      // 4M
  float* dbl    = ws + 20971520;      // 256K
  float* mout   = ws + 21233664;      // 4M (concat fwd|bwd)
  float* minter = ws + 25427968;      // 2M
  float* x2     = ws + 27525120;      // 2M
  // d_out scratch (dead until final GEMM overwrites everything)
  float* qkv = ob;             // 6.29M floats
  float* xz  = ob + 8388608;   // 8.39M floats

  dim3 blk(256);

  // 1. x0 = mel @ mel_w.T + mel_b          (M=4096,N=512,K=80)
  gemm_kernel<1><<<dim3(4, 32), blk, 0, stream>>>(mel, mel_w, x0, mel_b, 4096, 512, 80, 80, 80, 512);
  // 2. qkv = x0 @ attn_in_w.T + b          (N=1536,K=512)
  gemm_kernel<1><<<dim3(12, 32), blk, 0, stream>>>(x0, attn_in_w, qkv, attn_in_b, 4096, 1536, 512, 512, 512, 1536);
  // 3. attention (L=2)
  attn_kernel<<<4096, blk, 0, stream>>>(qkv, attn_o);
  // 4. attn proj -> qkv slot (dead)        (N=512,K=512)
  gemm_kernel<1><<<dim3(4, 32), blk, 0, stream>>>(attn_o, attn_out_w, qkv, attn_out_b, 4096, 512, 512, 512, 512, 512);
  // 5. x1 = LN(x0 + attnproj)
  ln_res_kernel<<<1024, blk, 0, stream>>>(x0, qkv, ln1_g, ln1_b, x1);
  // 6. x1f = time-flip(x1)
  flip_kernel<<<8192, blk, 0, stream>>>(x1, x1f, 9);

  for (int dir = 0; dir < 2; dir++) {
    int base = 11 + dir * 9;
    const float* in_w    = (const float*)d_in[base + 0];
    const float* conv_w  = (const float*)d_in[base + 1];
    const float* conv_b  = (const float*)d_in[base + 2];
    const float* x_w     = (const float*)d_in[base + 3];
    const float* dt_w    = (const float*)d_in[base + 4];
    const float* dt_bias = (const float*)d_in[base + 5];
    const float* A_log   = (const float*)d_in[base + 6];
    const float* Dp      = (const float*)d_in[base + 7];
    const float* o_w     = (const float*)d_in[base + 8];
    const float* xin = dir ? x1f : x1;
    // xz = xin @ in_w.T                    (N=2048,K=512)
    gemm_kernel<0><<<dim3(16, 32), blk, 0, stream>>>(xin, in_w, xz, nullptr, 4096, 2048, 512, 512, 512, 2048);
    // conv + silu
    conv_silu_kernel<<<16384, blk, 0, stream>>>(xz, conv_w, conv_b, xc);
    // dbl = xc @ x_w.T                     (N=64,K=1024)
    gemm_kernel<0><<<dim3(1, 32), blk, 0, stream>>>(xc, x_w, dbl, nullptr, 4096, 64, 1024, 1024, 1024, 64);
    // dt = softplus(dbl[:, :32] @ dt_w.T + dt_b)   (N=1024,K=32, lda=64)
    gemm_kernel<2><<<dim3(8, 32), blk, 0, stream>>>(dbl, dt_w, dtb, dt_bias, 4096, 1024, 32, 64, 32, 1024);
    // selective scan
    scan_kernel<<<128, blk, 0, stream>>>(dtb, xc, dbl, A_log, ysb);
    // gate: ys = (ys + xc*D) * silu(z)
    gate_kernel<<<16384, blk, 0, stream>>>(ysb, xc, Dp, xz);
    const float* yin = ysb;
    if (dir) { flip_kernel<<<16384, blk, 0, stream>>>(ysb, dtb, 10); yin = dtb; }
    // mamba out proj -> mout columns [dir*512, dir*512+512)   (N=512,K=1024, ldc=1024)
    gemm_kernel<0><<<dim3(4, 32), blk, 0, stream>>>(yin, o_w, mout + dir * 512, nullptr, 4096, 512, 1024, 1024, 1024, 1024);
  }

  // m = mout @ bim_w.T + bim_b             (N=512,K=1024)
  gemm_kernel<1><<<dim3(4, 32), blk, 0, stream>>>(mout, bim_w, minter, bim_b, 4096, 512, 1024, 1024, 1024, 512);
  // x2 = LN(x1 + m)
  ln_res_kernel<<<1024, blk, 0, stream>>>(x1, minter, ln2_g, ln2_b, x2);
  // logits = x2 @ out_w.T + out_b          (N=10000,K=512) -> overwrites all of d_out
  gemm_kernel<1><<<dim3(79, 32), blk, 0, stream>>>(x2, out_w, ob, out_b, 4096, 10000, 512, 512, 512, 10000);
}

// Round 2
// 1393.835 us; speedup vs baseline: 1.9335x; 1.9335x over previous
//
#include <hip/hip_runtime.h>
#include <hip/hip_bf16.h>
#include <math.h>

// Model dims
#define SEQ 2048
#define NBATCH 2
// DM=512, DI=1024, N=16, K=4, R=32, H=8, V=10000

typedef __attribute__((ext_vector_type(4))) float f32x4;
typedef __attribute__((ext_vector_type(8))) short bf16x8s;
typedef __attribute__((ext_vector_type(4))) short short4v;

__device__ __forceinline__ short f2bf(float f) {
  union { float f; unsigned u; } c; c.f = f;
  unsigned u = c.u;
  u += 0x7fffu + ((u >> 16) & 1u);   // RNE
  return (short)(u >> 16);
}

// ---------------- Generic MFMA bf16 GEMM:  C[M,N] = A[M,K] @ B[N,K]^T (+epilogue)
// EPI: 0 = none, 1 = +bias, 2 = +bias then softplus
#define BM 128
#define BN 128
#define BKK 32
#define LDT 40   // padded LDS row stride in bf16 elems

template<int EPI>
__launch_bounds__(256)
__global__ void gemm_kernel(const float* __restrict__ A, const float* __restrict__ B,
                            float* __restrict__ C, const float* __restrict__ bias,
                            int M, int N, int K, int lda, int ldb, int ldc) {
  __shared__ short As[BM * LDT];
  __shared__ short Bs[BN * LDT];
  const int tid  = threadIdx.x;
  const int lane = tid & 63;
  const int wave = tid >> 6;
  const int m0 = blockIdx.y * BM;
  const int n0 = blockIdx.x * BN;
  const int wr = (wave >> 1) * 64;
  const int wc = (wave & 1) * 64;
  const int srow = tid >> 3;        // 0..31
  const int scol = (tid & 7) * 4;   // 0,4,...,28
  const int fr = lane & 15;
  const int fq = lane >> 4;

  f32x4 acc[4][4] = {};

  for (int k0 = 0; k0 < K; k0 += BKK) {
    const bool kok = (k0 + scol) < K;   // all K are %4==0, float4 all-or-nothing
    #pragma unroll
    for (int rr = 0; rr < BM; rr += 32) {
      int r = srow + rr;
      f32x4 v = {0.f, 0.f, 0.f, 0.f};
      if (kok) v = *(const f32x4*)(A + (size_t)(m0 + r) * lda + k0 + scol);
      short4v s = { f2bf(v[0]), f2bf(v[1]), f2bf(v[2]), f2bf(v[3]) };
      *(short4v*)(&As[r * LDT + scol]) = s;
    }
    #pragma unroll
    for (int rr = 0; rr < BN; rr += 32) {
      int r = srow + rr;
      f32x4 v = {0.f, 0.f, 0.f, 0.f};
      if (kok && (n0 + r) < N) v = *(const f32x4*)(B + (size_t)(n0 + r) * ldb + k0 + scol);
      short4v s = { f2bf(v[0]), f2bf(v[1]), f2bf(v[2]), f2bf(v[3]) };
      *(short4v*)(&Bs[r * LDT + scol]) = s;
    }
    __syncthreads();
    bf16x8s af[4], bfv[4];
    #pragma unroll
    for (int i = 0; i < 4; i++)
      af[i]  = *(const bf16x8s*)(&As[(wr + i * 16 + fr) * LDT + fq * 8]);
    #pragma unroll
    for (int i = 0; i < 4; i++)
      bfv[i] = *(const bf16x8s*)(&Bs[(wc + i * 16 + fr) * LDT + fq * 8]);
    #pragma unroll
    for (int i = 0; i < 4; i++)
      #pragma unroll
      for (int j = 0; j < 4; j++)
        acc[i][j] = __builtin_amdgcn_mfma_f32_16x16x32_bf16(af[i], bfv[j], acc[i][j], 0, 0, 0);
    __syncthreads();
  }

  #pragma unroll
  for (int j = 0; j < 4; j++) {
    int cn = n0 + wc + j * 16 + fr;
    if (cn < N) {
      float bv = 0.f;
      if (EPI >= 1) bv = bias[cn];
      #pragma unroll
      for (int i = 0; i < 4; i++) {
        #pragma unroll
        for (int r4 = 0; r4 < 4; r4++) {
          int cm = m0 + wr + i * 16 + fq * 4 + r4;
          float val = acc[i][j][r4] + bv;
          if (EPI == 2) val = fmaxf(val, 0.f) + log1pf(__expf(-fabsf(val)));
          C[(size_t)cm * ldc + cn] = val;
        }
      }
    }
  }
}

// ---------------- Tiny attention: per (n,h) a 2x2 score matrix over 64-dim heads.
__global__ void attn_kernel(const float* __restrict__ qkv, float* __restrict__ o) {
  int gw = blockIdx.x * 4 + (threadIdx.x >> 6);  // (n,h) id
  int lane = threadIdx.x & 63;
  int n = gw >> 3, h = gw & 7;
  size_t r0 = (size_t)n * 1536 + h * 64 + lane;
  size_t r1 = (size_t)(SEQ + n) * 1536 + h * 64 + lane;
  float q0 = qkv[r0], k0 = qkv[r0 + 512], v0 = qkv[r0 + 1024];
  float q1 = qkv[r1], k1 = qkv[r1 + 512], v1 = qkv[r1 + 1024];
  float s00 = q0 * k0, s01 = q0 * k1, s10 = q1 * k0, s11 = q1 * k1;
  #pragma unroll
  for (int off = 32; off > 0; off >>= 1) {
    s00 += __shfl_xor(s00, off);
    s01 += __shfl_xor(s01, off);
    s10 += __shfl_xor(s10, off);
    s11 += __shfl_xor(s11, off);
  }
  const float sc = 0.125f;  // 1/sqrt(64)
  s00 *= sc; s01 *= sc; s10 *= sc; s11 *= sc;
  float mx0 = fmaxf(s00, s01), mx1 = fmaxf(s10, s11);
  float e00 = __expf(s00 - mx0), e01 = __expf(s01 - mx0);
  float e10 = __expf(s10 - mx1), e11 = __expf(s11 - mx1);
  float i0 = 1.f / (e00 + e01), i1 = 1.f / (e10 + e11);
  size_t w0 = (size_t)n * 512 + h * 64 + lane;
  size_t w1 = (size_t)(SEQ + n) * 512 + h * 64 + lane;
  o[w0] = (e00 * v0 + e01 * v1) * i0;
  o[w1] = (e10 * v0 + e11 * v1) * i1;
}

// ---------------- LN(a+b) over last dim 512, one wave per row
__global__ void ln_res_kernel(const float* __restrict__ a, const float* __restrict__ b,
                              const float* __restrict__ g, const float* __restrict__ be,
                              float* __restrict__ out) {
  int row = blockIdx.x * 4 + (threadIdx.x >> 6);
  int lane = threadIdx.x & 63;
  const float* pa = a + (size_t)row * 512 + lane * 8;
  const float* pb = b + (size_t)row * 512 + lane * 8;
  f32x4 va0 = *(const f32x4*)pa, va1 = *(const f32x4*)(pa + 4);
  f32x4 vb0 = *(const f32x4*)pb, vb1 = *(const f32x4*)(pb + 4);
  float v[8];
  #pragma unroll
  for (int j = 0; j < 4; j++) { v[j] = va0[j] + vb0[j]; v[4 + j] = va1[j] + vb1[j]; }
  float s = 0.f, s2 = 0.f;
  #pragma unroll
  for (int j = 0; j < 8; j++) { s += v[j]; s2 += v[j] * v[j]; }
  #pragma unroll
  for (int off = 32; off > 0; off >>= 1) { s += __shfl_xor(s, off); s2 += __shfl_xor(s2, off); }
  float mu = s * (1.f / 512.f);
  float var = s2 * (1.f / 512.f) - mu * mu;
  float rs = rsqrtf(var + 1e-5f);
  float* po = out + (size_t)row * 512 + lane * 8;
  const float* pg = g + lane * 8;
  const float* pe = be + lane * 8;
  #pragma unroll
  for (int j = 0; j < 8; j++) po[j] = (v[j] - mu) * rs * pg[j] + pe[j];
}

// ---------------- depthwise causal conv (K=4) + silu.  xz: (B,S,2*DI), xa = cols [0,DI)
__global__ void conv_silu_kernel(const float* __restrict__ xz, const float* __restrict__ w,
                                 const float* __restrict__ cb, float* __restrict__ xc) {
  int idx = blockIdx.x * 256 + threadIdx.x;  // over B*S*DI
  int d = idx & 1023;
  int t = (idx >> 10) & (SEQ - 1);
  int b = idx >> 21;
  const float* base = xz + (size_t)(b * SEQ) * 2048 + d;
  float acc = cb[d];
  #pragma unroll
  for (int k = 0; k < 4; k++) {
    int tt = t - 3 + k;
    if (tt >= 0) acc += w[d * 4 + k] * base[(size_t)tt * 2048];
  }
  xc[idx] = acc / (1.f + __expf(-acc));
}

// ---------------- chunked selective scan ----------------
// h_t = exp(dt_t*A) * h_{t-1} + dt_t*x_t*B_t ; y_t = <h_t, C_t>
// Split S into NC chunks of CL. p1: per-(b,chunk,d) local scan from h=0 ->
// hend[16], aprod[16]. p2: serial combine over chunks -> chunk-entry h0.
// p3: recompute within chunk from h0, emit y.
#define CL 16
#define NC 128

__global__ void scan_p1(const float* __restrict__ dt, const float* __restrict__ xc,
                        const float* __restrict__ dbl, const float* __restrict__ A_log,
                        float* __restrict__ hend, float* __restrict__ aprod) {
  int tid = blockIdx.x * 256 + threadIdx.x;   // over B*NC*DI = 262144
  int d = tid & 1023;
  int c = (tid >> 10) & (NC - 1);
  int b = tid >> 17;
  float A[16];
  #pragma unroll
  for (int q = 0; q < 4; q++) {
    f32x4 v = *(const f32x4*)(A_log + d * 16 + q * 4);
    #pragma unroll
    for (int j = 0; j < 4; j++) A[q * 4 + j] = -__expf(v[j]);
  }
  float h[16] = {0.f, 0.f, 0.f, 0.f, 0.f, 0.f, 0.f, 0.f,
                 0.f, 0.f, 0.f, 0.f, 0.f, 0.f, 0.f, 0.f};
  float ap[16];
  #pragma unroll
  for (int n = 0; n < 16; n++) ap[n] = 1.f;
  const float* dtp = dt + ((size_t)b * SEQ) * 1024 + d;
  const float* xcp = xc + ((size_t)b * SEQ) * 1024 + d;
  const float* dbp = dbl + ((size_t)b * SEQ) * 64;
  const int t0 = c * CL;
  for (int t = t0; t < t0 + CL; t++) {
    float dtv = dtp[(size_t)t * 1024];
    float dx = dtv * xcp[(size_t)t * 1024];
    float Bv[16];
    #pragma unroll
    for (int q = 0; q < 4; q++) {
      f32x4 v = *(const f32x4*)(dbp + (size_t)t * 64 + 32 + q * 4);
      #pragma unroll
      for (int j = 0; j < 4; j++) Bv[q * 4 + j] = v[j];
    }
    #pragma unroll
    for (int n = 0; n < 16; n++) {
      float e = __expf(dtv * A[n]);
      h[n] = e * h[n] + dx * Bv[n];
      ap[n] *= e;
    }
  }
  size_t o = ((size_t)((b * NC + c) * 1024 + d)) * 16;
  #pragma unroll
  for (int q = 0; q < 4; q++) {
    f32x4 vh = { h[q * 4], h[q * 4 + 1], h[q * 4 + 2], h[q * 4 + 3] };
    f32x4 va = { ap[q * 4], ap[q * 4 + 1], ap[q * 4 + 2], ap[q * 4 + 3] };
    *(f32x4*)(hend + o + q * 4) = vh;
    *(f32x4*)(aprod + o + q * 4) = va;
  }
}

__global__ void scan_p2(const float* __restrict__ hend, const float* __restrict__ aprod,
                        float* __restrict__ h0) {
  int tid = blockIdx.x * 256 + threadIdx.x;   // over B*DI*N = 32768
  int n = tid & 15;
  int d = (tid >> 4) & 1023;
  int b = tid >> 14;
  float h = 0.f;
  for (int c = 0; c < NC; c++) {
    size_t idx = ((size_t)((b * NC + c) * 1024 + d)) * 16 + n;
    h0[idx] = h;
    h = aprod[idx] * h + hend[idx];
  }
}

__global__ void scan_p3(const float* __restrict__ dt, const float* __restrict__ xc,
                        const float* __restrict__ dbl, const float* __restrict__ A_log,
                        const float* __restrict__ h0, float* __restrict__ ys) {
  int tid = blockIdx.x * 256 + threadIdx.x;   // over B*NC*DI = 262144
  int d = tid & 1023;
  int c = (tid >> 10) & (NC - 1);
  int b = tid >> 17;
  float A[16];
  #pragma unroll
  for (int q = 0; q < 4; q++) {
    f32x4 v = *(const f32x4*)(A_log + d * 16 + q * 4);
    #pragma unroll
    for (int j = 0; j < 4; j++) A[q * 4 + j] = -__expf(v[j]);
  }
  float h[16];
  size_t o = ((size_t)((b * NC + c) * 1024 + d)) * 16;
  #pragma unroll
  for (int q = 0; q < 4; q++) {
    f32x4 v = *(const f32x4*)(h0 + o + q * 4);
    #pragma unroll
    for (int j = 0; j < 4; j++) h[q * 4 + j] = v[j];
  }
  const float* dtp = dt + ((size_t)b * SEQ) * 1024 + d;
  const float* xcp = xc + ((size_t)b * SEQ) * 1024 + d;
  const float* dbp = dbl + ((size_t)b * SEQ) * 64;
  float* ysp = ys + ((size_t)b * SEQ) * 1024 + d;
  const int t0 = c * CL;
  for (int t = t0; t < t0 + CL; t++) {
    float dtv = dtp[(size_t)t * 1024];
    float dx = dtv * xcp[(size_t)t * 1024];
    float Bv[16], Cv[16];
    #pragma unroll
    for (int q = 0; q < 4; q++) {
      f32x4 v = *(const f32x4*)(dbp + (size_t)t * 64 + 32 + q * 4);
      f32x4 w = *(const f32x4*)(dbp + (size_t)t * 64 + 48 + q * 4);
      #pragma unroll
      for (int j = 0; j < 4; j++) { Bv[q * 4 + j] = v[j]; Cv[q * 4 + j] = w[j]; }
    }
    float y = 0.f;
    #pragma unroll
    for (int n = 0; n < 16; n++) {
      float e = __expf(dtv * A[n]);
      h[n] = e * h[n] + dx * Bv[n];
      y += h[n] * Cv[n];
    }
    ysp[(size_t)t * 1024] = y;
  }
}

// ---------------- y = (ys + xc*D) * silu(z),   z = xz[:, DI + d]
__global__ void gate_kernel(float* __restrict__ ys, const float* __restrict__ xc,
                            const float* __restrict__ Dp, const float* __restrict__ xz) {
  int idx = blockIdx.x * 256 + threadIdx.x;
  int d = idx & 1023;
  int bt = idx >> 10;
  float z = xz[(size_t)bt * 2048 + 1024 + d];
  float y = ys[idx] + xc[idx] * Dp[d];
  ys[idx] = y * (z / (1.f + __expf(-z)));
}

// ---------------- time flip for (B,S,W) f32, W = 1<<shift
__global__ void flip_kernel(const float* __restrict__ in, float* __restrict__ out, int shift) {
  int idx = blockIdx.x * 256 + threadIdx.x;
  int c = idx & ((1 << shift) - 1);
  int t = (idx >> shift) & (SEQ - 1);
  int b = idx >> (shift + 11);
  out[idx] = in[(((size_t)(b * SEQ + (SEQ - 1 - t))) << shift) + c];
}

extern "C" void kernel_launch(void* const* d_in, const int* in_sizes, int n_in,
                              void* d_out, int out_size, void* d_ws, size_t ws_size,
                              hipStream_t stream) {
  (void)in_sizes; (void)n_in; (void)out_size; (void)ws_size;
  const float* mel        = (const float*)d_in[0];
  const float* mel_w      = (const float*)d_in[1];
  const float* mel_b      = (const float*)d_in[2];
  const float* attn_in_w  = (const float*)d_in[3];
  const float* attn_in_b  = (const float*)d_in[4];
  const float* attn_out_w = (const float*)d_in[5];
  const float* attn_out_b = (const float*)d_in[6];
  const float* ln1_g = (const float*)d_in[7];
  const float* ln1_b = (const float*)d_in[8];
  const float* ln2_g = (const float*)d_in[9];
  const float* ln2_b = (const float*)d_in[10];
  const float* bim_w = (const float*)d_in[29];
  const float* bim_b = (const float*)d_in[30];
  const float* out_w = (const float*)d_in[31];
  const float* out_b = (const float*)d_in[32];

  float* ws = (float*)d_ws;
  float* ob = (float*)d_out;
  // ws layout (floats)
  float* x0     = ws;                 // 2M
  float* x1     = ws + 2097152;       // 2M
  float* x1f    = ws + 4194304;       // 2M
  float* attn_o = ws + 6291456;       // 2M
  float* xc     = ws + 8388608;       // 4M
  float* dtb    = ws + 12582912;      // 4M (reused as flipped-y for bwd)
  float* ysb    = ws + 16777216;      // 4M
  float* dbl    = ws + 20971520;      // 256K
  float* mout   = ws + 21233664;      // 4M (concat fwd|bwd)
  float* minter = ws + 25427968;      // 2M
  float* x2     = ws + 27525120;      // 2M
  // d_out scratch (dead until final GEMM overwrites everything; out_size = 40.96M floats)
  float* qkv  = ob;              // 6.29M floats
  float* xz   = ob + 8388608;    // 8.39M floats (alive per-direction)
  float* hend = ob + 16777216;   // 4M floats scan scratch
  float* apr  = ob + 20971520;   // 4M floats
  float* h0s  = ob + 25165824;   // 4M floats

  dim3 blk(256);

  // 1. x0 = mel @ mel_w.T + mel_b          (M=4096,N=512,K=80)
  gemm_kernel<1><<<dim3(4, 32), blk, 0, stream>>>(mel, mel_w, x0, mel_b, 4096, 512, 80, 80, 80, 512);
  // 2. qkv = x0 @ attn_in_w.T + b          (N=1536,K=512)
  gemm_kernel<1><<<dim3(12, 32), blk, 0, stream>>>(x0, attn_in_w, qkv, attn_in_b, 4096, 1536, 512, 512, 512, 1536);
  // 3. attention (L=2)
  attn_kernel<<<4096, blk, 0, stream>>>(qkv, attn_o);
  // 4. attn proj -> qkv slot (dead)        (N=512,K=512)
  gemm_kernel<1><<<dim3(4, 32), blk, 0, stream>>>(attn_o, attn_out_w, qkv, attn_out_b, 4096, 512, 512, 512, 512, 512);
  // 5. x1 = LN(x0 + attnproj)
  ln_res_kernel<<<1024, blk, 0, stream>>>(x0, qkv, ln1_g, ln1_b, x1);
  // 6. x1f = time-flip(x1)
  flip_kernel<<<8192, blk, 0, stream>>>(x1, x1f, 9);

  for (int dir = 0; dir < 2; dir++) {
    int base = 11 + dir * 9;
    const float* in_w    = (const float*)d_in[base + 0];
    const float* conv_w  = (const float*)d_in[base + 1];
    const float* conv_b  = (const float*)d_in[base + 2];
    const float* x_w     = (const float*)d_in[base + 3];
    const float* dt_w    = (const float*)d_in[base + 4];
    const float* dt_bias = (const float*)d_in[base + 5];
    const float* A_log   = (const float*)d_in[base + 6];
    const float* Dp      = (const float*)d_in[base + 7];
    const float* o_w     = (const float*)d_in[base + 8];
    const float* xin = dir ? x1f : x1;
    // xz = xin @ in_w.T                    (N=2048,K=512)
    gemm_kernel<0><<<dim3(16, 32), blk, 0, stream>>>(xin, in_w, xz, nullptr, 4096, 2048, 512, 512, 512, 2048);
    // conv + silu
    conv_silu_kernel<<<16384, blk, 0, stream>>>(xz, conv_w, conv_b, xc);
    // dbl = xc @ x_w.T                     (N=64,K=1024)
    gemm_kernel<0><<<dim3(1, 32), blk, 0, stream>>>(xc, x_w, dbl, nullptr, 4096, 64, 1024, 1024, 1024, 64);
    // dt = softplus(dbl[:, :32] @ dt_w.T + dt_b)   (N=1024,K=32, lda=64)
    gemm_kernel<2><<<dim3(8, 32), blk, 0, stream>>>(dbl, dt_w, dtb, dt_bias, 4096, 1024, 32, 64, 32, 1024);
    // selective scan (chunked, 3 passes)
    scan_p1<<<1024, blk, 0, stream>>>(dtb, xc, dbl, A_log, hend, apr);
    scan_p2<<<128, blk, 0, stream>>>(hend, apr, h0s);
    scan_p3<<<1024, blk, 0, stream>>>(dtb, xc, dbl, A_log, h0s, ysb);
    // gate: ys = (ys + xc*D) * silu(z)
    gate_kernel<<<16384, blk, 0, stream>>>(ysb, xc, Dp, xz);
    const float* yin = ysb;
    if (dir) { flip_kernel<<<16384, blk, 0, stream>>>(ysb, dtb, 10); yin = dtb; }
    // mamba out proj -> mout columns [dir*512, dir*512+512)   (N=512,K=1024, ldc=1024)
    gemm_kernel<0><<<dim3(4, 32), blk, 0, stream>>>(yin, o_w, mout + dir * 512, nullptr, 4096, 512, 1024, 1024, 1024, 1024);
  }

  // m = mout @ bim_w.T + bim_b             (N=512,K=1024)
  gemm_kernel<1><<<dim3(4, 32), blk, 0, stream>>>(mout, bim_w, minter, bim_b, 4096, 512, 1024, 1024, 1024, 512);
  // x2 = LN(x1 + m)
  ln_res_kernel<<<1024, blk, 0, stream>>>(x1, minter, ln2_g, ln2_b, x2);
  // logits = x2 @ out_w.T + out_b          (N=10000,K=512) -> overwrites all of d_out
  gemm_kernel<1><<<dim3(79, 32), blk, 0, stream>>>(x2, out_w, ob, out_b, 4096, 10000, 512, 512, 512, 10000);
}

// Round 3
// 864.734 us; speedup vs baseline: 3.1166x; 1.6119x over previous
//
#include <hip/hip_runtime.h>
#include <hip/hip_bf16.h>
#include <math.h>

// Model dims
#define SEQ 2048
// B=2, DM=512, DI=1024, N=16, K=4, R=32, H=8, V=10000

typedef __attribute__((ext_vector_type(4))) float f32x4;
typedef __attribute__((ext_vector_type(8))) short bf16x8s;
typedef __attribute__((ext_vector_type(4))) short short4v;
typedef __attribute__((ext_vector_type(8))) unsigned short ushort8;

__device__ __forceinline__ short f2bf(float f) {
  union { float f; unsigned u; } c; c.f = f;
  unsigned u = c.u;
  u += 0x7fffu + ((u >> 16) & 1u);   // RNE
  return (short)(u >> 16);
}
__device__ __forceinline__ float bf2f(unsigned short u) {
  union { unsigned u; float f; } c; c.u = ((unsigned)u) << 16; return c.f;
}

__device__ __forceinline__ void lds_load16(const void* g, void* s) {
  __builtin_amdgcn_global_load_lds(
      (const __attribute__((address_space(1))) void*)g,
      (__attribute__((address_space(3))) void*)s, 16, 0, 0);
}

// =================== bf16 MFMA GEMM: C[M,N] = A[M,K] @ B[N,K]^T ===================
// A,B bf16 (K%64==0, lda/ldb %8==0); EPI: 0 none, 1 +bias, 2 +bias+softplus.
// OUTBF: 1 -> ushort bf16 C, 0 -> float C.
// global_load_lds staging with XOR column-chunk swizzle (pre-swizzled source,
// linear LDS write, swizzled ds_read) -> conflict-free ds_read_b128.
// 1D grid with bijective XCD-chunked swizzle, m-fastest within chunk.
template<int EPI, int OUTBF>
__launch_bounds__(256)
__global__ void gemm_bf16(const unsigned short* __restrict__ A, const unsigned short* __restrict__ B,
                          void* __restrict__ Cv, const float* __restrict__ bias,
                          int M, int N, int K, int lda, int ldb, int ldc, int nby) {
  __shared__ unsigned short As[128 * 64];
  __shared__ unsigned short Bs[128 * 64];
  // bijective XCD chunk swizzle (m204)
  const int nwg = gridDim.x;
  const int g = blockIdx.x;
  const int q = nwg >> 3, r = nwg & 7;
  const int xcd = g & 7, idx = g >> 3;
  const int wg = (xcd < r ? xcd * (q + 1) : r * (q + 1) + (xcd - r) * q) + idx;
  const int bn = wg / nby, bm = wg % nby;
  const int m0 = bm * 128, n0 = bn * 128;

  const int tid = threadIdx.x, lane = tid & 63, wave = tid >> 6;
  const int wr = (wave >> 1) * 64, wc = (wave & 1) * 64;
  const int fr = lane & 15, fq = lane >> 4;
  const int srow = tid >> 3;   // 0..31 (LDS row within issue group)
  const int scc  = tid & 7;    // column chunk 0..7 (8 bf16 each)

  f32x4 acc[4][4] = {};

  for (int k0 = 0; k0 < K; k0 += 64) {
    // stage A (4 issues x 256 lanes x 16B = 16KB) and B, pre-swizzled source cols
    #pragma unroll
    for (int j = 0; j < 4; j++) {
      int lrow = j * 32 + srow;
      int gcol = (scc ^ (lrow & 7)) * 8;
      lds_load16(A + (size_t)(m0 + lrow) * lda + k0 + gcol, &As[(j * 256 + wave * 64) * 8]);
    }
    #pragma unroll
    for (int j = 0; j < 4; j++) {
      int lrow = j * 32 + srow;
      int gcol = (scc ^ (lrow & 7)) * 8;
      int grow = n0 + lrow; if (grow >= N) grow = N - 1;   // clamp (junk cols never stored)
      lds_load16(B + (size_t)grow * ldb + k0 + gcol, &Bs[(j * 256 + wave * 64) * 8]);
    }
    __syncthreads();   // drains vmcnt(0) then barrier

    #pragma unroll
    for (int ks = 0; ks < 2; ks++) {
      bf16x8s af[4], bfv[4];
      #pragma unroll
      for (int i = 0; i < 4; i++) {
        int ra = wr + i * 16 + fr;
        af[i] = *(const bf16x8s*)&As[ra * 64 + (((ks << 2) + fq) ^ (ra & 7)) * 8];
      }
      #pragma unroll
      for (int i = 0; i < 4; i++) {
        int rb = wc + i * 16 + fr;
        bfv[i] = *(const bf16x8s*)&Bs[rb * 64 + (((ks << 2) + fq) ^ (rb & 7)) * 8];
      }
      #pragma unroll
      for (int i = 0; i < 4; i++)
        #pragma unroll
        for (int j = 0; j < 4; j++)
          acc[i][j] = __builtin_amdgcn_mfma_f32_16x16x32_bf16(af[i], bfv[j], acc[i][j], 0, 0, 0);
    }
    __syncthreads();
  }

  #pragma unroll
  for (int j = 0; j < 4; j++) {
    int cn = n0 + wc + j * 16 + fr;
    if (cn < N) {
      float bv = 0.f;
      if (EPI >= 1) bv = bias[cn];
      #pragma unroll
      for (int i = 0; i < 4; i++) {
        #pragma unroll
        for (int r4 = 0; r4 < 4; r4++) {
          int cm = m0 + wr + i * 16 + fq * 4 + r4;
          float val = acc[i][j][r4] + bv;
          if (EPI == 2) val = fmaxf(val, 0.f) + log1pf(__expf(-fabsf(val)));
          if (OUTBF) ((unsigned short*)Cv)[(size_t)cm * ldc + cn] = (unsigned short)f2bf(val);
          else       ((float*)Cv)[(size_t)cm * ldc + cn] = val;
        }
      }
    }
  }
}

// =================== f32-input GEMM (mel K=80, dt K=32) ===================
#define LDT 40
template<int EPI, int OUTBF>
__launch_bounds__(256)
__global__ void gemm_f32in(const float* __restrict__ A, const float* __restrict__ B,
                           void* __restrict__ Cv, const float* __restrict__ bias,
                           int M, int N, int K, int lda, int ldb, int ldc) {
  __shared__ short As[128 * LDT];
  __shared__ short Bs[128 * LDT];
  const int tid  = threadIdx.x;
  const int lane = tid & 63;
  const int wave = tid >> 6;
  const int m0 = blockIdx.y * 128;
  const int n0 = blockIdx.x * 128;
  const int wr = (wave >> 1) * 64;
  const int wc = (wave & 1) * 64;
  const int srow = tid >> 3;
  const int scol = (tid & 7) * 4;
  const int fr = lane & 15;
  const int fq = lane >> 4;

  f32x4 acc[4][4] = {};

  for (int k0 = 0; k0 < K; k0 += 32) {
    const bool kok = (k0 + scol) < K;
    #pragma unroll
    for (int rr = 0; rr < 128; rr += 32) {
      int r = srow + rr;
      f32x4 v = {0.f, 0.f, 0.f, 0.f};
      if (kok) v = *(const f32x4*)(A + (size_t)(m0 + r) * lda + k0 + scol);
      short4v s = { f2bf(v[0]), f2bf(v[1]), f2bf(v[2]), f2bf(v[3]) };
      *(short4v*)(&As[r * LDT + scol]) = s;
    }
    #pragma unroll
    for (int rr = 0; rr < 128; rr += 32) {
      int r = srow + rr;
      f32x4 v = {0.f, 0.f, 0.f, 0.f};
      if (kok && (n0 + r) < N) v = *(const f32x4*)(B + (size_t)(n0 + r) * ldb + k0 + scol);
      short4v s = { f2bf(v[0]), f2bf(v[1]), f2bf(v[2]), f2bf(v[3]) };
      *(short4v*)(&Bs[r * LDT + scol]) = s;
    }
    __syncthreads();
    bf16x8s af[4], bfv[4];
    #pragma unroll
    for (int i = 0; i < 4; i++)
      af[i]  = *(const bf16x8s*)(&As[(wr + i * 16 + fr) * LDT + fq * 8]);
    #pragma unroll
    for (int i = 0; i < 4; i++)
      bfv[i] = *(const bf16x8s*)(&Bs[(wc + i * 16 + fr) * LDT + fq * 8]);
    #pragma unroll
    for (int i = 0; i < 4; i++)
      #pragma unroll
      for (int j = 0; j < 4; j++)
        acc[i][j] = __builtin_amdgcn_mfma_f32_16x16x32_bf16(af[i], bfv[j], acc[i][j], 0, 0, 0);
    __syncthreads();
  }

  #pragma unroll
  for (int j = 0; j < 4; j++) {
    int cn = n0 + wc + j * 16 + fr;
    if (cn < N) {
      float bv = 0.f;
      if (EPI >= 1) bv = bias[cn];
      #pragma unroll
      for (int i = 0; i < 4; i++) {
        #pragma unroll
        for (int r4 = 0; r4 < 4; r4++) {
          int cm = m0 + wr + i * 16 + fq * 4 + r4;
          float val = acc[i][j][r4] + bv;
          if (EPI == 2) val = fmaxf(val, 0.f) + log1pf(__expf(-fabsf(val)));
          if (OUTBF) ((unsigned short*)Cv)[(size_t)cm * ldc + cn] = (unsigned short)f2bf(val);
          else       ((float*)Cv)[(size_t)cm * ldc + cn] = val;
        }
      }
    }
  }
}

// =================== weight f32 -> bf16 conversion (12 tensors, one launch) ===================
struct CvtArgs { const float* s[12]; unsigned short* d[12]; int n[12]; };
__global__ void cvt_many(CvtArgs a) {
  int y = blockIdx.y;
  int i = (blockIdx.x * 256 + threadIdx.x) * 8;
  if (i >= a.n[y]) return;
  const float* s = a.s[y];
  f32x4 v0 = *(const f32x4*)(s + i);
  f32x4 v1 = *(const f32x4*)(s + i + 4);
  ushort8 o = { (unsigned short)f2bf(v0[0]), (unsigned short)f2bf(v0[1]),
                (unsigned short)f2bf(v0[2]), (unsigned short)f2bf(v0[3]),
                (unsigned short)f2bf(v1[0]), (unsigned short)f2bf(v1[1]),
                (unsigned short)f2bf(v1[2]), (unsigned short)f2bf(v1[3]) };
  *(ushort8*)(a.d[y] + i) = o;
}

// =================== tiny attention (L=2) over bf16 qkv ===================
__global__ void attn_kernel(const unsigned short* __restrict__ qkv, unsigned short* __restrict__ o) {
  int gw = blockIdx.x * 4 + (threadIdx.x >> 6);
  int lane = threadIdx.x & 63;
  int n = gw >> 3, h = gw & 7;
  size_t r0 = (size_t)n * 1536 + h * 64 + lane;
  size_t r1 = (size_t)(SEQ + n) * 1536 + h * 64 + lane;
  float q0 = bf2f(qkv[r0]), k0 = bf2f(qkv[r0 + 512]), v0 = bf2f(qkv[r0 + 1024]);
  float q1 = bf2f(qkv[r1]), k1 = bf2f(qkv[r1 + 512]), v1 = bf2f(qkv[r1 + 1024]);
  float s00 = q0 * k0, s01 = q0 * k1, s10 = q1 * k0, s11 = q1 * k1;
  #pragma unroll
  for (int off = 32; off > 0; off >>= 1) {
    s00 += __shfl_xor(s00, off);
    s01 += __shfl_xor(s01, off);
    s10 += __shfl_xor(s10, off);
    s11 += __shfl_xor(s11, off);
  }
  const float sc = 0.125f;
  s00 *= sc; s01 *= sc; s10 *= sc; s11 *= sc;
  float mx0 = fmaxf(s00, s01), mx1 = fmaxf(s10, s11);
  float e00 = __expf(s00 - mx0), e01 = __expf(s01 - mx0);
  float e10 = __expf(s10 - mx1), e11 = __expf(s11 - mx1);
  float i0 = 1.f / (e00 + e01), i1 = 1.f / (e10 + e11);
  size_t w0 = (size_t)n * 512 + h * 64 + lane;
  size_t w1 = (size_t)(SEQ + n) * 512 + h * 64 + lane;
  o[w0] = (unsigned short)f2bf((e00 * v0 + e01 * v1) * i0);
  o[w1] = (unsigned short)f2bf((e10 * v0 + e11 * v1) * i1);
}

// =================== LN(a+b) over 512, bf16 in/out ===================
__global__ void ln_res_kernel(const unsigned short* __restrict__ a, const unsigned short* __restrict__ b,
                              const float* __restrict__ g, const float* __restrict__ be,
                              unsigned short* __restrict__ out) {
  int row = blockIdx.x * 4 + (threadIdx.x >> 6);
  int lane = threadIdx.x & 63;
  ushort8 va = *(const ushort8*)(a + (size_t)row * 512 + lane * 8);
  ushort8 vb = *(const ushort8*)(b + (size_t)row * 512 + lane * 8);
  float v[8];
  #pragma unroll
  for (int j = 0; j < 8; j++) v[j] = bf2f(va[j]) + bf2f(vb[j]);
  float s = 0.f, s2 = 0.f;
  #pragma unroll
  for (int j = 0; j < 8; j++) { s += v[j]; s2 += v[j] * v[j]; }
  #pragma unroll
  for (int off = 32; off > 0; off >>= 1) { s += __shfl_xor(s, off); s2 += __shfl_xor(s2, off); }
  float mu = s * (1.f / 512.f);
  float var = s2 * (1.f / 512.f) - mu * mu;
  float rs = rsqrtf(var + 1e-5f);
  const float* pg = g + lane * 8;
  const float* pe = be + lane * 8;
  ushort8 o;
  #pragma unroll
  for (int j = 0; j < 8; j++) o[j] = (unsigned short)f2bf((v[j] - mu) * rs * pg[j] + pe[j]);
  *(ushort8*)(out + (size_t)row * 512 + lane * 8) = o;
}

// =================== depthwise causal conv(K=4)+silu, bf16, 8 d per thread ===================
__global__ void conv_silu_kernel(const unsigned short* __restrict__ xz, const float* __restrict__ w,
                                 const float* __restrict__ cb, unsigned short* __restrict__ xc) {
  int idx = blockIdx.x * 256 + threadIdx.x;     // over B*S*(DI/8) = 524288
  int dc = (idx & 127) * 8;
  int t  = (idx >> 7) & (SEQ - 1);
  int b  = idx >> 18;
  f32x4 wv[8];
  #pragma unroll
  for (int j = 0; j < 8; j++) wv[j] = *(const f32x4*)(w + (dc + j) * 4);
  float acc[8];
  f32x4 cb0 = *(const f32x4*)(cb + dc), cb1 = *(const f32x4*)(cb + dc + 4);
  #pragma unroll
  for (int j = 0; j < 4; j++) { acc[j] = cb0[j]; acc[4 + j] = cb1[j]; }
  const unsigned short* base = xz + ((size_t)b * SEQ) * 2048 + dc;
  #pragma unroll
  for (int k = 0; k < 4; k++) {
    int tt = t - 3 + k;
    if (tt >= 0) {
      ushort8 xv = *(const ushort8*)(base + (size_t)tt * 2048);
      #pragma unroll
      for (int j = 0; j < 8; j++) acc[j] += wv[j][k] * bf2f(xv[j]);
    }
  }
  ushort8 o;
  #pragma unroll
  for (int j = 0; j < 8; j++) {
    float v = acc[j];
    o[j] = (unsigned short)f2bf(v / (1.f + __expf(-v)));
  }
  *(ushort8*)(xc + (size_t)idx * 8) = o;
}

// =================== chunked selective scan ===================
#define CL 16
#define NC 128

__global__ void scan_p1(const float* __restrict__ dt, const unsigned short* __restrict__ xc,
                        const float* __restrict__ dbl, const float* __restrict__ A_log,
                        float* __restrict__ hend, float* __restrict__ aprod) {
  int tid = blockIdx.x * 256 + threadIdx.x;   // B*NC*DI = 262144
  int d = tid & 1023;
  int c = (tid >> 10) & (NC - 1);
  int b = tid >> 17;
  float A[16];
  #pragma unroll
  for (int q = 0; q < 4; q++) {
    f32x4 v = *(const f32x4*)(A_log + d * 16 + q * 4);
    #pragma unroll
    for (int j = 0; j < 4; j++) A[q * 4 + j] = -__expf(v[j]);
  }
  float h[16] = {};
  float ap[16];
  #pragma unroll
  for (int n = 0; n < 16; n++) ap[n] = 1.f;
  const float* dtp = dt + ((size_t)b * SEQ) * 1024 + d;
  const unsigned short* xcp = xc + ((size_t)b * SEQ) * 1024 + d;
  const float* dbp = dbl + ((size_t)b * SEQ) * 64;
  const int t0 = c * CL;
  for (int t = t0; t < t0 + CL; t++) {
    float dtv = dtp[(size_t)t * 1024];
    float dx = dtv * bf2f(xcp[(size_t)t * 1024]);
    float Bv[16];
    #pragma unroll
    for (int q = 0; q < 4; q++) {
      f32x4 v = *(const f32x4*)(dbp + (size_t)t * 64 + 32 + q * 4);
      #pragma unroll
      for (int j = 0; j < 4; j++) Bv[q * 4 + j] = v[j];
    }
    #pragma unroll
    for (int n = 0; n < 16; n++) {
      float e = __expf(dtv * A[n]);
      h[n] = e * h[n] + dx * Bv[n];
      ap[n] *= e;
    }
  }
  size_t o = ((size_t)((b * NC + c) * 1024 + d)) * 16;
  #pragma unroll
  for (int q = 0; q < 4; q++) {
    f32x4 vh = { h[q * 4], h[q * 4 + 1], h[q * 4 + 2], h[q * 4 + 3] };
    f32x4 va = { ap[q * 4], ap[q * 4 + 1], ap[q * 4 + 2], ap[q * 4 + 3] };
    *(f32x4*)(hend + o + q * 4) = vh;
    *(f32x4*)(aprod + o + q * 4) = va;
  }
}

__global__ void scan_p2(const float* __restrict__ hend, const float* __restrict__ aprod,
                        float* __restrict__ h0) {
  int tid = blockIdx.x * 256 + threadIdx.x;   // B*DI*N = 32768
  int n = tid & 15;
  int d = (tid >> 4) & 1023;
  int b = tid >> 14;
  float h = 0.f;
  for (int c = 0; c < NC; c++) {
    size_t idx = ((size_t)((b * NC + c) * 1024 + d)) * 16 + n;
    h0[idx] = h;
    h = aprod[idx] * h + hend[idx];
  }
}

__global__ void scan_p3(const float* __restrict__ dt, const unsigned short* __restrict__ xc,
                        const float* __restrict__ dbl, const float* __restrict__ A_log,
                        const float* __restrict__ h0, unsigned short* __restrict__ ys) {
  int tid = blockIdx.x * 256 + threadIdx.x;   // B*NC*DI = 262144
  int d = tid & 1023;
  int c = (tid >> 10) & (NC - 1);
  int b = tid >> 17;
  float A[16];
  #pragma unroll
  for (int q = 0; q < 4; q++) {
    f32x4 v = *(const f32x4*)(A_log + d * 16 + q * 4);
    #pragma unroll
    for (int j = 0; j < 4; j++) A[q * 4 + j] = -__expf(v[j]);
  }
  float h[16];
  size_t o = ((size_t)((b * NC + c) * 1024 + d)) * 16;
  #pragma unroll
  for (int q = 0; q < 4; q++) {
    f32x4 v = *(const f32x4*)(h0 + o + q * 4);
    #pragma unroll
    for (int j = 0; j < 4; j++) h[q * 4 + j] = v[j];
  }
  const float* dtp = dt + ((size_t)b * SEQ) * 1024 + d;
  const unsigned short* xcp = xc + ((size_t)b * SEQ) * 1024 + d;
  const float* dbp = dbl + ((size_t)b * SEQ) * 64;
  unsigned short* ysp = ys + ((size_t)b * SEQ) * 1024 + d;
  const int t0 = c * CL;
  for (int t = t0; t < t0 + CL; t++) {
    float dtv = dtp[(size_t)t * 1024];
    float dx = dtv * bf2f(xcp[(size_t)t * 1024]);
    float Bv[16], Cv[16];
    #pragma unroll
    for (int q = 0; q < 4; q++) {
      f32x4 v = *(const f32x4*)(dbp + (size_t)t * 64 + 32 + q * 4);
      f32x4 w = *(const f32x4*)(dbp + (size_t)t * 64 + 48 + q * 4);
      #pragma unroll
      for (int j = 0; j < 4; j++) { Bv[q * 4 + j] = v[j]; Cv[q * 4 + j] = w[j]; }
    }
    float y = 0.f;
    #pragma unroll
    for (int n = 0; n < 16; n++) {
      float e = __expf(dtv * A[n]);
      h[n] = e * h[n] + dx * Bv[n];
      y += h[n] * Cv[n];
    }
    ysp[(size_t)t * 1024] = (unsigned short)f2bf(y);
  }
}

// =================== gate: ys = (ys + xc*D) * silu(z) ===================
__global__ void gate_kernel(unsigned short* __restrict__ ys, const unsigned short* __restrict__ xc,
                            const float* __restrict__ Dp, const unsigned short* __restrict__ xz) {
  int idx = blockIdx.x * 256 + threadIdx.x;   // over B*S*(DI/8) = 524288
  int dc = (idx & 127) * 8;
  int bt = idx >> 7;
  ushort8 y8 = *(const ushort8*)(ys + (size_t)idx * 8);
  ushort8 x8 = *(const ushort8*)(xc + (size_t)idx * 8);
  ushort8 z8 = *(const ushort8*)(xz + (size_t)bt * 2048 + 1024 + dc);
  f32x4 d0 = *(const f32x4*)(Dp + dc), d1 = *(const f32x4*)(Dp + dc + 4);
  float dp[8];
  #pragma unroll
  for (int j = 0; j < 4; j++) { dp[j] = d0[j]; dp[4 + j] = d1[j]; }
  ushort8 o;
  #pragma unroll
  for (int j = 0; j < 8; j++) {
    float z = bf2f(z8[j]);
    float y = bf2f(y8[j]) + bf2f(x8[j]) * dp[j];
    o[j] = (unsigned short)f2bf(y * (z / (1.f + __expf(-z))));
  }
  *(ushort8*)(ys + (size_t)idx * 8) = o;
}

// =================== time flip for (B,S,W) bf16, W = 1<<ws, 8 elems/thread ===================
__global__ void flip_kernel(const unsigned short* __restrict__ in, unsigned short* __restrict__ out, int ws) {
  int idx = blockIdx.x * 256 + threadIdx.x;
  int c = idx & ((1 << (ws - 3)) - 1);
  int t = (idx >> (ws - 3)) & (SEQ - 1);
  int b = idx >> (ws - 3 + 11);
  ushort8 v = *(const ushort8*)(in + (((size_t)(b * SEQ + (SEQ - 1 - t))) << ws) + c * 8);
  *(ushort8*)(out + (size_t)idx * 8) = v;
}

extern "C" void kernel_launch(void* const* d_in, const int* in_sizes, int n_in,
                              void* d_out, int out_size, void* d_ws, size_t ws_size,
                              hipStream_t stream) {
  (void)in_sizes; (void)n_in; (void)out_size; (void)ws_size;
  const float* mel        = (const float*)d_in[0];
  const float* mel_w      = (const float*)d_in[1];
  const float* mel_b      = (const float*)d_in[2];
  const float* attn_in_b  = (const float*)d_in[4];
  const float* attn_out_b = (const float*)d_in[6];
  const float* ln1_g = (const float*)d_in[7];
  const float* ln1_b = (const float*)d_in[8];
  const float* ln2_g = (const float*)d_in[9];
  const float* ln2_b = (const float*)d_in[10];
  const float* bim_b = (const float*)d_in[30];
  const float* out_b = (const float*)d_in[32];

  char* wsb = (char*)d_ws;
  char* obb = (char*)d_out;

  // ---- bf16 weights in ws (byte offsets) ----
  unsigned short* w_attn_in  = (unsigned short*)(wsb + 0);          // 786432
  unsigned short* w_attn_out = (unsigned short*)(wsb + 1572864);    // 262144
  unsigned short* w_dir[2][4]; // in_w, x_w, dt_w(unused slot), out_w  -- dt handled f32
  // fm block @2097152: in_w(1048576 us), x_w(65536), dt_w(32768), out_w(524288)
  for (int dir = 0; dir < 2; dir++) {
    size_t base = 2097152 + (size_t)dir * 3342336;
    w_dir[dir][0] = (unsigned short*)(wsb + base);                  // in_w
    w_dir[dir][1] = (unsigned short*)(wsb + base + 2097152);        // x_w
    w_dir[dir][2] = (unsigned short*)(wsb + base + 2228224);        // dt_w (bf16, unused)
    w_dir[dir][3] = (unsigned short*)(wsb + base + 2293760);        // out_w
  }
  unsigned short* w_bim = (unsigned short*)(wsb + 8781824);         // 524288
  unsigned short* w_out = (unsigned short*)(wsb + 9830400);         // 5120000

  // ---- bf16 activations in ws ----
  unsigned short* x0     = (unsigned short*)(wsb + 20971520);  // 2M us
  unsigned short* x1     = (unsigned short*)(wsb + 25165824);
  unsigned short* x1f    = (unsigned short*)(wsb + 29360128);
  unsigned short* attn_o = (unsigned short*)(wsb + 33554432);
  unsigned short* xc     = (unsigned short*)(wsb + 37748736);  // 4M us
  unsigned short* ysb    = (unsigned short*)(wsb + 46137344);  // 4M us
  unsigned short* yflip  = (unsigned short*)(wsb + 54525952);  // 4M us
  unsigned short* mout   = (unsigned short*)(wsb + 62914560);  // 4M us
  unsigned short* minter = (unsigned short*)(wsb + 71303168);  // 2M us
  unsigned short* x2     = (unsigned short*)(wsb + 75497472);  // 2M us
  float*          dbl    = (float*)(wsb + 79691776);           // 262144 f32

  // ---- d_out scratch (dead until final GEMM overwrites all) ----
  unsigned short* qkv = (unsigned short*)(obb + 0);            // 6.29M us
  unsigned short* xz  = (unsigned short*)(obb + 12582912);     // 16.78M us
  float* dtf  = (float*)(obb + 46137344);                      // 4M f32
  float* hend = (float*)(obb + 62914560);                      // 4M f32
  float* apr  = (float*)(obb + 79691776);                      // 4M f32
  float* h0s  = (float*)(obb + 96468992);                      // 4M f32
  float* ob   = (float*)d_out;

  dim3 blk(256);

  // 0. convert weights to bf16 (one launch)
  {
    CvtArgs a;
    const float* srcs[12] = { (const float*)d_in[3], (const float*)d_in[5],
      (const float*)d_in[11], (const float*)d_in[14], (const float*)d_in[15], (const float*)d_in[19],
      (const float*)d_in[20], (const float*)d_in[23], (const float*)d_in[24], (const float*)d_in[28],
      (const float*)d_in[29], (const float*)d_in[31] };
    unsigned short* dsts[12] = { w_attn_in, w_attn_out,
      w_dir[0][0], w_dir[0][1], w_dir[0][2], w_dir[0][3],
      w_dir[1][0], w_dir[1][1], w_dir[1][2], w_dir[1][3],
      w_bim, w_out };
    int ns[12] = { 786432, 262144, 1048576, 65536, 32768, 524288,
                   1048576, 65536, 32768, 524288, 524288, 5120000 };
    for (int i = 0; i < 12; i++) { a.s[i] = srcs[i]; a.d[i] = dsts[i]; a.n[i] = ns[i]; }
    cvt_many<<<dim3(2500, 12), blk, 0, stream>>>(a);
  }

  // 1. x0 = mel @ mel_w.T + mel_b (f32-in path, K=80)
  gemm_f32in<1, 1><<<dim3(4, 32), blk, 0, stream>>>(mel, mel_w, x0, mel_b, 4096, 512, 80, 80, 80, 512);
  // 2. qkv = x0 @ attn_in_w.T + b
  gemm_bf16<1, 1><<<dim3(12 * 32), blk, 0, stream>>>(x0, w_attn_in, qkv, attn_in_b, 4096, 1536, 512, 512, 512, 1536, 32);
  // 3. attention
  attn_kernel<<<4096, blk, 0, stream>>>(qkv, attn_o);
  // 4. attnproj -> qkv slot
  gemm_bf16<1, 1><<<dim3(4 * 32), blk, 0, stream>>>(attn_o, w_attn_out, qkv, attn_out_b, 4096, 512, 512, 512, 512, 512, 32);
  // 5. x1 = LN(x0 + attnproj)
  ln_res_kernel<<<1024, blk, 0, stream>>>(x0, qkv, ln1_g, ln1_b, x1);
  // 6. x1f = flip(x1)
  flip_kernel<<<1024, blk, 0, stream>>>(x1, x1f, 9);

  for (int dir = 0; dir < 2; dir++) {
    int base = 11 + dir * 9;
    const float* conv_w  = (const float*)d_in[base + 1];
    const float* conv_b  = (const float*)d_in[base + 2];
    const float* dt_w    = (const float*)d_in[base + 4];
    const float* dt_bias = (const float*)d_in[base + 5];
    const float* A_log   = (const float*)d_in[base + 6];
    const float* Dp      = (const float*)d_in[base + 7];
    const unsigned short* xin = dir ? x1f : x1;
    // xz = xin @ in_w.T
    gemm_bf16<0, 1><<<dim3(16 * 32), blk, 0, stream>>>(xin, w_dir[dir][0], xz, nullptr, 4096, 2048, 512, 512, 512, 2048, 32);
    // conv + silu
    conv_silu_kernel<<<2048, blk, 0, stream>>>(xz, conv_w, conv_b, xc);
    // dbl = xc @ x_w.T (f32 out for scan numerics)
    gemm_bf16<0, 0><<<dim3(1 * 32), blk, 0, stream>>>(xc, w_dir[dir][1], dbl, nullptr, 4096, 64, 1024, 1024, 1024, 64, 32);
    // dt = softplus(dbl[:, :32] @ dt_w.T + dt_b)  (f32-in path, K=32)
    gemm_f32in<2, 0><<<dim3(8, 32), blk, 0, stream>>>(dbl, dt_w, dtf, dt_bias, 4096, 1024, 32, 64, 32, 1024);
    // selective scan
    scan_p1<<<1024, blk, 0, stream>>>(dtf, xc, dbl, A_log, hend, apr);
    scan_p2<<<128, blk, 0, stream>>>(hend, apr, h0s);
    scan_p3<<<1024, blk, 0, stream>>>(dtf, xc, dbl, A_log, h0s, ysb);
    // gate
    gate_kernel<<<2048, blk, 0, stream>>>(ysb, xc, Dp, xz);
    const unsigned short* yin = ysb;
    if (dir) { flip_kernel<<<2048, blk, 0, stream>>>(ysb, yflip, 10); yin = yflip; }
    // mamba out proj -> mout cols [dir*512, +512)
    gemm_bf16<0, 1><<<dim3(4 * 32), blk, 0, stream>>>(yin, w_dir[dir][3], mout + dir * 512, nullptr, 4096, 512, 1024, 1024, 1024, 1024, 32);
  }

  // m = mout @ bim_w.T + bim_b
  gemm_bf16<1, 1><<<dim3(4 * 32), blk, 0, stream>>>(mout, w_bim, minter, bim_b, 4096, 512, 1024, 1024, 1024, 512, 32);
  // x2 = LN(x1 + m)
  ln_res_kernel<<<1024, blk, 0, stream>>>(x1, minter, ln2_g, ln2_b, x2);
  // logits = x2 @ out_w.T + out_b  (overwrites all of d_out)
  gemm_bf16<1, 0><<<dim3(79 * 32), blk, 0, stream>>>(x2, w_out, ob, out_b, 4096, 10000, 512, 512, 512, 10000, 32);
}

// Round 5
// 737.246 us; speedup vs baseline: 3.6555x; 1.1729x over previous
//
#include <hip/hip_runtime.h>
#include <hip/hip_bf16.h>
#include <math.h>

// Model dims
#define SEQ 2048
// B=2, DM=512, DI=1024, N=16, K=4, R=32, H=8, V=10000

typedef __attribute__((ext_vector_type(4))) float f32x4;
typedef __attribute__((ext_vector_type(8))) short bf16x8s;
typedef __attribute__((ext_vector_type(4))) short short4v;
typedef __attribute__((ext_vector_type(8))) unsigned short ushort8;
typedef __attribute__((ext_vector_type(2))) unsigned int uint2v;

__device__ __forceinline__ short f2bf(float f) {
  union { float f; unsigned u; } c; c.f = f;
  unsigned u = c.u;
  u += 0x7fffu + ((u >> 16) & 1u);   // RNE
  return (short)(u >> 16);
}
__device__ __forceinline__ float bf2f(unsigned short u) {
  union { unsigned u; float f; } c; c.u = ((unsigned)u) << 16; return c.f;
}

__device__ __forceinline__ void lds_load16(const void* g, void* s) {
  __builtin_amdgcn_global_load_lds(
      (const __attribute__((address_space(1))) void*)g,
      (__attribute__((address_space(3))) void*)s, 16, 0, 0);
}

// =================== bf16 MFMA GEMM: C[M,N] = A[M,K] @ B[N,K]^T ===================
// A,B bf16 (K%64==0, lda/ldb %8==0, M%128==0, N%4==0).
// EPI: 0 none, 1 +bias, 2 +bias+softplus. OUTBF: 1 -> bf16 C, 0 -> f32 C.
// T3-min double-buffered pipeline: STAGE(t+1) issued before compute(t), one
// raw vmcnt(0)+s_barrier per K-tile. XOR-chunk swizzled LDS (pre-swizzled
// global source, linear LDS dest). Epilogue staged through LDS for coalesced
// dwordx4/dwordx2 stores; nontemporal for the f32 final-logits case.
template<int EPI, int OUTBF>
__launch_bounds__(256)
__global__ void gemm_bf16(const unsigned short* __restrict__ A, const unsigned short* __restrict__ B,
                          void* __restrict__ Cv, const float* __restrict__ bias,
                          int M, int N, int K, int lda, int ldb, int ldc, int nbn) {
  __shared__ char smem[67584];   // 2x(16KB A + 16KB B) dbuf; 128x132 f32 epilogue tile

  // bijective XCD chunk swizzle (m204), bn-fastest within chunk (A L2-resident)
  const int nwg = gridDim.x;
  const int g = blockIdx.x;
  const int q = nwg >> 3, r = nwg & 7;
  const int xcd = g & 7, cidx = g >> 3;
  const int wg = (xcd < r ? xcd * (q + 1) : r * (q + 1) + (xcd - r) * q) + cidx;
  const int bm = wg / nbn, bn = wg % nbn;
  const int m0 = bm * 128, n0 = bn * 128;

  const int tid = threadIdx.x, lane = tid & 63, wave = tid >> 6;
  const int wr = (wave >> 1) * 64, wc = (wave & 1) * 64;
  const int fr = lane & 15, fq = lane >> 4;
  const int srow = tid >> 3;   // 0..31
  const int scc  = tid & 7;    // column chunk 0..7 (8 bf16 each)

  f32x4 acc[4][4] = {};
  const int nkt = K >> 6;

  auto STAGE = [&](int buf, int kt) {
    const int k0 = kt << 6;
    unsigned short* sAb = (unsigned short*)(smem + buf * 32768);
    unsigned short* sBb = (unsigned short*)(smem + buf * 32768 + 16384);
    #pragma unroll
    for (int j = 0; j < 4; j++) {
      int lrow = j * 32 + srow;
      int gcol = (scc ^ (lrow & 7)) * 8;
      lds_load16(A + (size_t)(m0 + lrow) * lda + k0 + gcol, &sAb[(j * 256 + wave * 64) * 8]);
    }
    #pragma unroll
    for (int j = 0; j < 4; j++) {
      int lrow = j * 32 + srow;
      int gcol = (scc ^ (lrow & 7)) * 8;
      int grow = n0 + lrow; if (grow >= N) grow = N - 1;   // clamp; junk never stored
      lds_load16(B + (size_t)grow * ldb + k0 + gcol, &sBb[(j * 256 + wave * 64) * 8]);
    }
  };

  STAGE(0, 0);
  asm volatile("s_waitcnt vmcnt(0)" ::: "memory");
  __builtin_amdgcn_s_barrier();

  int cur = 0;
  for (int kt = 0; kt < nkt; kt++) {
    if (kt + 1 < nkt) STAGE(cur ^ 1, kt + 1);   // issue next-tile loads first
    const unsigned short* As = (const unsigned short*)(smem + cur * 32768);
    const unsigned short* Bs = (const unsigned short*)(smem + cur * 32768 + 16384);
    #pragma unroll
    for (int ks = 0; ks < 2; ks++) {
      bf16x8s af[4], bfv[4];
      #pragma unroll
      for (int i = 0; i < 4; i++) {
        int ra = wr + i * 16 + fr;
        af[i] = *(const bf16x8s*)&As[ra * 64 + (((ks << 2) + fq) ^ (ra & 7)) * 8];
      }
      #pragma unroll
      for (int i = 0; i < 4; i++) {
        int rb = wc + i * 16 + fr;
        bfv[i] = *(const bf16x8s*)&Bs[rb * 64 + (((ks << 2) + fq) ^ (rb & 7)) * 8];
      }
      #pragma unroll
      for (int i = 0; i < 4; i++)
        #pragma unroll
        for (int j = 0; j < 4; j++)
          acc[i][j] = __builtin_amdgcn_mfma_f32_16x16x32_bf16(af[i], bfv[j], acc[i][j], 0, 0, 0);
    }
    asm volatile("s_waitcnt vmcnt(0)" ::: "memory");  // this wave's stage loads landed
    __builtin_amdgcn_s_barrier();                     // all waves' loads landed / reads done
    cur ^= 1;
  }

  // ---- epilogue: stage f32 tile in LDS, write coalesced ----
  float* ct = (float*)smem;   // [128][132]
  #pragma unroll
  for (int i = 0; i < 4; i++)
    #pragma unroll
    for (int j = 0; j < 4; j++)
      #pragma unroll
      for (int r4 = 0; r4 < 4; r4++)
        ct[(wr + i * 16 + fq * 4 + r4) * 132 + wc + j * 16 + fr] = acc[i][j][r4];
  __syncthreads();
  const int half = lane >> 5;
  const int col4 = (lane & 31) * 4;
  const int cn = n0 + col4;
  #pragma unroll
  for (int it = 0; it < 16; it++) {
    int row = wave * 32 + it * 2 + half;
    f32x4 v = *(const f32x4*)&ct[row * 132 + col4];
    if (cn < N) {
      if (EPI >= 1) {
        f32x4 b4 = *(const f32x4*)&bias[cn];
        #pragma unroll
        for (int j = 0; j < 4; j++) v[j] += b4[j];
      }
      if (EPI == 2) {
        #pragma unroll
        for (int j = 0; j < 4; j++)
          v[j] = fmaxf(v[j], 0.f) + log1pf(__expf(-fabsf(v[j])));
      }
      if (OUTBF) {
        unsigned short h0 = (unsigned short)f2bf(v[0]), h1 = (unsigned short)f2bf(v[1]);
        unsigned short h2 = (unsigned short)f2bf(v[2]), h3 = (unsigned short)f2bf(v[3]);
        uint2v o = { (unsigned)h0 | ((unsigned)h1 << 16), (unsigned)h2 | ((unsigned)h3 << 16) };
        *(uint2v*)((unsigned short*)Cv + (size_t)(m0 + row) * ldc + cn) = o;
      } else {
        float* dst = (float*)Cv + (size_t)(m0 + row) * ldc + cn;
        if (EPI == 1) __builtin_nontemporal_store(v, (f32x4*)dst);  // final logits: stream past L2
        else          *(f32x4*)dst = v;
      }
    }
  }
}

// =================== f32-input GEMM (mel K=80, dt K=32) ===================
#define LDT 40
template<int EPI, int OUTBF>
__launch_bounds__(256)
__global__ void gemm_f32in(const float* __restrict__ A, const float* __restrict__ B,
                           void* __restrict__ Cv, const float* __restrict__ bias,
                           int M, int N, int K, int lda, int ldb, int ldc) {
  __shared__ short As[128 * LDT];
  __shared__ short Bs[128 * LDT];
  const int tid  = threadIdx.x;
  const int lane = tid & 63;
  const int wave = tid >> 6;
  const int m0 = blockIdx.y * 128;
  const int n0 = blockIdx.x * 128;
  const int wr = (wave >> 1) * 64;
  const int wc = (wave & 1) * 64;
  const int srow = tid >> 3;
  const int scol = (tid & 7) * 4;
  const int fr = lane & 15;
  const int fq = lane >> 4;

  f32x4 acc[4][4] = {};

  for (int k0 = 0; k0 < K; k0 += 32) {
    const bool kok = (k0 + scol) < K;
    #pragma unroll
    for (int rr = 0; rr < 128; rr += 32) {
      int r = srow + rr;
      f32x4 v = {0.f, 0.f, 0.f, 0.f};
      if (kok) v = *(const f32x4*)(A + (size_t)(m0 + r) * lda + k0 + scol);
      short4v s = { f2bf(v[0]), f2bf(v[1]), f2bf(v[2]), f2bf(v[3]) };
      *(short4v*)(&As[r * LDT + scol]) = s;
    }
    #pragma unroll
    for (int rr = 0; rr < 128; rr += 32) {
      int r = srow + rr;
      f32x4 v = {0.f, 0.f, 0.f, 0.f};
      if (kok && (n0 + r) < N) v = *(const f32x4*)(B + (size_t)(n0 + r) * ldb + k0 + scol);
      short4v s = { f2bf(v[0]), f2bf(v[1]), f2bf(v[2]), f2bf(v[3]) };
      *(short4v*)(&Bs[r * LDT + scol]) = s;
    }
    __syncthreads();
    bf16x8s af[4], bfv[4];
    #pragma unroll
    for (int i = 0; i < 4; i++)
      af[i]  = *(const bf16x8s*)(&As[(wr + i * 16 + fr) * LDT + fq * 8]);
    #pragma unroll
    for (int i = 0; i < 4; i++)
      bfv[i] = *(const bf16x8s*)(&Bs[(wc + i * 16 + fr) * LDT + fq * 8]);
    #pragma unroll
    for (int i = 0; i < 4; i++)
      #pragma unroll
      for (int j = 0; j < 4; j++)
        acc[i][j] = __builtin_amdgcn_mfma_f32_16x16x32_bf16(af[i], bfv[j], acc[i][j], 0, 0, 0);
    __syncthreads();
  }

  #pragma unroll
  for (int j = 0; j < 4; j++) {
    int cn = n0 + wc + j * 16 + fr;
    if (cn < N) {
      float bv = 0.f;
      if (EPI >= 1) bv = bias[cn];
      #pragma unroll
      for (int i = 0; i < 4; i++) {
        #pragma unroll
        for (int r4 = 0; r4 < 4; r4++) {
          int cm = m0 + wr + i * 16 + fq * 4 + r4;
          float val = acc[i][j][r4] + bv;
          if (EPI == 2) val = fmaxf(val, 0.f) + log1pf(__expf(-fabsf(val)));
          if (OUTBF) ((unsigned short*)Cv)[(size_t)cm * ldc + cn] = (unsigned short)f2bf(val);
          else       ((float*)Cv)[(size_t)cm * ldc + cn] = val;
        }
      }
    }
  }
}

// =================== weight f32 -> bf16 conversion (12 tensors, one launch) ===================
struct CvtArgs { const float* s[12]; unsigned short* d[12]; int n[12]; };
__global__ void cvt_many(CvtArgs a) {
  int y = blockIdx.y;
  int i = (blockIdx.x * 256 + threadIdx.x) * 8;
  if (i >= a.n[y]) return;
  const float* s = a.s[y];
  f32x4 v0 = *(const f32x4*)(s + i);
  f32x4 v1 = *(const f32x4*)(s + i + 4);
  ushort8 o = { (unsigned short)f2bf(v0[0]), (unsigned short)f2bf(v0[1]),
                (unsigned short)f2bf(v0[2]), (unsigned short)f2bf(v0[3]),
                (unsigned short)f2bf(v1[0]), (unsigned short)f2bf(v1[1]),
                (unsigned short)f2bf(v1[2]), (unsigned short)f2bf(v1[3]) };
  *(ushort8*)(a.d[y] + i) = o;
}

// =================== tiny attention (L=2) over bf16 qkv ===================
__global__ void attn_kernel(const unsigned short* __restrict__ qkv, unsigned short* __restrict__ o) {
  int gw = blockIdx.x * 4 + (threadIdx.x >> 6);
  int lane = threadIdx.x & 63;
  int n = gw >> 3, h = gw & 7;
  size_t r0 = (size_t)n * 1536 + h * 64 + lane;
  size_t r1 = (size_t)(SEQ + n) * 1536 + h * 64 + lane;
  float q0 = bf2f(qkv[r0]), k0 = bf2f(qkv[r0 + 512]), v0 = bf2f(qkv[r0 + 1024]);
  float q1 = bf2f(qkv[r1]), k1 = bf2f(qkv[r1 + 512]), v1 = bf2f(qkv[r1 + 1024]);
  float s00 = q0 * k0, s01 = q0 * k1, s10 = q1 * k0, s11 = q1 * k1;
  #pragma unroll
  for (int off = 32; off > 0; off >>= 1) {
    s00 += __shfl_xor(s00, off);
    s01 += __shfl_xor(s01, off);
    s10 += __shfl_xor(s10, off);
    s11 += __shfl_xor(s11, off);
  }
  const float sc = 0.125f;
  s00 *= sc; s01 *= sc; s10 *= sc; s11 *= sc;
  float mx0 = fmaxf(s00, s01), mx1 = fmaxf(s10, s11);
  float e00 = __expf(s00 - mx0), e01 = __expf(s01 - mx0);
  float e10 = __expf(s10 - mx1), e11 = __expf(s11 - mx1);
  float i0 = 1.f / (e00 + e01), i1 = 1.f / (e10 + e11);
  size_t w0 = (size_t)n * 512 + h * 64 + lane;
  size_t w1 = (size_t)(SEQ + n) * 512 + h * 64 + lane;
  o[w0] = (unsigned short)f2bf((e00 * v0 + e01 * v1) * i0);
  o[w1] = (unsigned short)f2bf((e10 * v0 + e11 * v1) * i1);
}

// =================== LN(a+b) over 512, bf16 in/out ===================
__global__ void ln_res_kernel(const unsigned short* __restrict__ a, const unsigned short* __restrict__ b,
                              const float* __restrict__ g, const float* __restrict__ be,
                              unsigned short* __restrict__ out) {
  int row = blockIdx.x * 4 + (threadIdx.x >> 6);
  int lane = threadIdx.x & 63;
  ushort8 va = *(const ushort8*)(a + (size_t)row * 512 + lane * 8);
  ushort8 vb = *(const ushort8*)(b + (size_t)row * 512 + lane * 8);
  float v[8];
  #pragma unroll
  for (int j = 0; j < 8; j++) v[j] = bf2f(va[j]) + bf2f(vb[j]);
  float s = 0.f, s2 = 0.f;
  #pragma unroll
  for (int j = 0; j < 8; j++) { s += v[j]; s2 += v[j] * v[j]; }
  #pragma unroll
  for (int off = 32; off > 0; off >>= 1) { s += __shfl_xor(s, off); s2 += __shfl_xor(s2, off); }
  float mu = s * (1.f / 512.f);
  float var = s2 * (1.f / 512.f) - mu * mu;
  float rs = rsqrtf(var + 1e-5f);
  const float* pg = g + lane * 8;
  const float* pe = be + lane * 8;
  ushort8 o;
  #pragma unroll
  for (int j = 0; j < 8; j++) o[j] = (unsigned short)f2bf((v[j] - mu) * rs * pg[j] + pe[j]);
  *(ushort8*)(out + (size_t)row * 512 + lane * 8) = o;
}

// =================== depthwise causal conv(K=4)+silu, bf16, 8 d per thread ===================
__global__ void conv_silu_kernel(const unsigned short* __restrict__ xz, const float* __restrict__ w,
                                 const float* __restrict__ cb, unsigned short* __restrict__ xc) {
  int idx = blockIdx.x * 256 + threadIdx.x;     // over B*S*(DI/8) = 524288
  int dc = (idx & 127) * 8;
  int t  = (idx >> 7) & (SEQ - 1);
  int b  = idx >> 18;
  f32x4 wv[8];
  #pragma unroll
  for (int j = 0; j < 8; j++) wv[j] = *(const f32x4*)(w + (dc + j) * 4);
  float acc[8];
  f32x4 cb0 = *(const f32x4*)(cb + dc), cb1 = *(const f32x4*)(cb + dc + 4);
  #pragma unroll
  for (int j = 0; j < 4; j++) { acc[j] = cb0[j]; acc[4 + j] = cb1[j]; }
  const unsigned short* base = xz + ((size_t)b * SEQ) * 2048 + dc;
  #pragma unroll
  for (int k = 0; k < 4; k++) {
    int tt = t - 3 + k;
    if (tt >= 0) {
      ushort8 xv = *(const ushort8*)(base + (size_t)tt * 2048);
      #pragma unroll
      for (int j = 0; j < 8; j++) acc[j] += wv[j][k] * bf2f(xv[j]);
    }
  }
  ushort8 o;
  #pragma unroll
  for (int j = 0; j < 8; j++) {
    float v = acc[j];
    o[j] = (unsigned short)f2bf(v / (1.f + __expf(-v)));
  }
  *(ushort8*)(xc + (size_t)idx * 8) = o;
}

// =================== chunked selective scan ===================
#define CL 16
#define NC 128

__global__ void scan_p1(const float* __restrict__ dt, const unsigned short* __restrict__ xc,
                        const float* __restrict__ dbl, const float* __restrict__ A_log,
                        float* __restrict__ hend, float* __restrict__ aprod) {
  int tid = blockIdx.x * 256 + threadIdx.x;   // B*NC*DI = 262144
  int d = tid & 1023;
  int c = (tid >> 10) & (NC - 1);
  int b = tid >> 17;
  float A[16];
  #pragma unroll
  for (int q = 0; q < 4; q++) {
    f32x4 v = *(const f32x4*)(A_log + d * 16 + q * 4);
    #pragma unroll
    for (int j = 0; j < 4; j++) A[q * 4 + j] = -__expf(v[j]);
  }
  float h[16] = {};
  float ap[16];
  #pragma unroll
  for (int n = 0; n < 16; n++) ap[n] = 1.f;
  const float* dtp = dt + ((size_t)b * SEQ) * 1024 + d;
  const unsigned short* xcp = xc + ((size_t)b * SEQ) * 1024 + d;
  const float* dbp = dbl + ((size_t)b * SEQ) * 64;
  const int t0 = c * CL;
  for (int t = t0; t < t0 + CL; t++) {
    float dtv = dtp[(size_t)t * 1024];
    float dx = dtv * bf2f(xcp[(size_t)t * 1024]);
    float Bv[16];
    #pragma unroll
    for (int q = 0; q < 4; q++) {
      f32x4 v = *(const f32x4*)(dbp + (size_t)t * 64 + 32 + q * 4);
      #pragma unroll
      for (int j = 0; j < 4; j++) Bv[q * 4 + j] = v[j];
    }
    #pragma unroll
    for (int n = 0; n < 16; n++) {
      float e = __expf(dtv * A[n]);
      h[n] = e * h[n] + dx * Bv[n];
      ap[n] *= e;
    }
  }
  size_t o = ((size_t)((b * NC + c) * 1024 + d)) * 16;
  #pragma unroll
  for (int q = 0; q < 4; q++) {
    f32x4 vh = { h[q * 4], h[q * 4 + 1], h[q * 4 + 2], h[q * 4 + 3] };
    f32x4 va = { ap[q * 4], ap[q * 4 + 1], ap[q * 4 + 2], ap[q * 4 + 3] };
    *(f32x4*)(hend + o + q * 4) = vh;
    *(f32x4*)(aprod + o + q * 4) = va;
  }
}

__global__ void scan_p2(const float* __restrict__ hend, const float* __restrict__ aprod,
                        float* __restrict__ h0) {
  int tid = blockIdx.x * 256 + threadIdx.x;   // B*DI*N = 32768
  int n = tid & 15;
  int d = (tid >> 4) & 1023;
  int b = tid >> 14;
  float h = 0.f;
  for (int c = 0; c < NC; c++) {
    size_t idx = ((size_t)((b * NC + c) * 1024 + d)) * 16 + n;
    h0[idx] = h;
    h = aprod[idx] * h + hend[idx];
  }
}

__global__ void scan_p3(const float* __restrict__ dt, const unsigned short* __restrict__ xc,
                        const float* __restrict__ dbl, const float* __restrict__ A_log,
                        const float* __restrict__ h0, unsigned short* __restrict__ ys) {
  int tid = blockIdx.x * 256 + threadIdx.x;   // B*NC*DI = 262144
  int d = tid & 1023;
  int c = (tid >> 10) & (NC - 1);
  int b = tid >> 17;
  float A[16];
  #pragma unroll
  for (int q = 0; q < 4; q++) {
    f32x4 v = *(const f32x4*)(A_log + d * 16 + q * 4);
    #pragma unroll
    for (int j = 0; j < 4; j++) A[q * 4 + j] = -__expf(v[j]);
  }
  float h[16];
  size_t o = ((size_t)((b * NC + c) * 1024 + d)) * 16;
  #pragma unroll
  for (int q = 0; q < 4; q++) {
    f32x4 v = *(const f32x4*)(h0 + o + q * 4);
    #pragma unroll
    for (int j = 0; j < 4; j++) h[q * 4 + j] = v[j];
  }
  const float* dtp = dt + ((size_t)b * SEQ) * 1024 + d;
  const unsigned short* xcp = xc + ((size_t)b * SEQ) * 1024 + d;
  const float* dbp = dbl + ((size_t)b * SEQ) * 64;
  unsigned short* ysp = ys + ((size_t)b * SEQ) * 1024 + d;
  const int t0 = c * CL;
  for (int t = t0; t < t0 + CL; t++) {
    float dtv = dtp[(size_t)t * 1024];
    float dx = dtv * bf2f(xcp[(size_t)t * 1024]);
    float Bv[16], Cv[16];
    #pragma unroll
    for (int q = 0; q < 4; q++) {
      f32x4 v = *(const f32x4*)(dbp + (size_t)t * 64 + 32 + q * 4);
      f32x4 w = *(const f32x4*)(dbp + (size_t)t * 64 + 48 + q * 4);
      #pragma unroll
      for (int j = 0; j < 4; j++) { Bv[q * 4 + j] = v[j]; Cv[q * 4 + j] = w[j]; }
    }
    float y = 0.f;
    #pragma unroll
    for (int n = 0; n < 16; n++) {
      float e = __expf(dtv * A[n]);
      h[n] = e * h[n] + dx * Bv[n];
      y += h[n] * Cv[n];
    }
    ysp[(size_t)t * 1024] = (unsigned short)f2bf(y);
  }
}

// =================== gate: ys = (ys + xc*D) * silu(z) ===================
__global__ void gate_kernel(unsigned short* __restrict__ ys, const unsigned short* __restrict__ xc,
                            const float* __restrict__ Dp, const unsigned short* __restrict__ xz) {
  int idx = blockIdx.x * 256 + threadIdx.x;   // over B*S*(DI/8) = 524288
  int dc = (idx & 127) * 8;
  int bt = idx >> 7;
  ushort8 y8 = *(const ushort8*)(ys + (size_t)idx * 8);
  ushort8 x8 = *(const ushort8*)(xc + (size_t)idx * 8);
  ushort8 z8 = *(const ushort8*)(xz + (size_t)bt * 2048 + 1024 + dc);
  f32x4 d0 = *(const f32x4*)(Dp + dc), d1 = *(const f32x4*)(Dp + dc + 4);
  float dp[8];
  #pragma unroll
  for (int j = 0; j < 4; j++) { dp[j] = d0[j]; dp[4 + j] = d1[j]; }
  ushort8 o;
  #pragma unroll
  for (int j = 0; j < 8; j++) {
    float z = bf2f(z8[j]);
    float y = bf2f(y8[j]) + bf2f(x8[j]) * dp[j];
    o[j] = (unsigned short)f2bf(y * (z / (1.f + __expf(-z))));
  }
  *(ushort8*)(ys + (size_t)idx * 8) = o;
}

// =================== time flip for (B,S,W) bf16, W = 1<<ws, 8 elems/thread ===================
__global__ void flip_kernel(const unsigned short* __restrict__ in, unsigned short* __restrict__ out, int ws) {
  int idx = blockIdx.x * 256 + threadIdx.x;
  int c = idx & ((1 << (ws - 3)) - 1);
  int t = (idx >> (ws - 3)) & (SEQ - 1);
  int b = idx >> (ws - 3 + 11);
  ushort8 v = *(const ushort8*)(in + (((size_t)(b * SEQ + (SEQ - 1 - t))) << ws) + c * 8);
  *(ushort8*)(out + (size_t)idx * 8) = v;
}

extern "C" void kernel_launch(void* const* d_in, const int* in_sizes, int n_in,
                              void* d_out, int out_size, void* d_ws, size_t ws_size,
                              hipStream_t stream) {
  (void)in_sizes; (void)n_in; (void)out_size; (void)ws_size;
  const float* mel        = (const float*)d_in[0];
  const float* mel_w      = (const float*)d_in[1];
  const float* mel_b      = (const float*)d_in[2];
  const float* attn_in_b  = (const float*)d_in[4];
  const float* attn_out_b = (const float*)d_in[6];
  const float* ln1_g = (const float*)d_in[7];
  const float* ln1_b = (const float*)d_in[8];
  const float* ln2_g = (const float*)d_in[9];
  const float* ln2_b = (const float*)d_in[10];
  const float* bim_b = (const float*)d_in[30];
  const float* out_b = (const float*)d_in[32];

  char* wsb = (char*)d_ws;
  char* obb = (char*)d_out;

  // ---- bf16 weights in ws (byte offsets) ----
  unsigned short* w_attn_in  = (unsigned short*)(wsb + 0);          // 786432
  unsigned short* w_attn_out = (unsigned short*)(wsb + 1572864);    // 262144
  unsigned short* w_dir[2][4];
  for (int dir = 0; dir < 2; dir++) {
    size_t base = 2097152 + (size_t)dir * 3342336;
    w_dir[dir][0] = (unsigned short*)(wsb + base);                  // in_w
    w_dir[dir][1] = (unsigned short*)(wsb + base + 2097152);        // x_w
    w_dir[dir][2] = (unsigned short*)(wsb + base + 2228224);        // dt_w (bf16, unused)
    w_dir[dir][3] = (unsigned short*)(wsb + base + 2293760);        // out_w
  }
  unsigned short* w_bim = (unsigned short*)(wsb + 8781824);         // 524288
  unsigned short* w_out = (unsigned short*)(wsb + 9830400);         // 5120000

  // ---- bf16 activations in ws ----
  unsigned short* x0     = (unsigned short*)(wsb + 20971520);
  unsigned short* x1     = (unsigned short*)(wsb + 25165824);
  unsigned short* x1f    = (unsigned short*)(wsb + 29360128);
  unsigned short* attn_o = (unsigned short*)(wsb + 33554432);
  unsigned short* xc     = (unsigned short*)(wsb + 37748736);
  unsigned short* ysb    = (unsigned short*)(wsb + 46137344);
  unsigned short* yflip  = (unsigned short*)(wsb + 54525952);
  unsigned short* mout   = (unsigned short*)(wsb + 62914560);
  unsigned short* minter = (unsigned short*)(wsb + 71303168);
  unsigned short* x2     = (unsigned short*)(wsb + 75497472);
  float*          dbl    = (float*)(wsb + 79691776);

  // ---- d_out scratch (dead until final GEMM overwrites all) ----
  unsigned short* qkv = (unsigned short*)(obb + 0);
  unsigned short* xz  = (unsigned short*)(obb + 12582912);
  float* dtf  = (float*)(obb + 46137344);
  float* hend = (float*)(obb + 62914560);
  float* apr  = (float*)(obb + 79691776);
  float* h0s  = (float*)(obb + 96468992);
  float* ob   = (float*)d_out;

  dim3 blk(256);

  // 0. convert weights to bf16
  {
    CvtArgs a;
    const float* srcs[12] = { (const float*)d_in[3], (const float*)d_in[5],
      (const float*)d_in[11], (const float*)d_in[14], (const float*)d_in[15], (const float*)d_in[19],
      (const float*)d_in[20], (const float*)d_in[23], (const float*)d_in[24], (const float*)d_in[28],
      (const float*)d_in[29], (const float*)d_in[31] };
    unsigned short* dsts[12] = { w_attn_in, w_attn_out,
      w_dir[0][0], w_dir[0][1], w_dir[0][2], w_dir[0][3],
      w_dir[1][0], w_dir[1][1], w_dir[1][2], w_dir[1][3],
      w_bim, w_out };
    int ns[12] = { 786432, 262144, 1048576, 65536, 32768, 524288,
                   1048576, 65536, 32768, 524288, 524288, 5120000 };
    for (int i = 0; i < 12; i++) { a.s[i] = srcs[i]; a.d[i] = dsts[i]; a.n[i] = ns[i]; }
    cvt_many<<<dim3(2500, 12), blk, 0, stream>>>(a);
  }

  // 1. x0 = mel @ mel_w.T + mel_b (f32-in path, K=80)
  gemm_f32in<1, 1><<<dim3(4, 32), blk, 0, stream>>>(mel, mel_w, x0, mel_b, 4096, 512, 80, 80, 80, 512);
  // 2. qkv = x0 @ attn_in_w.T + b
  gemm_bf16<1, 1><<<dim3(12 * 32), blk, 0, stream>>>(x0, w_attn_in, qkv, attn_in_b, 4096, 1536, 512, 512, 512, 1536, 12);
  // 3. attention
  attn_kernel<<<4096, blk, 0, stream>>>(qkv, attn_o);
  // 4. attnproj -> qkv slot
  gemm_bf16<1, 1><<<dim3(4 * 32), blk, 0, stream>>>(attn_o, w_attn_out, qkv, attn_out_b, 4096, 512, 512, 512, 512, 512, 4);
  // 5. x1 = LN(x0 + attnproj)
  ln_res_kernel<<<1024, blk, 0, stream>>>(x0, qkv, ln1_g, ln1_b, x1);
  // 6. x1f = flip(x1)
  flip_kernel<<<1024, blk, 0, stream>>>(x1, x1f, 9);

  for (int dir = 0; dir < 2; dir++) {
    int base = 11 + dir * 9;
    const float* conv_w  = (const float*)d_in[base + 1];
    const float* conv_b  = (const float*)d_in[base + 2];
    const float* dt_w    = (const float*)d_in[base + 4];
    const float* dt_bias = (const float*)d_in[base + 5];
    const float* A_log   = (const float*)d_in[base + 6];
    const float* Dp      = (const float*)d_in[base + 7];
    const unsigned short* xin = dir ? x1f : x1;
    // xz = xin @ in_w.T
    gemm_bf16<0, 1><<<dim3(16 * 32), blk, 0, stream>>>(xin, w_dir[dir][0], xz, nullptr, 4096, 2048, 512, 512, 512, 2048, 16);
    // conv + silu
    conv_silu_kernel<<<2048, blk, 0, stream>>>(xz, conv_w, conv_b, xc);
    // dbl = xc @ x_w.T (f32 out for scan numerics)
    gemm_bf16<0, 0><<<dim3(1 * 32), blk, 0, stream>>>(xc, w_dir[dir][1], dbl, nullptr, 4096, 64, 1024, 1024, 1024, 64, 1);
    // dt = softplus(dbl[:, :32] @ dt_w.T + dt_b)  (f32-in path, K=32)
    gemm_f32in<2, 0><<<dim3(8, 32), blk, 0, stream>>>(dbl, dt_w, dtf, dt_bias, 4096, 1024, 32, 64, 32, 1024);
    // selective scan
    scan_p1<<<1024, blk, 0, stream>>>(dtf, xc, dbl, A_log, hend, apr);
    scan_p2<<<128, blk, 0, stream>>>(hend, apr, h0s);
    scan_p3<<<1024, blk, 0, stream>>>(dtf, xc, dbl, A_log, h0s, ysb);
    // gate
    gate_kernel<<<2048, blk, 0, stream>>>(ysb, xc, Dp, xz);
    const unsigned short* yin = ysb;
    if (dir) { flip_kernel<<<2048, blk, 0, stream>>>(ysb, yflip, 10); yin = yflip; }
    // mamba out proj -> mout cols [dir*512, +512)
    gemm_bf16<0, 1><<<dim3(4 * 32), blk, 0, stream>>>(yin, w_dir[dir][3], mout + dir * 512, nullptr, 4096, 512, 1024, 1024, 1024, 1024, 4);
  }

  // m = mout @ bim_w.T + bim_b
  gemm_bf16<1, 1><<<dim3(4 * 32), blk, 0, stream>>>(mout, w_bim, minter, bim_b, 4096, 512, 1024, 1024, 1024, 512, 4);
  // x2 = LN(x1 + m)
  ln_res_kernel<<<1024, blk, 0, stream>>>(x1, minter, ln2_g, ln2_b, x2);
  // logits = x2 @ out_w.T + out_b  (overwrites all of d_out; nontemporal f32 stores)
  gemm_bf16<1, 0><<<dim3(79 * 32), blk, 0, stream>>>(x2, w_out, ob, out_b, 4096, 10000, 512, 512, 512, 10000, 79);
}

// Round 6
// 523.721 us; speedup vs baseline: 5.1459x; 1.4077x over previous
//
#include <hip/hip_runtime.h>
#include <hip/hip_bf16.h>
#include <math.h>

// Model dims
#define SEQ 2048
// B=2, DM=512, DI=1024, N=16, K=4, R=32, H=8, V=10000

typedef __attribute__((ext_vector_type(4))) float f32x4;
typedef __attribute__((ext_vector_type(8))) short bf16x8s;
typedef __attribute__((ext_vector_type(4))) short short4v;
typedef __attribute__((ext_vector_type(8))) unsigned short ushort8;
typedef __attribute__((ext_vector_type(2))) unsigned int uint2v;

__device__ __forceinline__ short f2bf(float f) {
  union { float f; unsigned u; } c; c.f = f;
  unsigned u = c.u;
  u += 0x7fffu + ((u >> 16) & 1u);   // RNE
  return (short)(u >> 16);
}
__device__ __forceinline__ float bf2f(unsigned short u) {
  union { unsigned u; float f; } c; c.u = ((unsigned)u) << 16; return c.f;
}

__device__ __forceinline__ void lds_load16(const void* g, void* s) {
  __builtin_amdgcn_global_load_lds(
      (const __attribute__((address_space(1))) void*)g,
      (__attribute__((address_space(3))) void*)s, 16, 0, 0);
}

// =================== bf16 MFMA GEMM: C[M,N] = A[M,K] @ B[N,K]^T ===================
// A,B bf16 (K%64==0, lda/ldb %8==0, M%128==0, N%4==0).
// EPI: 0 none, 1 +bias. OUTBF: 1 -> bf16 C, 0 -> f32 C.
// T3-min double-buffered pipeline: STAGE(t+1) issued before compute(t), one
// raw vmcnt(0)+s_barrier per K-tile. XOR-chunk swizzled LDS (pre-swizzled
// global source, linear LDS dest). Epilogue staged through LDS for coalesced
// dwordx4/dwordx2 stores; nontemporal for the f32 final-logits case.
template<int EPI, int OUTBF>
__launch_bounds__(256)
__global__ void gemm_bf16(const unsigned short* __restrict__ A, const unsigned short* __restrict__ B,
                          void* __restrict__ Cv, const float* __restrict__ bias,
                          int M, int N, int K, int lda, int ldb, int ldc, int nbn) {
  __shared__ char smem[67584];   // 2x(16KB A + 16KB B) dbuf; 128x132 f32 epilogue tile

  // bijective XCD chunk swizzle (m204), bn-fastest within chunk (A L2-resident)
  const int nwg = gridDim.x;
  const int g = blockIdx.x;
  const int q = nwg >> 3, r = nwg & 7;
  const int xcd = g & 7, cidx = g >> 3;
  const int wg = (xcd < r ? xcd * (q + 1) : r * (q + 1) + (xcd - r) * q) + cidx;
  const int bm = wg / nbn, bn = wg % nbn;
  const int m0 = bm * 128, n0 = bn * 128;

  const int tid = threadIdx.x, lane = tid & 63, wave = tid >> 6;
  const int wr = (wave >> 1) * 64, wc = (wave & 1) * 64;
  const int fr = lane & 15, fq = lane >> 4;
  const int srow = tid >> 3;   // 0..31
  const int scc  = tid & 7;    // column chunk 0..7 (8 bf16 each)

  f32x4 acc[4][4] = {};
  const int nkt = K >> 6;

  auto STAGE = [&](int buf, int kt) {
    const int k0 = kt << 6;
    unsigned short* sAb = (unsigned short*)(smem + buf * 32768);
    unsigned short* sBb = (unsigned short*)(smem + buf * 32768 + 16384);
    #pragma unroll
    for (int j = 0; j < 4; j++) {
      int lrow = j * 32 + srow;
      int gcol = (scc ^ (lrow & 7)) * 8;
      lds_load16(A + (size_t)(m0 + lrow) * lda + k0 + gcol, &sAb[(j * 256 + wave * 64) * 8]);
    }
    #pragma unroll
    for (int j = 0; j < 4; j++) {
      int lrow = j * 32 + srow;
      int gcol = (scc ^ (lrow & 7)) * 8;
      int grow = n0 + lrow; if (grow >= N) grow = N - 1;   // clamp; junk never stored
      lds_load16(B + (size_t)grow * ldb + k0 + gcol, &sBb[(j * 256 + wave * 64) * 8]);
    }
  };

  STAGE(0, 0);
  asm volatile("s_waitcnt vmcnt(0)" ::: "memory");
  __builtin_amdgcn_s_barrier();

  int cur = 0;
  for (int kt = 0; kt < nkt; kt++) {
    if (kt + 1 < nkt) STAGE(cur ^ 1, kt + 1);   // issue next-tile loads first
    const unsigned short* As = (const unsigned short*)(smem + cur * 32768);
    const unsigned short* Bs = (const unsigned short*)(smem + cur * 32768 + 16384);
    #pragma unroll
    for (int ks = 0; ks < 2; ks++) {
      bf16x8s af[4], bfv[4];
      #pragma unroll
      for (int i = 0; i < 4; i++) {
        int ra = wr + i * 16 + fr;
        af[i] = *(const bf16x8s*)&As[ra * 64 + (((ks << 2) + fq) ^ (ra & 7)) * 8];
      }
      #pragma unroll
      for (int i = 0; i < 4; i++) {
        int rb = wc + i * 16 + fr;
        bfv[i] = *(const bf16x8s*)&Bs[rb * 64 + (((ks << 2) + fq) ^ (rb & 7)) * 8];
      }
      #pragma unroll
      for (int i = 0; i < 4; i++)
        #pragma unroll
        for (int j = 0; j < 4; j++)
          acc[i][j] = __builtin_amdgcn_mfma_f32_16x16x32_bf16(af[i], bfv[j], acc[i][j], 0, 0, 0);
    }
    asm volatile("s_waitcnt vmcnt(0)" ::: "memory");  // this wave's stage loads landed
    __builtin_amdgcn_s_barrier();                     // all waves' loads landed / reads done
    cur ^= 1;
  }

  // ---- epilogue: stage f32 tile in LDS, write coalesced ----
  float* ct = (float*)smem;   // [128][132]
  #pragma unroll
  for (int i = 0; i < 4; i++)
    #pragma unroll
    for (int j = 0; j < 4; j++)
      #pragma unroll
      for (int r4 = 0; r4 < 4; r4++)
        ct[(wr + i * 16 + fq * 4 + r4) * 132 + wc + j * 16 + fr] = acc[i][j][r4];
  __syncthreads();
  const int half = lane >> 5;
  const int col4 = (lane & 31) * 4;
  const int cn = n0 + col4;
  #pragma unroll
  for (int it = 0; it < 16; it++) {
    int row = wave * 32 + it * 2 + half;
    f32x4 v = *(const f32x4*)&ct[row * 132 + col4];
    if (cn < N) {
      if (EPI >= 1) {
        f32x4 b4 = *(const f32x4*)&bias[cn];
        #pragma unroll
        for (int j = 0; j < 4; j++) v[j] += b4[j];
      }
      if (OUTBF) {
        unsigned short h0 = (unsigned short)f2bf(v[0]), h1 = (unsigned short)f2bf(v[1]);
        unsigned short h2 = (unsigned short)f2bf(v[2]), h3 = (unsigned short)f2bf(v[3]);
        uint2v o = { (unsigned)h0 | ((unsigned)h1 << 16), (unsigned)h2 | ((unsigned)h3 << 16) };
        *(uint2v*)((unsigned short*)Cv + (size_t)(m0 + row) * ldc + cn) = o;
      } else {
        float* dst = (float*)Cv + (size_t)(m0 + row) * ldc + cn;
        if (EPI == 1) __builtin_nontemporal_store(v, (f32x4*)dst);  // final logits: stream past L2
        else          *(f32x4*)dst = v;
      }
    }
  }
}

// =================== f32-input GEMM (mel K=80) ===================
#define LDT 40
template<int EPI, int OUTBF>
__launch_bounds__(256)
__global__ void gemm_f32in(const float* __restrict__ A, const float* __restrict__ B,
                           void* __restrict__ Cv, const float* __restrict__ bias,
                           int M, int N, int K, int lda, int ldb, int ldc) {
  __shared__ short As[128 * LDT];
  __shared__ short Bs[128 * LDT];
  const int tid  = threadIdx.x;
  const int lane = tid & 63;
  const int wave = tid >> 6;
  const int m0 = blockIdx.y * 128;
  const int n0 = blockIdx.x * 128;
  const int wr = (wave >> 1) * 64;
  const int wc = (wave & 1) * 64;
  const int srow = tid >> 3;
  const int scol = (tid & 7) * 4;
  const int fr = lane & 15;
  const int fq = lane >> 4;

  f32x4 acc[4][4] = {};

  for (int k0 = 0; k0 < K; k0 += 32) {
    const bool kok = (k0 + scol) < K;
    #pragma unroll
    for (int rr = 0; rr < 128; rr += 32) {
      int r = srow + rr;
      f32x4 v = {0.f, 0.f, 0.f, 0.f};
      if (kok) v = *(const f32x4*)(A + (size_t)(m0 + r) * lda + k0 + scol);
      short4v s = { f2bf(v[0]), f2bf(v[1]), f2bf(v[2]), f2bf(v[3]) };
      *(short4v*)(&As[r * LDT + scol]) = s;
    }
    #pragma unroll
    for (int rr = 0; rr < 128; rr += 32) {
      int r = srow + rr;
      f32x4 v = {0.f, 0.f, 0.f, 0.f};
      if (kok && (n0 + r) < N) v = *(const f32x4*)(B + (size_t)(n0 + r) * ldb + k0 + scol);
      short4v s = { f2bf(v[0]), f2bf(v[1]), f2bf(v[2]), f2bf(v[3]) };
      *(short4v*)(&Bs[r * LDT + scol]) = s;
    }
    __syncthreads();
    bf16x8s af[4], bfv[4];
    #pragma unroll
    for (int i = 0; i < 4; i++)
      af[i]  = *(const bf16x8s*)(&As[(wr + i * 16 + fr) * LDT + fq * 8]);
    #pragma unroll
    for (int i = 0; i < 4; i++)
      bfv[i] = *(const bf16x8s*)(&Bs[(wc + i * 16 + fr) * LDT + fq * 8]);
    #pragma unroll
    for (int i = 0; i < 4; i++)
      #pragma unroll
      for (int j = 0; j < 4; j++)
        acc[i][j] = __builtin_amdgcn_mfma_f32_16x16x32_bf16(af[i], bfv[j], acc[i][j], 0, 0, 0);
    __syncthreads();
  }

  #pragma unroll
  for (int j = 0; j < 4; j++) {
    int cn = n0 + wc + j * 16 + fr;
    if (cn < N) {
      float bv = 0.f;
      if (EPI >= 1) bv = bias[cn];
      #pragma unroll
      for (int i = 0; i < 4; i++) {
        #pragma unroll
        for (int r4 = 0; r4 < 4; r4++) {
          int cm = m0 + wr + i * 16 + fq * 4 + r4;
          float val = acc[i][j][r4] + bv;
          if (OUTBF) ((unsigned short*)Cv)[(size_t)cm * ldc + cn] = (unsigned short)f2bf(val);
          else       ((float*)Cv)[(size_t)cm * ldc + cn] = val;
        }
      }
    }
  }
}

// =================== weight f32 -> bf16 conversion (12 tensors, one launch) ===================
struct CvtArgs { const float* s[12]; unsigned short* d[12]; int n[12]; };
__global__ void cvt_many(CvtArgs a) {
  int y = blockIdx.y;
  int i = (blockIdx.x * 256 + threadIdx.x) * 8;
  if (i >= a.n[y]) return;
  const float* s = a.s[y];
  f32x4 v0 = *(const f32x4*)(s + i);
  f32x4 v1 = *(const f32x4*)(s + i + 4);
  ushort8 o = { (unsigned short)f2bf(v0[0]), (unsigned short)f2bf(v0[1]),
                (unsigned short)f2bf(v0[2]), (unsigned short)f2bf(v0[3]),
                (unsigned short)f2bf(v1[0]), (unsigned short)f2bf(v1[1]),
                (unsigned short)f2bf(v1[2]), (unsigned short)f2bf(v1[3]) };
  *(ushort8*)(a.d[y] + i) = o;
}

// =================== tiny attention (L=2) over bf16 qkv ===================
__global__ void attn_kernel(const unsigned short* __restrict__ qkv, unsigned short* __restrict__ o) {
  int gw = blockIdx.x * 4 + (threadIdx.x >> 6);
  int lane = threadIdx.x & 63;
  int n = gw >> 3, h = gw & 7;
  size_t r0 = (size_t)n * 1536 + h * 64 + lane;
  size_t r1 = (size_t)(SEQ + n) * 1536 + h * 64 + lane;
  float q0 = bf2f(qkv[r0]), k0 = bf2f(qkv[r0 + 512]), v0 = bf2f(qkv[r0 + 1024]);
  float q1 = bf2f(qkv[r1]), k1 = bf2f(qkv[r1 + 512]), v1 = bf2f(qkv[r1 + 1024]);
  float s00 = q0 * k0, s01 = q0 * k1, s10 = q1 * k0, s11 = q1 * k1;
  #pragma unroll
  for (int off = 32; off > 0; off >>= 1) {
    s00 += __shfl_xor(s00, off);
    s01 += __shfl_xor(s01, off);
    s10 += __shfl_xor(s10, off);
    s11 += __shfl_xor(s11, off);
  }
  const float sc = 0.125f;
  s00 *= sc; s01 *= sc; s10 *= sc; s11 *= sc;
  float mx0 = fmaxf(s00, s01), mx1 = fmaxf(s10, s11);
  float e00 = __expf(s00 - mx0), e01 = __expf(s01 - mx0);
  float e10 = __expf(s10 - mx1), e11 = __expf(s11 - mx1);
  float i0 = 1.f / (e00 + e01), i1 = 1.f / (e10 + e11);
  size_t w0 = (size_t)n * 512 + h * 64 + lane;
  size_t w1 = (size_t)(SEQ + n) * 512 + h * 64 + lane;
  o[w0] = (unsigned short)f2bf((e00 * v0 + e01 * v1) * i0);
  o[w1] = (unsigned short)f2bf((e10 * v0 + e11 * v1) * i1);
}

// =================== LN(a+b) over 512, bf16 in/out ===================
__global__ void ln_res_kernel(const unsigned short* __restrict__ a, const unsigned short* __restrict__ b,
                              const float* __restrict__ g, const float* __restrict__ be,
                              unsigned short* __restrict__ out) {
  int row = blockIdx.x * 4 + (threadIdx.x >> 6);
  int lane = threadIdx.x & 63;
  ushort8 va = *(const ushort8*)(a + (size_t)row * 512 + lane * 8);
  ushort8 vb = *(const ushort8*)(b + (size_t)row * 512 + lane * 8);
  float v[8];
  #pragma unroll
  for (int j = 0; j < 8; j++) v[j] = bf2f(va[j]) + bf2f(vb[j]);
  float s = 0.f, s2 = 0.f;
  #pragma unroll
  for (int j = 0; j < 8; j++) { s += v[j]; s2 += v[j] * v[j]; }
  #pragma unroll
  for (int off = 32; off > 0; off >>= 1) { s += __shfl_xor(s, off); s2 += __shfl_xor(s2, off); }
  float mu = s * (1.f / 512.f);
  float var = s2 * (1.f / 512.f) - mu * mu;
  float rs = rsqrtf(var + 1e-5f);
  const float* pg = g + lane * 8;
  const float* pe = be + lane * 8;
  ushort8 o;
  #pragma unroll
  for (int j = 0; j < 8; j++) o[j] = (unsigned short)f2bf((v[j] - mu) * rs * pg[j] + pe[j]);
  *(ushort8*)(out + (size_t)row * 512 + lane * 8) = o;
}

// =================== depthwise causal conv(K=4)+silu, bf16, 8 d per thread ===================
__global__ void conv_silu_kernel(const unsigned short* __restrict__ xz, const float* __restrict__ w,
                                 const float* __restrict__ cb, unsigned short* __restrict__ xc) {
  int idx = blockIdx.x * 256 + threadIdx.x;     // over B*S*(DI/8) = 524288
  int dc = (idx & 127) * 8;
  int t  = (idx >> 7) & (SEQ - 1);
  int b  = idx >> 18;
  f32x4 wv[8];
  #pragma unroll
  for (int j = 0; j < 8; j++) wv[j] = *(const f32x4*)(w + (dc + j) * 4);
  float acc[8];
  f32x4 cb0 = *(const f32x4*)(cb + dc), cb1 = *(const f32x4*)(cb + dc + 4);
  #pragma unroll
  for (int j = 0; j < 4; j++) { acc[j] = cb0[j]; acc[4 + j] = cb1[j]; }
  const unsigned short* base = xz + ((size_t)b * SEQ) * 2048 + dc;
  #pragma unroll
  for (int k = 0; k < 4; k++) {
    int tt = t - 3 + k;
    if (tt >= 0) {
      ushort8 xv = *(const ushort8*)(base + (size_t)tt * 2048);
      #pragma unroll
      for (int j = 0; j < 8; j++) acc[j] += wv[j][k] * bf2f(xv[j]);
    }
  }
  ushort8 o;
  #pragma unroll
  for (int j = 0; j < 8; j++) {
    float v = acc[j];
    o[j] = (unsigned short)f2bf(v / (1.f + __expf(-v)));
  }
  *(ushort8*)(xc + (size_t)idx * 8) = o;
}

// =================== chunked selective scan (dt inlined, gate+flip fused) ===================
#define CL 32
#define NC 64

__device__ __forceinline__ float dt_inline(const float* __restrict__ dr,
                                           const float* __restrict__ dtw, float db) {
  float acc = db;
  #pragma unroll
  for (int q = 0; q < 8; q++) {
    f32x4 v = *(const f32x4*)(dr + q * 4);
    acc += v[0] * dtw[q * 4] + v[1] * dtw[q * 4 + 1] + v[2] * dtw[q * 4 + 2] + v[3] * dtw[q * 4 + 3];
  }
  // softplus
  return fmaxf(acc, 0.f) + log1pf(__expf(-fabsf(acc)));
}

__global__ void scan_p1(const unsigned short* __restrict__ xc, const float* __restrict__ dbl,
                        const float* __restrict__ A_log, const float* __restrict__ dt_w,
                        const float* __restrict__ dt_b,
                        float* __restrict__ hend, float* __restrict__ aprod) {
  int tid = blockIdx.x * 256 + threadIdx.x;   // B*NC*DI = 131072
  int d = tid & 1023;
  int c = (tid >> 10) & (NC - 1);
  int b = tid >> 16;
  float A[16];
  #pragma unroll
  for (int q = 0; q < 4; q++) {
    f32x4 v = *(const f32x4*)(A_log + d * 16 + q * 4);
    #pragma unroll
    for (int j = 0; j < 4; j++) A[q * 4 + j] = -__expf(v[j]);
  }
  float dtw[32];
  #pragma unroll
  for (int q = 0; q < 8; q++) {
    f32x4 v = *(const f32x4*)(dt_w + d * 32 + q * 4);
    #pragma unroll
    for (int j = 0; j < 4; j++) dtw[q * 4 + j] = v[j];
  }
  const float db = dt_b[d];
  float h[16] = {};
  float ap[16];
  #pragma unroll
  for (int n = 0; n < 16; n++) ap[n] = 1.f;
  const unsigned short* xcp = xc + ((size_t)b * SEQ) * 1024 + d;
  const float* dbp = dbl + ((size_t)b * SEQ) * 64;
  const int t0 = c * CL;
  for (int t = t0; t < t0 + CL; t++) {
    const float* dr = dbp + (size_t)t * 64;
    float dtv = dt_inline(dr, dtw, db);
    float dx = dtv * bf2f(xcp[(size_t)t * 1024]);
    float Bv[16];
    #pragma unroll
    for (int q = 0; q < 4; q++) {
      f32x4 v = *(const f32x4*)(dr + 32 + q * 4);
      #pragma unroll
      for (int j = 0; j < 4; j++) Bv[q * 4 + j] = v[j];
    }
    #pragma unroll
    for (int n = 0; n < 16; n++) {
      float e = __expf(dtv * A[n]);
      h[n] = e * h[n] + dx * Bv[n];
      ap[n] *= e;
    }
  }
  size_t o = ((size_t)((b * NC + c) * 1024 + d)) * 16;
  #pragma unroll
  for (int q = 0; q < 4; q++) {
    f32x4 vh = { h[q * 4], h[q * 4 + 1], h[q * 4 + 2], h[q * 4 + 3] };
    f32x4 va = { ap[q * 4], ap[q * 4 + 1], ap[q * 4 + 2], ap[q * 4 + 3] };
    *(f32x4*)(hend + o + q * 4) = vh;
    *(f32x4*)(aprod + o + q * 4) = va;
  }
}

__global__ void scan_p2(const float* __restrict__ hend, const float* __restrict__ aprod,
                        float* __restrict__ h0) {
  int tid = blockIdx.x * 256 + threadIdx.x;   // B*DI*N = 32768
  int n = tid & 15;
  int d = (tid >> 4) & 1023;
  int b = tid >> 14;
  float h = 0.f;
  for (int c = 0; c < NC; c++) {
    size_t idx = ((size_t)((b * NC + c) * 1024 + d)) * 16 + n;
    h0[idx] = h;
    h = aprod[idx] * h + hend[idx];
  }
}

// p3: recompute with h0, emit gated output, write (optionally time-flipped)
__global__ void scan_p3(const unsigned short* __restrict__ xc, const float* __restrict__ dbl,
                        const float* __restrict__ A_log, const float* __restrict__ dt_w,
                        const float* __restrict__ dt_b, const float* __restrict__ h0,
                        const unsigned short* __restrict__ xz, const float* __restrict__ Dp,
                        unsigned short* __restrict__ ys, int rev) {
  int tid = blockIdx.x * 256 + threadIdx.x;   // B*NC*DI = 131072
  int d = tid & 1023;
  int c = (tid >> 10) & (NC - 1);
  int b = tid >> 16;
  float A[16];
  #pragma unroll
  for (int q = 0; q < 4; q++) {
    f32x4 v = *(const f32x4*)(A_log + d * 16 + q * 4);
    #pragma unroll
    for (int j = 0; j < 4; j++) A[q * 4 + j] = -__expf(v[j]);
  }
  float dtw[32];
  #pragma unroll
  for (int q = 0; q < 8; q++) {
    f32x4 v = *(const f32x4*)(dt_w + d * 32 + q * 4);
    #pragma unroll
    for (int j = 0; j < 4; j++) dtw[q * 4 + j] = v[j];
  }
  const float db = dt_b[d];
  const float Dv = Dp[d];
  float h[16];
  size_t o = ((size_t)((b * NC + c) * 1024 + d)) * 16;
  #pragma unroll
  for (int q = 0; q < 4; q++) {
    f32x4 v = *(const f32x4*)(h0 + o + q * 4);
    #pragma unroll
    for (int j = 0; j < 4; j++) h[q * 4 + j] = v[j];
  }
  const unsigned short* xcp = xc + ((size_t)b * SEQ) * 1024 + d;
  const unsigned short* zp  = xz + ((size_t)b * SEQ) * 2048 + 1024 + d;
  const float* dbp = dbl + ((size_t)b * SEQ) * 64;
  unsigned short* ysp = ys + ((size_t)b * SEQ) * 1024 + d;
  const int t0 = c * CL;
  for (int t = t0; t < t0 + CL; t++) {
    const float* dr = dbp + (size_t)t * 64;
    float dtv = dt_inline(dr, dtw, db);
    float xcv = bf2f(xcp[(size_t)t * 1024]);
    float dx = dtv * xcv;
    float Bv[16], Cv[16];
    #pragma unroll
    for (int q = 0; q < 4; q++) {
      f32x4 v = *(const f32x4*)(dr + 32 + q * 4);
      f32x4 w = *(const f32x4*)(dr + 48 + q * 4);
      #pragma unroll
      for (int j = 0; j < 4; j++) { Bv[q * 4 + j] = v[j]; Cv[q * 4 + j] = w[j]; }
    }
    float y = 0.f;
    #pragma unroll
    for (int n = 0; n < 16; n++) {
      float e = __expf(dtv * A[n]);
      h[n] = e * h[n] + dx * Bv[n];
      y += h[n] * Cv[n];
    }
    // gate: (y + xc*D) * silu(z)
    float z = bf2f(zp[(size_t)t * 2048]);
    float out = (y + xcv * Dv) * (z / (1.f + __expf(-z)));
    int tw = rev ? (SEQ - 1 - t) : t;
    ysp[(size_t)tw * 1024] = (unsigned short)f2bf(out);
  }
}

// =================== time flip for (B,S,W) bf16, W = 1<<ws, 8 elems/thread ===================
__global__ void flip_kernel(const unsigned short* __restrict__ in, unsigned short* __restrict__ out, int ws) {
  int idx = blockIdx.x * 256 + threadIdx.x;
  int c = idx & ((1 << (ws - 3)) - 1);
  int t = (idx >> (ws - 3)) & (SEQ - 1);
  int b = idx >> (ws - 3 + 11);
  ushort8 v = *(const ushort8*)(in + (((size_t)(b * SEQ + (SEQ - 1 - t))) << ws) + c * 8);
  *(ushort8*)(out + (size_t)idx * 8) = v;
}

extern "C" void kernel_launch(void* const* d_in, const int* in_sizes, int n_in,
                              void* d_out, int out_size, void* d_ws, size_t ws_size,
                              hipStream_t stream) {
  (void)in_sizes; (void)n_in; (void)out_size; (void)ws_size;
  const float* mel        = (const float*)d_in[0];
  const float* mel_w      = (const float*)d_in[1];
  const float* mel_b      = (const float*)d_in[2];
  const float* attn_in_b  = (const float*)d_in[4];
  const float* attn_out_b = (const float*)d_in[6];
  const float* ln1_g = (const float*)d_in[7];
  const float* ln1_b = (const float*)d_in[8];
  const float* ln2_g = (const float*)d_in[9];
  const float* ln2_b = (const float*)d_in[10];
  const float* bim_b = (const float*)d_in[30];
  const float* out_b = (const float*)d_in[32];

  char* wsb = (char*)d_ws;
  char* obb = (char*)d_out;

  // ---- bf16 weights in ws (byte offsets) ----
  unsigned short* w_attn_in  = (unsigned short*)(wsb + 0);          // 786432
  unsigned short* w_attn_out = (unsigned short*)(wsb + 1572864);    // 262144
  unsigned short* w_dir[2][4];
  for (int dir = 0; dir < 2; dir++) {
    size_t base = 2097152 + (size_t)dir * 3342336;
    w_dir[dir][0] = (unsigned short*)(wsb + base);                  // in_w
    w_dir[dir][1] = (unsigned short*)(wsb + base + 2097152);        // x_w
    w_dir[dir][2] = (unsigned short*)(wsb + base + 2228224);        // (spare)
    w_dir[dir][3] = (unsigned short*)(wsb + base + 2293760);        // out_w
  }
  unsigned short* w_bim = (unsigned short*)(wsb + 8781824);         // 524288
  unsigned short* w_out = (unsigned short*)(wsb + 9830400);         // 5120000

  // ---- bf16 activations in ws ----
  unsigned short* x0     = (unsigned short*)(wsb + 20971520);
  unsigned short* x1     = (unsigned short*)(wsb + 25165824);
  unsigned short* x1f    = (unsigned short*)(wsb + 29360128);
  unsigned short* attn_o = (unsigned short*)(wsb + 33554432);
  unsigned short* xc     = (unsigned short*)(wsb + 37748736);
  unsigned short* ysb    = (unsigned short*)(wsb + 46137344);
  unsigned short* mout   = (unsigned short*)(wsb + 62914560);
  unsigned short* minter = (unsigned short*)(wsb + 71303168);
  unsigned short* x2     = (unsigned short*)(wsb + 75497472);
  float*          dbl    = (float*)(wsb + 79691776);

  // ---- d_out scratch (dead until final GEMM overwrites all) ----
  unsigned short* qkv = (unsigned short*)(obb + 0);
  unsigned short* xz  = (unsigned short*)(obb + 12582912);
  float* hend = (float*)(obb + 62914560);     // 8.39 MB (NC=64)
  float* apr  = (float*)(obb + 79691776);     // 8.39 MB
  float* h0s  = (float*)(obb + 96468992);     // 8.39 MB
  float* ob   = (float*)d_out;

  dim3 blk(256);

  // 0. convert weights to bf16
  {
    CvtArgs a;
    const float* srcs[12] = { (const float*)d_in[3], (const float*)d_in[5],
      (const float*)d_in[11], (const float*)d_in[14], (const float*)d_in[15], (const float*)d_in[19],
      (const float*)d_in[20], (const float*)d_in[23], (const float*)d_in[24], (const float*)d_in[28],
      (const float*)d_in[29], (const float*)d_in[31] };
    unsigned short* dsts[12] = { w_attn_in, w_attn_out,
      w_dir[0][0], w_dir[0][1], w_dir[0][2], w_dir[0][3],
      w_dir[1][0], w_dir[1][1], w_dir[1][2], w_dir[1][3],
      w_bim, w_out };
    int ns[12] = { 786432, 262144, 1048576, 65536, 32768, 524288,
                   1048576, 65536, 32768, 524288, 524288, 5120000 };
    for (int i = 0; i < 12; i++) { a.s[i] = srcs[i]; a.d[i] = dsts[i]; a.n[i] = ns[i]; }
    cvt_many<<<dim3(2500, 12), blk, 0, stream>>>(a);
  }

  // 1. x0 = mel @ mel_w.T + mel_b (f32-in path, K=80)
  gemm_f32in<1, 1><<<dim3(4, 32), blk, 0, stream>>>(mel, mel_w, x0, mel_b, 4096, 512, 80, 80, 80, 512);
  // 2. qkv = x0 @ attn_in_w.T + b
  gemm_bf16<1, 1><<<dim3(12 * 32), blk, 0, stream>>>(x0, w_attn_in, qkv, attn_in_b, 4096, 1536, 512, 512, 512, 1536, 12);
  // 3. attention
  attn_kernel<<<4096, blk, 0, stream>>>(qkv, attn_o);
  // 4. attnproj -> qkv slot
  gemm_bf16<1, 1><<<dim3(4 * 32), blk, 0, stream>>>(attn_o, w_attn_out, qkv, attn_out_b, 4096, 512, 512, 512, 512, 512, 4);
  // 5. x1 = LN(x0 + attnproj)
  ln_res_kernel<<<1024, blk, 0, stream>>>(x0, qkv, ln1_g, ln1_b, x1);
  // 6. x1f = flip(x1)
  flip_kernel<<<1024, blk, 0, stream>>>(x1, x1f, 9);

  for (int dir = 0; dir < 2; dir++) {
    int base = 11 + dir * 9;
    const float* conv_w  = (const float*)d_in[base + 1];
    const float* conv_b  = (const float*)d_in[base + 2];
    const float* dt_w    = (const float*)d_in[base + 4];
    const float* dt_bias = (const float*)d_in[base + 5];
    const float* A_log   = (const float*)d_in[base + 6];
    const float* Dp      = (const float*)d_in[base + 7];
    const unsigned short* xin = dir ? x1f : x1;
    // xz = xin @ in_w.T
    gemm_bf16<0, 1><<<dim3(16 * 32), blk, 0, stream>>>(xin, w_dir[dir][0], xz, nullptr, 4096, 2048, 512, 512, 512, 2048, 16);
    // conv + silu
    conv_silu_kernel<<<2048, blk, 0, stream>>>(xz, conv_w, conv_b, xc);
    // dbl = xc @ x_w.T (f32 out for scan numerics)
    gemm_bf16<0, 0><<<dim3(1 * 32), blk, 0, stream>>>(xc, w_dir[dir][1], dbl, nullptr, 4096, 64, 1024, 1024, 1024, 64, 1);
    // selective scan (dt inlined; gate + output-flip fused into p3)
    scan_p1<<<512, blk, 0, stream>>>(xc, dbl, A_log, dt_w, dt_bias, hend, apr);
    scan_p2<<<128, blk, 0, stream>>>(hend, apr, h0s);
    scan_p3<<<512, blk, 0, stream>>>(xc, dbl, A_log, dt_w, dt_bias, h0s, xz, Dp, ysb, dir);
    // mamba out proj -> mout cols [dir*512, +512)
    gemm_bf16<0, 1><<<dim3(4 * 32), blk, 0, stream>>>(ysb, w_dir[dir][3], mout + dir * 512, nullptr, 4096, 512, 1024, 1024, 1024, 1024, 4);
  }

  // m = mout @ bim_w.T + bim_b
  gemm_bf16<1, 1><<<dim3(4 * 32), blk, 0, stream>>>(mout, w_bim, minter, bim_b, 4096, 512, 1024, 1024, 1024, 512, 4);
  // x2 = LN(x1 + m)
  ln_res_kernel<<<1024, blk, 0, stream>>>(x1, minter, ln2_g, ln2_b, x2);
  // logits = x2 @ out_w.T + out_b  (overwrites all of d_out; nontemporal f32 stores)
  gemm_bf16<1, 0><<<dim3(79 * 32), blk, 0, stream>>>(x2, w_out, ob, out_b, 4096, 10000, 512, 512, 512, 10000, 79);
}

// Round 7
// 507.013 us; speedup vs baseline: 5.3155x; 1.0330x over previous
//
#include <hip/hip_runtime.h>
#include <hip/hip_bf16.h>
#include <math.h>

// Model dims
#define SEQ 2048
// B=2, DM=512, DI=1024, N=16, K=4, R=32, H=8, V=10000

typedef __attribute__((ext_vector_type(4))) float f32x4;
typedef __attribute__((ext_vector_type(8))) short bf16x8s;
typedef __attribute__((ext_vector_type(4))) short short4v;
typedef __attribute__((ext_vector_type(8))) unsigned short ushort8;
typedef __attribute__((ext_vector_type(2))) unsigned int uint2v;

__device__ __forceinline__ short f2bf(float f) {
  union { float f; unsigned u; } c; c.f = f;
  unsigned u = c.u;
  u += 0x7fffu + ((u >> 16) & 1u);   // RNE
  return (short)(u >> 16);
}
__device__ __forceinline__ float bf2f(unsigned short u) {
  union { unsigned u; float f; } c; c.u = ((unsigned)u) << 16; return c.f;
}

__device__ __forceinline__ void lds_load16(const void* g, void* s) {
  __builtin_amdgcn_global_load_lds(
      (const __attribute__((address_space(1))) void*)g,
      (__attribute__((address_space(3))) void*)s, 16, 0, 0);
}

// =================== bf16 MFMA GEMM: C[M,N] = A[M,K] @ B[N,K]^T ===================
// A,B bf16 (K%64==0, lda/ldb %8==0, M%512==0, N%4==0). nbm = M/128 must be %4.
// EPI: 0 none, 1 +bias. OUTBF: 1 -> bf16 C, 0 -> f32 C.
// Block order: bijective XCD chunks (all grids %8==0 -> r=0), and within the
// grid a 4-bm supertile order (bm-inner-of-4, bn-outer). With nbm=32 each XCD
// chunk is exactly one 4-bm stripe x all bn: A stripe (512KB) + concurrent B
// panels stay L2-resident; B fetched once per XCD (was: per 2 bm-rows).
template<int EPI, int OUTBF>
__launch_bounds__(256)
__global__ void gemm_bf16(const unsigned short* __restrict__ A, const unsigned short* __restrict__ B,
                          void* __restrict__ Cv, const float* __restrict__ bias,
                          int M, int N, int K, int lda, int ldb, int ldc, int nbn) {
  __shared__ char smem[67584];   // 2x(16KB A + 16KB B) dbuf; 128x132 f32 epilogue tile

  // bijective XCD chunk swizzle (m204)
  const int nwg = gridDim.x;
  const int g = blockIdx.x;
  const int q = nwg >> 3, r = nwg & 7;
  const int xcd = g & 7, cidx = g >> 3;
  const int wg = (xcd < r ? xcd * (q + 1) : r * (q + 1) + (xcd - r) * q) + cidx;
  // 4-bm supertile order: bm fastest within group of 4, then bn, then bm-group
  const int sup = nbn << 2;
  const int bmg = wg / sup, rem = wg % sup;
  const int bn = rem >> 2;
  const int bm = (bmg << 2) + (rem & 3);
  const int m0 = bm * 128, n0 = bn * 128;

  const int tid = threadIdx.x, lane = tid & 63, wave = tid >> 6;
  const int wr = (wave >> 1) * 64, wc = (wave & 1) * 64;
  const int fr = lane & 15, fq = lane >> 4;
  const int srow = tid >> 3;   // 0..31
  const int scc  = tid & 7;    // column chunk 0..7 (8 bf16 each)

  f32x4 acc[4][4] = {};
  const int nkt = K >> 6;

  auto STAGE = [&](int buf, int kt) {
    const int k0 = kt << 6;
    unsigned short* sAb = (unsigned short*)(smem + buf * 32768);
    unsigned short* sBb = (unsigned short*)(smem + buf * 32768 + 16384);
    #pragma unroll
    for (int j = 0; j < 4; j++) {
      int lrow = j * 32 + srow;
      int gcol = (scc ^ (lrow & 7)) * 8;
      lds_load16(A + (size_t)(m0 + lrow) * lda + k0 + gcol, &sAb[(j * 256 + wave * 64) * 8]);
    }
    #pragma unroll
    for (int j = 0; j < 4; j++) {
      int lrow = j * 32 + srow;
      int gcol = (scc ^ (lrow & 7)) * 8;
      int grow = n0 + lrow; if (grow >= N) grow = N - 1;   // clamp; junk never stored
      lds_load16(B + (size_t)grow * ldb + k0 + gcol, &sBb[(j * 256 + wave * 64) * 8]);
    }
  };

  STAGE(0, 0);
  asm volatile("s_waitcnt vmcnt(0)" ::: "memory");
  __builtin_amdgcn_s_barrier();

  int cur = 0;
  for (int kt = 0; kt < nkt; kt++) {
    if (kt + 1 < nkt) STAGE(cur ^ 1, kt + 1);   // issue next-tile loads first
    const unsigned short* As = (const unsigned short*)(smem + cur * 32768);
    const unsigned short* Bs = (const unsigned short*)(smem + cur * 32768 + 16384);
    #pragma unroll
    for (int ks = 0; ks < 2; ks++) {
      bf16x8s af[4], bfv[4];
      #pragma unroll
      for (int i = 0; i < 4; i++) {
        int ra = wr + i * 16 + fr;
        af[i] = *(const bf16x8s*)&As[ra * 64 + (((ks << 2) + fq) ^ (ra & 7)) * 8];
      }
      #pragma unroll
      for (int i = 0; i < 4; i++) {
        int rb = wc + i * 16 + fr;
        bfv[i] = *(const bf16x8s*)&Bs[rb * 64 + (((ks << 2) + fq) ^ (rb & 7)) * 8];
      }
      #pragma unroll
      for (int i = 0; i < 4; i++)
        #pragma unroll
        for (int j = 0; j < 4; j++)
          acc[i][j] = __builtin_amdgcn_mfma_f32_16x16x32_bf16(af[i], bfv[j], acc[i][j], 0, 0, 0);
    }
    asm volatile("s_waitcnt vmcnt(0)" ::: "memory");  // this wave's stage loads landed
    __builtin_amdgcn_s_barrier();                     // all waves' loads landed / reads done
    cur ^= 1;
  }

  // ---- epilogue: stage f32 tile in LDS, write coalesced ----
  float* ct = (float*)smem;   // [128][132]
  #pragma unroll
  for (int i = 0; i < 4; i++)
    #pragma unroll
    for (int j = 0; j < 4; j++)
      #pragma unroll
      for (int r4 = 0; r4 < 4; r4++)
        ct[(wr + i * 16 + fq * 4 + r4) * 132 + wc + j * 16 + fr] = acc[i][j][r4];
  __syncthreads();
  const int half = lane >> 5;
  const int col4 = (lane & 31) * 4;
  const int cn = n0 + col4;
  #pragma unroll
  for (int it = 0; it < 16; it++) {
    int row = wave * 32 + it * 2 + half;
    f32x4 v = *(const f32x4*)&ct[row * 132 + col4];
    if (cn < N) {
      if (EPI >= 1) {
        f32x4 b4 = *(const f32x4*)&bias[cn];
        #pragma unroll
        for (int j = 0; j < 4; j++) v[j] += b4[j];
      }
      if (OUTBF) {
        unsigned short h0 = (unsigned short)f2bf(v[0]), h1 = (unsigned short)f2bf(v[1]);
        unsigned short h2 = (unsigned short)f2bf(v[2]), h3 = (unsigned short)f2bf(v[3]);
        uint2v o = { (unsigned)h0 | ((unsigned)h1 << 16), (unsigned)h2 | ((unsigned)h3 << 16) };
        *(uint2v*)((unsigned short*)Cv + (size_t)(m0 + row) * ldc + cn) = o;
      } else {
        float* dst = (float*)Cv + (size_t)(m0 + row) * ldc + cn;
        if (EPI == 1) __builtin_nontemporal_store(v, (f32x4*)dst);  // final logits: stream past L2
        else          *(f32x4*)dst = v;
      }
    }
  }
}

// =================== f32-input GEMM (mel K=80) ===================
#define LDT 40
template<int EPI, int OUTBF>
__launch_bounds__(256)
__global__ void gemm_f32in(const float* __restrict__ A, const float* __restrict__ B,
                           void* __restrict__ Cv, const float* __restrict__ bias,
                           int M, int N, int K, int lda, int ldb, int ldc) {
  __shared__ short As[128 * LDT];
  __shared__ short Bs[128 * LDT];
  const int tid  = threadIdx.x;
  const int lane = tid & 63;
  const int wave = tid >> 6;
  const int m0 = blockIdx.y * 128;
  const int n0 = blockIdx.x * 128;
  const int wr = (wave >> 1) * 64;
  const int wc = (wave & 1) * 64;
  const int srow = tid >> 3;
  const int scol = (tid & 7) * 4;
  const int fr = lane & 15;
  const int fq = lane >> 4;

  f32x4 acc[4][4] = {};

  for (int k0 = 0; k0 < K; k0 += 32) {
    const bool kok = (k0 + scol) < K;
    #pragma unroll
    for (int rr = 0; rr < 128; rr += 32) {
      int r = srow + rr;
      f32x4 v = {0.f, 0.f, 0.f, 0.f};
      if (kok) v = *(const f32x4*)(A + (size_t)(m0 + r) * lda + k0 + scol);
      short4v s = { f2bf(v[0]), f2bf(v[1]), f2bf(v[2]), f2bf(v[3]) };
      *(short4v*)(&As[r * LDT + scol]) = s;
    }
    #pragma unroll
    for (int rr = 0; rr < 128; rr += 32) {
      int r = srow + rr;
      f32x4 v = {0.f, 0.f, 0.f, 0.f};
      if (kok && (n0 + r) < N) v = *(const f32x4*)(B + (size_t)(n0 + r) * ldb + k0 + scol);
      short4v s = { f2bf(v[0]), f2bf(v[1]), f2bf(v[2]), f2bf(v[3]) };
      *(short4v*)(&Bs[r * LDT + scol]) = s;
    }
    __syncthreads();
    bf16x8s af[4], bfv[4];
    #pragma unroll
    for (int i = 0; i < 4; i++)
      af[i]  = *(const bf16x8s*)(&As[(wr + i * 16 + fr) * LDT + fq * 8]);
    #pragma unroll
    for (int i = 0; i < 4; i++)
      bfv[i] = *(const bf16x8s*)(&Bs[(wc + i * 16 + fr) * LDT + fq * 8]);
    #pragma unroll
    for (int i = 0; i < 4; i++)
      #pragma unroll
      for (int j = 0; j < 4; j++)
        acc[i][j] = __builtin_amdgcn_mfma_f32_16x16x32_bf16(af[i], bfv[j], acc[i][j], 0, 0, 0);
    __syncthreads();
  }

  #pragma unroll
  for (int j = 0; j < 4; j++) {
    int cn = n0 + wc + j * 16 + fr;
    if (cn < N) {
      float bv = 0.f;
      if (EPI >= 1) bv = bias[cn];
      #pragma unroll
      for (int i = 0; i < 4; i++) {
        #pragma unroll
        for (int r4 = 0; r4 < 4; r4++) {
          int cm = m0 + wr + i * 16 + fq * 4 + r4;
          float val = acc[i][j][r4] + bv;
          if (OUTBF) ((unsigned short*)Cv)[(size_t)cm * ldc + cn] = (unsigned short)f2bf(val);
          else       ((float*)Cv)[(size_t)cm * ldc + cn] = val;
        }
      }
    }
  }
}

// =================== weight f32 -> bf16 conversion (12 tensors, one launch) ===================
struct CvtArgs { const float* s[12]; unsigned short* d[12]; int n[12]; };
__global__ void cvt_many(CvtArgs a) {
  int y = blockIdx.y;
  int i = (blockIdx.x * 256 + threadIdx.x) * 8;
  if (i >= a.n[y]) return;
  const float* s = a.s[y];
  f32x4 v0 = *(const f32x4*)(s + i);
  f32x4 v1 = *(const f32x4*)(s + i + 4);
  ushort8 o = { (unsigned short)f2bf(v0[0]), (unsigned short)f2bf(v0[1]),
                (unsigned short)f2bf(v0[2]), (unsigned short)f2bf(v0[3]),
                (unsigned short)f2bf(v1[0]), (unsigned short)f2bf(v1[1]),
                (unsigned short)f2bf(v1[2]), (unsigned short)f2bf(v1[3]) };
  *(ushort8*)(a.d[y] + i) = o;
}

// =================== tiny attention (L=2) over bf16 qkv ===================
__global__ void attn_kernel(const unsigned short* __restrict__ qkv, unsigned short* __restrict__ o) {
  int gw = blockIdx.x * 4 + (threadIdx.x >> 6);
  int lane = threadIdx.x & 63;
  int n = gw >> 3, h = gw & 7;
  size_t r0 = (size_t)n * 1536 + h * 64 + lane;
  size_t r1 = (size_t)(SEQ + n) * 1536 + h * 64 + lane;
  float q0 = bf2f(qkv[r0]), k0 = bf2f(qkv[r0 + 512]), v0 = bf2f(qkv[r0 + 1024]);
  float q1 = bf2f(qkv[r1]), k1 = bf2f(qkv[r1 + 512]), v1 = bf2f(qkv[r1 + 1024]);
  float s00 = q0 * k0, s01 = q0 * k1, s10 = q1 * k0, s11 = q1 * k1;
  #pragma unroll
  for (int off = 32; off > 0; off >>= 1) {
    s00 += __shfl_xor(s00, off);
    s01 += __shfl_xor(s01, off);
    s10 += __shfl_xor(s10, off);
    s11 += __shfl_xor(s11, off);
  }
  const float sc = 0.125f;
  s00 *= sc; s01 *= sc; s10 *= sc; s11 *= sc;
  float mx0 = fmaxf(s00, s01), mx1 = fmaxf(s10, s11);
  float e00 = __expf(s00 - mx0), e01 = __expf(s01 - mx0);
  float e10 = __expf(s10 - mx1), e11 = __expf(s11 - mx1);
  float i0 = 1.f / (e00 + e01), i1 = 1.f / (e10 + e11);
  size_t w0 = (size_t)n * 512 + h * 64 + lane;
  size_t w1 = (size_t)(SEQ + n) * 512 + h * 64 + lane;
  o[w0] = (unsigned short)f2bf((e00 * v0 + e01 * v1) * i0);
  o[w1] = (unsigned short)f2bf((e10 * v0 + e11 * v1) * i1);
}

// =================== LN(a+b) over 512, bf16 in/out; DUAL: also write time-flipped copy ===================
template<int DUAL>
__global__ void ln_res_kernel(const unsigned short* __restrict__ a, const unsigned short* __restrict__ b,
                              const float* __restrict__ g, const float* __restrict__ be,
                              unsigned short* __restrict__ out, unsigned short* __restrict__ out2) {
  int row = blockIdx.x * 4 + (threadIdx.x >> 6);
  int lane = threadIdx.x & 63;
  ushort8 va = *(const ushort8*)(a + (size_t)row * 512 + lane * 8);
  ushort8 vb = *(const ushort8*)(b + (size_t)row * 512 + lane * 8);
  float v[8];
  #pragma unroll
  for (int j = 0; j < 8; j++) v[j] = bf2f(va[j]) + bf2f(vb[j]);
  float s = 0.f, s2 = 0.f;
  #pragma unroll
  for (int j = 0; j < 8; j++) { s += v[j]; s2 += v[j] * v[j]; }
  #pragma unroll
  for (int off = 32; off > 0; off >>= 1) { s += __shfl_xor(s, off); s2 += __shfl_xor(s2, off); }
  float mu = s * (1.f / 512.f);
  float var = s2 * (1.f / 512.f) - mu * mu;
  float rs = rsqrtf(var + 1e-5f);
  const float* pg = g + lane * 8;
  const float* pe = be + lane * 8;
  ushort8 o;
  #pragma unroll
  for (int j = 0; j < 8; j++) o[j] = (unsigned short)f2bf((v[j] - mu) * rs * pg[j] + pe[j]);
  *(ushort8*)(out + (size_t)row * 512 + lane * 8) = o;
  if (DUAL) {
    int t = row & (SEQ - 1), bb = row >> 11;
    int frow = (bb << 11) | (SEQ - 1 - t);
    *(ushort8*)(out2 + (size_t)frow * 512 + lane * 8) = o;
  }
}

// =================== depthwise causal conv(K=4)+silu, bf16, 8 d per thread ===================
__global__ void conv_silu_kernel(const unsigned short* __restrict__ xz, const float* __restrict__ w,
                                 const float* __restrict__ cb, unsigned short* __restrict__ xc) {
  int idx = blockIdx.x * 256 + threadIdx.x;     // over B*S*(DI/8) = 524288
  int dc = (idx & 127) * 8;
  int t  = (idx >> 7) & (SEQ - 1);
  int b  = idx >> 18;
  f32x4 wv[8];
  #pragma unroll
  for (int j = 0; j < 8; j++) wv[j] = *(const f32x4*)(w + (dc + j) * 4);
  float acc[8];
  f32x4 cb0 = *(const f32x4*)(cb + dc), cb1 = *(const f32x4*)(cb + dc + 4);
  #pragma unroll
  for (int j = 0; j < 4; j++) { acc[j] = cb0[j]; acc[4 + j] = cb1[j]; }
  const unsigned short* base = xz + ((size_t)b * SEQ) * 2048 + dc;
  #pragma unroll
  for (int k = 0; k < 4; k++) {
    int tt = t - 3 + k;
    if (tt >= 0) {
      ushort8 xv = *(const ushort8*)(base + (size_t)tt * 2048);
      #pragma unroll
      for (int j = 0; j < 8; j++) acc[j] += wv[j][k] * bf2f(xv[j]);
    }
  }
  ushort8 o;
  #pragma unroll
  for (int j = 0; j < 8; j++) {
    float v = acc[j];
    o[j] = (unsigned short)f2bf(v / (1.f + __expf(-v)));
  }
  *(ushort8*)(xc + (size_t)idx * 8) = o;
}

// =================== chunked selective scan (dt inlined, gate+flip fused) ===================
#define CL 32
#define NC 64

__device__ __forceinline__ float dt_inline(const float* __restrict__ dr,
                                           const float* __restrict__ dtw, float db) {
  float acc = db;
  #pragma unroll
  for (int q = 0; q < 8; q++) {
    f32x4 v = *(const f32x4*)(dr + q * 4);
    acc += v[0] * dtw[q * 4] + v[1] * dtw[q * 4 + 1] + v[2] * dtw[q * 4 + 2] + v[3] * dtw[q * 4 + 3];
  }
  // softplus
  return fmaxf(acc, 0.f) + log1pf(__expf(-fabsf(acc)));
}

__global__ void scan_p1(const unsigned short* __restrict__ xc, const float* __restrict__ dbl,
                        const float* __restrict__ A_log, const float* __restrict__ dt_w,
                        const float* __restrict__ dt_b,
                        float* __restrict__ hend, float* __restrict__ aprod) {
  int tid = blockIdx.x * 256 + threadIdx.x;   // B*NC*DI = 131072
  int d = tid & 1023;
  int c = (tid >> 10) & (NC - 1);
  int b = tid >> 16;
  float A[16];
  #pragma unroll
  for (int q = 0; q < 4; q++) {
    f32x4 v = *(const f32x4*)(A_log + d * 16 + q * 4);
    #pragma unroll
    for (int j = 0; j < 4; j++) A[q * 4 + j] = -__expf(v[j]);
  }
  float dtw[32];
  #pragma unroll
  for (int q = 0; q < 8; q++) {
    f32x4 v = *(const f32x4*)(dt_w + d * 32 + q * 4);
    #pragma unroll
    for (int j = 0; j < 4; j++) dtw[q * 4 + j] = v[j];
  }
  const float db = dt_b[d];
  float h[16] = {};
  float ap[16];
  #pragma unroll
  for (int n = 0; n < 16; n++) ap[n] = 1.f;
  const unsigned short* xcp = xc + ((size_t)b * SEQ) * 1024 + d;
  const float* dbp = dbl + ((size_t)b * SEQ) * 64;
  const int t0 = c * CL;
  for (int t = t0; t < t0 + CL; t++) {
    const float* dr = dbp + (size_t)t * 64;
    float dtv = dt_inline(dr, dtw, db);
    float dx = dtv * bf2f(xcp[(size_t)t * 1024]);
    float Bv[16];
    #pragma unroll
    for (int q = 0; q < 4; q++) {
      f32x4 v = *(const f32x4*)(dr + 32 + q * 4);
      #pragma unroll
      for (int j = 0; j < 4; j++) Bv[q * 4 + j] = v[j];
    }
    #pragma unroll
    for (int n = 0; n < 16; n++) {
      float e = __expf(dtv * A[n]);
      h[n] = e * h[n] + dx * Bv[n];
      ap[n] *= e;
    }
  }
  size_t o = ((size_t)((b * NC + c) * 1024 + d)) * 16;
  #pragma unroll
  for (int q = 0; q < 4; q++) {
    f32x4 vh = { h[q * 4], h[q * 4 + 1], h[q * 4 + 2], h[q * 4 + 3] };
    f32x4 va = { ap[q * 4], ap[q * 4 + 1], ap[q * 4 + 2], ap[q * 4 + 3] };
    *(f32x4*)(hend + o + q * 4) = vh;
    *(f32x4*)(aprod + o + q * 4) = va;
  }
}

__global__ void scan_p2(const float* __restrict__ hend, const float* __restrict__ aprod,
                        float* __restrict__ h0) {
  int tid = blockIdx.x * 256 + threadIdx.x;   // B*DI*N = 32768
  int n = tid & 15;
  int d = (tid >> 4) & 1023;
  int b = tid >> 14;
  float h = 0.f;
  for (int c = 0; c < NC; c++) {
    size_t idx = ((size_t)((b * NC + c) * 1024 + d)) * 16 + n;
    h0[idx] = h;
    h = aprod[idx] * h + hend[idx];
  }
}

// p3: recompute with h0, emit gated output, write (optionally time-flipped)
__global__ void scan_p3(const unsigned short* __restrict__ xc, const float* __restrict__ dbl,
                        const float* __restrict__ A_log, const float* __restrict__ dt_w,
                        const float* __restrict__ dt_b, const float* __restrict__ h0,
                        const unsigned short* __restrict__ xz, const float* __restrict__ Dp,
                        unsigned short* __restrict__ ys, int rev) {
  int tid = blockIdx.x * 256 + threadIdx.x;   // B*NC*DI = 131072
  int d = tid & 1023;
  int c = (tid >> 10) & (NC - 1);
  int b = tid >> 16;
  float A[16];
  #pragma unroll
  for (int q = 0; q < 4; q++) {
    f32x4 v = *(const f32x4*)(A_log + d * 16 + q * 4);
    #pragma unroll
    for (int j = 0; j < 4; j++) A[q * 4 + j] = -__expf(v[j]);
  }
  float dtw[32];
  #pragma unroll
  for (int q = 0; q < 8; q++) {
    f32x4 v = *(const f32x4*)(dt_w + d * 32 + q * 4);
    #pragma unroll
    for (int j = 0; j < 4; j++) dtw[q * 4 + j] = v[j];
  }
  const float db = dt_b[d];
  const float Dv = Dp[d];
  float h[16];
  size_t o = ((size_t)((b * NC + c) * 1024 + d)) * 16;
  #pragma unroll
  for (int q = 0; q < 4; q++) {
    f32x4 v = *(const f32x4*)(h0 + o + q * 4);
    #pragma unroll
    for (int j = 0; j < 4; j++) h[q * 4 + j] = v[j];
  }
  const unsigned short* xcp = xc + ((size_t)b * SEQ) * 1024 + d;
  const unsigned short* zp  = xz + ((size_t)b * SEQ) * 2048 + 1024 + d;
  const float* dbp = dbl + ((size_t)b * SEQ) * 64;
  unsigned short* ysp = ys + ((size_t)b * SEQ) * 1024 + d;
  const int t0 = c * CL;
  for (int t = t0; t < t0 + CL; t++) {
    const float* dr = dbp + (size_t)t * 64;
    float dtv = dt_inline(dr, dtw, db);
    float xcv = bf2f(xcp[(size_t)t * 1024]);
    float dx = dtv * xcv;
    float Bv[16], Cv[16];
    #pragma unroll
    for (int q = 0; q < 4; q++) {
      f32x4 v = *(const f32x4*)(dr + 32 + q * 4);
      f32x4 w = *(const f32x4*)(dr + 48 + q * 4);
      #pragma unroll
      for (int j = 0; j < 4; j++) { Bv[q * 4 + j] = v[j]; Cv[q * 4 + j] = w[j]; }
    }
    float y = 0.f;
    #pragma unroll
    for (int n = 0; n < 16; n++) {
      float e = __expf(dtv * A[n]);
      h[n] = e * h[n] + dx * Bv[n];
      y += h[n] * Cv[n];
    }
    // gate: (y + xc*D) * silu(z)
    float z = bf2f(zp[(size_t)t * 2048]);
    float out = (y + xcv * Dv) * (z / (1.f + __expf(-z)));
    int tw = rev ? (SEQ - 1 - t) : t;
    ysp[(size_t)tw * 1024] = (unsigned short)f2bf(out);
  }
}

extern "C" void kernel_launch(void* const* d_in, const int* in_sizes, int n_in,
                              void* d_out, int out_size, void* d_ws, size_t ws_size,
                              hipStream_t stream) {
  (void)in_sizes; (void)n_in; (void)out_size; (void)ws_size;
  const float* mel        = (const float*)d_in[0];
  const float* mel_w      = (const float*)d_in[1];
  const float* mel_b      = (const float*)d_in[2];
  const float* attn_in_b  = (const float*)d_in[4];
  const float* attn_out_b = (const float*)d_in[6];
  const float* ln1_g = (const float*)d_in[7];
  const float* ln1_b = (const float*)d_in[8];
  const float* ln2_g = (const float*)d_in[9];
  const float* ln2_b = (const float*)d_in[10];
  const float* bim_b = (const float*)d_in[30];
  const float* out_b = (const float*)d_in[32];

  char* wsb = (char*)d_ws;
  char* obb = (char*)d_out;

  // ---- bf16 weights in ws (byte offsets) ----
  unsigned short* w_attn_in  = (unsigned short*)(wsb + 0);          // 786432
  unsigned short* w_attn_out = (unsigned short*)(wsb + 1572864);    // 262144
  unsigned short* w_dir[2][4];
  for (int dir = 0; dir < 2; dir++) {
    size_t base = 2097152 + (size_t)dir * 3342336;
    w_dir[dir][0] = (unsigned short*)(wsb + base);                  // in_w
    w_dir[dir][1] = (unsigned short*)(wsb + base + 2097152);        // x_w
    w_dir[dir][2] = (unsigned short*)(wsb + base + 2228224);        // (spare)
    w_dir[dir][3] = (unsigned short*)(wsb + base + 2293760);        // out_w
  }
  unsigned short* w_bim = (unsigned short*)(wsb + 8781824);         // 524288
  unsigned short* w_out = (unsigned short*)(wsb + 9830400);         // 5120000

  // ---- bf16 activations in ws ----
  unsigned short* x0     = (unsigned short*)(wsb + 20971520);
  unsigned short* x1     = (unsigned short*)(wsb + 25165824);
  unsigned short* x1f    = (unsigned short*)(wsb + 29360128);
  unsigned short* attn_o = (unsigned short*)(wsb + 33554432);
  unsigned short* xc     = (unsigned short*)(wsb + 37748736);
  unsigned short* ysb    = (unsigned short*)(wsb + 46137344);
  unsigned short* mout   = (unsigned short*)(wsb + 62914560);
  unsigned short* minter = (unsigned short*)(wsb + 71303168);
  unsigned short* x2     = (unsigned short*)(wsb + 75497472);
  float*          dbl    = (float*)(wsb + 79691776);

  // ---- d_out scratch (dead until final GEMM overwrites all) ----
  unsigned short* qkv = (unsigned short*)(obb + 0);
  unsigned short* xz  = (unsigned short*)(obb + 12582912);
  float* hend = (float*)(obb + 62914560);     // 8.39 MB (NC=64)
  float* apr  = (float*)(obb + 79691776);     // 8.39 MB
  float* h0s  = (float*)(obb + 96468992);     // 8.39 MB
  float* ob   = (float*)d_out;

  dim3 blk(256);

  // 0. convert weights to bf16
  {
    CvtArgs a;
    const float* srcs[12] = { (const float*)d_in[3], (const float*)d_in[5],
      (const float*)d_in[11], (const float*)d_in[14], (const float*)d_in[15], (const float*)d_in[19],
      (const float*)d_in[20], (const float*)d_in[23], (const float*)d_in[24], (const float*)d_in[28],
      (const float*)d_in[29], (const float*)d_in[31] };
    unsigned short* dsts[12] = { w_attn_in, w_attn_out,
      w_dir[0][0], w_dir[0][1], w_dir[0][2], w_dir[0][3],
      w_dir[1][0], w_dir[1][1], w_dir[1][2], w_dir[1][3],
      w_bim, w_out };
    int ns[12] = { 786432, 262144, 1048576, 65536, 32768, 524288,
                   1048576, 65536, 32768, 524288, 524288, 5120000 };
    for (int i = 0; i < 12; i++) { a.s[i] = srcs[i]; a.d[i] = dsts[i]; a.n[i] = ns[i]; }
    cvt_many<<<dim3(2500, 12), blk, 0, stream>>>(a);
  }

  // 1. x0 = mel @ mel_w.T + mel_b (f32-in path, K=80)
  gemm_f32in<1, 1><<<dim3(4, 32), blk, 0, stream>>>(mel, mel_w, x0, mel_b, 4096, 512, 80, 80, 80, 512);
  // 2. qkv = x0 @ attn_in_w.T + b
  gemm_bf16<1, 1><<<dim3(12 * 32), blk, 0, stream>>>(x0, w_attn_in, qkv, attn_in_b, 4096, 1536, 512, 512, 512, 1536, 12);
  // 3. attention
  attn_kernel<<<4096, blk, 0, stream>>>(qkv, attn_o);
  // 4. attnproj -> qkv slot
  gemm_bf16<1, 1><<<dim3(4 * 32), blk, 0, stream>>>(attn_o, w_attn_out, qkv, attn_out_b, 4096, 512, 512, 512, 512, 512, 4);
  // 5. x1 = LN(x0 + attnproj); x1f = flip(x1) fused
  ln_res_kernel<1><<<1024, blk, 0, stream>>>(x0, qkv, ln1_g, ln1_b, x1, x1f);

  for (int dir = 0; dir < 2; dir++) {
    int base = 11 + dir * 9;
    const float* conv_w  = (const float*)d_in[base + 1];
    const float* conv_b  = (const float*)d_in[base + 2];
    const float* dt_w    = (const float*)d_in[base + 4];
    const float* dt_bias = (const float*)d_in[base + 5];
    const float* A_log   = (const float*)d_in[base + 6];
    const float* Dp      = (const float*)d_in[base + 7];
    const unsigned short* xin = dir ? x1f : x1;
    // xz = xin @ in_w.T
    gemm_bf16<0, 1><<<dim3(16 * 32), blk, 0, stream>>>(xin, w_dir[dir][0], xz, nullptr, 4096, 2048, 512, 512, 512, 2048, 16);
    // conv + silu
    conv_silu_kernel<<<2048, blk, 0, stream>>>(xz, conv_w, conv_b, xc);
    // dbl = xc @ x_w.T (f32 out for scan numerics)
    gemm_bf16<0, 0><<<dim3(1 * 32), blk, 0, stream>>>(xc, w_dir[dir][1], dbl, nullptr, 4096, 64, 1024, 1024, 1024, 64, 1);
    // selective scan (dt inlined; gate + output-flip fused into p3)
    scan_p1<<<512, blk, 0, stream>>>(xc, dbl, A_log, dt_w, dt_bias, hend, apr);
    scan_p2<<<128, blk, 0, stream>>>(hend, apr, h0s);
    scan_p3<<<512, blk, 0, stream>>>(xc, dbl, A_log, dt_w, dt_bias, h0s, xz, Dp, ysb, dir);
    // mamba out proj -> mout cols [dir*512, +512)
    gemm_bf16<0, 1><<<dim3(4 * 32), blk, 0, stream>>>(ysb, w_dir[dir][3], mout + dir * 512, nullptr, 4096, 512, 1024, 1024, 1024, 1024, 4);
  }

  // m = mout @ bim_w.T + bim_b
  gemm_bf16<1, 1><<<dim3(4 * 32), blk, 0, stream>>>(mout, w_bim, minter, bim_b, 4096, 512, 1024, 1024, 1024, 512, 4);
  // x2 = LN(x1 + m)
  ln_res_kernel<0><<<1024, blk, 0, stream>>>(x1, minter, ln2_g, ln2_b, x2, nullptr);
  // logits = x2 @ out_w.T + out_b  (overwrites all of d_out; nontemporal f32 stores)
  gemm_bf16<1, 0><<<dim3(79 * 32), blk, 0, stream>>>(x2, w_out, ob, out_b, 4096, 10000, 512, 512, 512, 10000, 79);
}

// Round 8
// 397.713 us; speedup vs baseline: 6.7763x; 1.2748x over previous
//
#include <hip/hip_runtime.h>
#include <hip/hip_bf16.h>
#include <math.h>

// Model dims
#define SEQ 2048
// B=2, DM=512, DI=1024, N=16, K=4, R=32, H=8, V=10000

typedef __attribute__((ext_vector_type(4))) float f32x4;
typedef __attribute__((ext_vector_type(8))) short bf16x8s;
typedef __attribute__((ext_vector_type(4))) short short4v;
typedef __attribute__((ext_vector_type(8))) unsigned short ushort8;
typedef __attribute__((ext_vector_type(2))) unsigned int uint2v;

__device__ __forceinline__ short f2bf(float f) {
  union { float f; unsigned u; } c; c.f = f;
  unsigned u = c.u;
  u += 0x7fffu + ((u >> 16) & 1u);   // RNE
  return (short)(u >> 16);
}
__device__ __forceinline__ float bf2f(unsigned short u) {
  union { unsigned u; float f; } c; c.u = ((unsigned)u) << 16; return c.f;
}

__device__ __forceinline__ void lds_load16(const void* g, void* s) {
  __builtin_amdgcn_global_load_lds(
      (const __attribute__((address_space(1))) void*)g,
      (__attribute__((address_space(3))) void*)s, 16, 0, 0);
}

// =================== bf16 MFMA GEMM: C[M,N] = A[M,K] @ B[N,K]^T ===================
// A,B bf16 (K%64==0, lda/ldb %8==0, M%512==0, N%4==0). nbm = M/128 must be %4.
// EPI: 0 none, 1 +bias. OUTBF: 1 -> bf16 C, 0 -> f32 C.
// blockIdx.y==1 selects the A1/B1/C1 tensor set (dual-direction launches).
// Pipeline (T3+T4): STAGE(t+1) issued first, then counted s_waitcnt vmcnt(8)
// (previous stage's 8 loads landed, new 8 stay in flight ACROSS the barrier),
// barrier, ds_read+MFMA, barrier. XOR-chunk swizzled LDS; LDS-staged epilogue.
// Block order: bijective XCD chunks + 4-bm supertiles (bm-inner, bn-outer).
template<int EPI, int OUTBF>
__launch_bounds__(256)
__global__ void gemm_bf16(const unsigned short* A, const unsigned short* B,
                          void* Cv, const float* __restrict__ bias,
                          int M, int N, int K, int lda, int ldb, int ldc, int nbn,
                          const unsigned short* A1, const unsigned short* B1, void* C1) {
  __shared__ char smem[67584];   // 2x(16KB A + 16KB B) dbuf; 128x132 f32 epilogue tile

  if (blockIdx.y) { A = A1; B = B1; Cv = C1; }

  // bijective XCD chunk swizzle (m204)
  const int nwg = gridDim.x;
  const int g = blockIdx.x;
  const int q = nwg >> 3, r = nwg & 7;
  const int xcd = g & 7, cidx = g >> 3;
  const int wg = (xcd < r ? xcd * (q + 1) : r * (q + 1) + (xcd - r) * q) + cidx;
  // 4-bm supertile order: bm fastest within group of 4, then bn, then bm-group
  const int sup = nbn << 2;
  const int bmg = wg / sup, rem = wg % sup;
  const int bn = rem >> 2;
  const int bm = (bmg << 2) + (rem & 3);
  const int m0 = bm * 128, n0 = bn * 128;

  const int tid = threadIdx.x, lane = tid & 63, wave = tid >> 6;
  const int wr = (wave >> 1) * 64, wc = (wave & 1) * 64;
  const int fr = lane & 15, fq = lane >> 4;
  const int srow = tid >> 3;   // 0..31
  const int scc  = tid & 7;    // column chunk 0..7 (8 bf16 each)

  f32x4 acc[4][4] = {};
  const int nkt = K >> 6;

  auto STAGE = [&](int buf, int kt) {
    const int k0 = kt << 6;
    unsigned short* sAb = (unsigned short*)(smem + buf * 32768);
    unsigned short* sBb = (unsigned short*)(smem + buf * 32768 + 16384);
    #pragma unroll
    for (int j = 0; j < 4; j++) {
      int lrow = j * 32 + srow;
      int gcol = (scc ^ (lrow & 7)) * 8;
      lds_load16(A + (size_t)(m0 + lrow) * lda + k0 + gcol, &sAb[(j * 256 + wave * 64) * 8]);
    }
    #pragma unroll
    for (int j = 0; j < 4; j++) {
      int lrow = j * 32 + srow;
      int gcol = (scc ^ (lrow & 7)) * 8;
      int grow = n0 + lrow; if (grow >= N) grow = N - 1;   // clamp; junk never stored
      lds_load16(B + (size_t)grow * ldb + k0 + gcol, &sBb[(j * 256 + wave * 64) * 8]);
    }
  };

  STAGE(0, 0);

  int cur = 0;
  for (int kt = 0; kt < nkt; kt++) {
    if (kt + 1 < nkt) {
      STAGE(cur ^ 1, kt + 1);                           // 8 new loads in flight
      asm volatile("s_waitcnt vmcnt(8)" ::: "memory");  // previous stage landed (wave-local)
    } else {
      asm volatile("s_waitcnt vmcnt(0)" ::: "memory");  // last tile: full drain
    }
    __builtin_amdgcn_s_barrier();                       // all waves' stage landed
    __builtin_amdgcn_sched_barrier(0);
    const unsigned short* As = (const unsigned short*)(smem + cur * 32768);
    const unsigned short* Bs = (const unsigned short*)(smem + cur * 32768 + 16384);
    #pragma unroll
    for (int ks = 0; ks < 2; ks++) {
      bf16x8s af[4], bfv[4];
      #pragma unroll
      for (int i = 0; i < 4; i++) {
        int ra = wr + i * 16 + fr;
        af[i] = *(const bf16x8s*)&As[ra * 64 + (((ks << 2) + fq) ^ (ra & 7)) * 8];
      }
      #pragma unroll
      for (int i = 0; i < 4; i++) {
        int rb = wc + i * 16 + fr;
        bfv[i] = *(const bf16x8s*)&Bs[rb * 64 + (((ks << 2) + fq) ^ (rb & 7)) * 8];
      }
      #pragma unroll
      for (int i = 0; i < 4; i++)
        #pragma unroll
        for (int j = 0; j < 4; j++)
          acc[i][j] = __builtin_amdgcn_mfma_f32_16x16x32_bf16(af[i], bfv[j], acc[i][j], 0, 0, 0);
    }
    __builtin_amdgcn_s_barrier();   // all reads of cur done -> next STAGE may overwrite it
    cur ^= 1;
  }

  // ---- epilogue: stage f32 tile in LDS, write coalesced ----
  float* ct = (float*)smem;   // [128][132]
  #pragma unroll
  for (int i = 0; i < 4; i++)
    #pragma unroll
    for (int j = 0; j < 4; j++)
      #pragma unroll
      for (int r4 = 0; r4 < 4; r4++)
        ct[(wr + i * 16 + fq * 4 + r4) * 132 + wc + j * 16 + fr] = acc[i][j][r4];
  __syncthreads();
  const int half = lane >> 5;
  const int col4 = (lane & 31) * 4;
  const int cn = n0 + col4;
  #pragma unroll
  for (int it = 0; it < 16; it++) {
    int row = wave * 32 + it * 2 + half;
    f32x4 v = *(const f32x4*)&ct[row * 132 + col4];
    if (cn < N) {
      if (EPI >= 1) {
        f32x4 b4 = *(const f32x4*)&bias[cn];
        #pragma unroll
        for (int j = 0; j < 4; j++) v[j] += b4[j];
      }
      if (OUTBF) {
        unsigned short h0 = (unsigned short)f2bf(v[0]), h1 = (unsigned short)f2bf(v[1]);
        unsigned short h2 = (unsigned short)f2bf(v[2]), h3 = (unsigned short)f2bf(v[3]);
        uint2v o = { (unsigned)h0 | ((unsigned)h1 << 16), (unsigned)h2 | ((unsigned)h3 << 16) };
        *(uint2v*)((unsigned short*)Cv + (size_t)(m0 + row) * ldc + cn) = o;
      } else {
        float* dst = (float*)Cv + (size_t)(m0 + row) * ldc + cn;
        if (EPI == 1) __builtin_nontemporal_store(v, (f32x4*)dst);  // final logits: stream past L2
        else          *(f32x4*)dst = v;
      }
    }
  }
}

// =================== f32-input GEMM (mel K=80) ===================
#define LDT 40
template<int EPI, int OUTBF>
__launch_bounds__(256)
__global__ void gemm_f32in(const float* __restrict__ A, const float* __restrict__ B,
                           void* __restrict__ Cv, const float* __restrict__ bias,
                           int M, int N, int K, int lda, int ldb, int ldc) {
  __shared__ short As[128 * LDT];
  __shared__ short Bs[128 * LDT];
  const int tid  = threadIdx.x;
  const int lane = tid & 63;
  const int wave = tid >> 6;
  const int m0 = blockIdx.y * 128;
  const int n0 = blockIdx.x * 128;
  const int wr = (wave >> 1) * 64;
  const int wc = (wave & 1) * 64;
  const int srow = tid >> 3;
  const int scol = (tid & 7) * 4;
  const int fr = lane & 15;
  const int fq = lane >> 4;

  f32x4 acc[4][4] = {};

  for (int k0 = 0; k0 < K; k0 += 32) {
    const bool kok = (k0 + scol) < K;
    #pragma unroll
    for (int rr = 0; rr < 128; rr += 32) {
      int r = srow + rr;
      f32x4 v = {0.f, 0.f, 0.f, 0.f};
      if (kok) v = *(const f32x4*)(A + (size_t)(m0 + r) * lda + k0 + scol);
      short4v s = { f2bf(v[0]), f2bf(v[1]), f2bf(v[2]), f2bf(v[3]) };
      *(short4v*)(&As[r * LDT + scol]) = s;
    }
    #pragma unroll
    for (int rr = 0; rr < 128; rr += 32) {
      int r = srow + rr;
      f32x4 v = {0.f, 0.f, 0.f, 0.f};
      if (kok && (n0 + r) < N) v = *(const f32x4*)(B + (size_t)(n0 + r) * ldb + k0 + scol);
      short4v s = { f2bf(v[0]), f2bf(v[1]), f2bf(v[2]), f2bf(v[3]) };
      *(short4v*)(&Bs[r * LDT + scol]) = s;
    }
    __syncthreads();
    bf16x8s af[4], bfv[4];
    #pragma unroll
    for (int i = 0; i < 4; i++)
      af[i]  = *(const bf16x8s*)(&As[(wr + i * 16 + fr) * LDT + fq * 8]);
    #pragma unroll
    for (int i = 0; i < 4; i++)
      bfv[i] = *(const bf16x8s*)(&Bs[(wc + i * 16 + fr) * LDT + fq * 8]);
    #pragma unroll
    for (int i = 0; i < 4; i++)
      #pragma unroll
      for (int j = 0; j < 4; j++)
        acc[i][j] = __builtin_amdgcn_mfma_f32_16x16x32_bf16(af[i], bfv[j], acc[i][j], 0, 0, 0);
    __syncthreads();
  }

  #pragma unroll
  for (int j = 0; j < 4; j++) {
    int cn = n0 + wc + j * 16 + fr;
    if (cn < N) {
      float bv = 0.f;
      if (EPI >= 1) bv = bias[cn];
      #pragma unroll
      for (int i = 0; i < 4; i++) {
        #pragma unroll
        for (int r4 = 0; r4 < 4; r4++) {
          int cm = m0 + wr + i * 16 + fq * 4 + r4;
          float val = acc[i][j][r4] + bv;
          if (OUTBF) ((unsigned short*)Cv)[(size_t)cm * ldc + cn] = (unsigned short)f2bf(val);
          else       ((float*)Cv)[(size_t)cm * ldc + cn] = val;
        }
      }
    }
  }
}

// =================== weight f32 -> bf16 conversion (12 tensors, one launch) ===================
struct CvtArgs { const float* s[12]; unsigned short* d[12]; int n[12]; };
__global__ void cvt_many(CvtArgs a) {
  int y = blockIdx.y;
  int i = (blockIdx.x * 256 + threadIdx.x) * 8;
  if (i >= a.n[y]) return;
  const float* s = a.s[y];
  f32x4 v0 = *(const f32x4*)(s + i);
  f32x4 v1 = *(const f32x4*)(s + i + 4);
  ushort8 o = { (unsigned short)f2bf(v0[0]), (unsigned short)f2bf(v0[1]),
                (unsigned short)f2bf(v0[2]), (unsigned short)f2bf(v0[3]),
                (unsigned short)f2bf(v1[0]), (unsigned short)f2bf(v1[1]),
                (unsigned short)f2bf(v1[2]), (unsigned short)f2bf(v1[3]) };
  *(ushort8*)(a.d[y] + i) = o;
}

// =================== tiny attention (L=2) over bf16 qkv ===================
__global__ void attn_kernel(const unsigned short* __restrict__ qkv, unsigned short* __restrict__ o) {
  int gw = blockIdx.x * 4 + (threadIdx.x >> 6);
  int lane = threadIdx.x & 63;
  int n = gw >> 3, h = gw & 7;
  size_t r0 = (size_t)n * 1536 + h * 64 + lane;
  size_t r1 = (size_t)(SEQ + n) * 1536 + h * 64 + lane;
  float q0 = bf2f(qkv[r0]), k0 = bf2f(qkv[r0 + 512]), v0 = bf2f(qkv[r0 + 1024]);
  float q1 = bf2f(qkv[r1]), k1 = bf2f(qkv[r1 + 512]), v1 = bf2f(qkv[r1 + 1024]);
  float s00 = q0 * k0, s01 = q0 * k1, s10 = q1 * k0, s11 = q1 * k1;
  #pragma unroll
  for (int off = 32; off > 0; off >>= 1) {
    s00 += __shfl_xor(s00, off);
    s01 += __shfl_xor(s01, off);
    s10 += __shfl_xor(s10, off);
    s11 += __shfl_xor(s11, off);
  }
  const float sc = 0.125f;
  s00 *= sc; s01 *= sc; s10 *= sc; s11 *= sc;
  float mx0 = fmaxf(s00, s01), mx1 = fmaxf(s10, s11);
  float e00 = __expf(s00 - mx0), e01 = __expf(s01 - mx0);
  float e10 = __expf(s10 - mx1), e11 = __expf(s11 - mx1);
  float i0 = 1.f / (e00 + e01), i1 = 1.f / (e10 + e11);
  size_t w0 = (size_t)n * 512 + h * 64 + lane;
  size_t w1 = (size_t)(SEQ + n) * 512 + h * 64 + lane;
  o[w0] = (unsigned short)f2bf((e00 * v0 + e01 * v1) * i0);
  o[w1] = (unsigned short)f2bf((e10 * v0 + e11 * v1) * i1);
}

// =================== LN(a+b) over 512, bf16 in/out; DUAL: also write time-flipped copy ===================
template<int DUAL>
__global__ void ln_res_kernel(const unsigned short* __restrict__ a, const unsigned short* __restrict__ b,
                              const float* __restrict__ g, const float* __restrict__ be,
                              unsigned short* __restrict__ out, unsigned short* __restrict__ out2) {
  int row = blockIdx.x * 4 + (threadIdx.x >> 6);
  int lane = threadIdx.x & 63;
  ushort8 va = *(const ushort8*)(a + (size_t)row * 512 + lane * 8);
  ushort8 vb = *(const ushort8*)(b + (size_t)row * 512 + lane * 8);
  float v[8];
  #pragma unroll
  for (int j = 0; j < 8; j++) v[j] = bf2f(va[j]) + bf2f(vb[j]);
  float s = 0.f, s2 = 0.f;
  #pragma unroll
  for (int j = 0; j < 8; j++) { s += v[j]; s2 += v[j] * v[j]; }
  #pragma unroll
  for (int off = 32; off > 0; off >>= 1) { s += __shfl_xor(s, off); s2 += __shfl_xor(s2, off); }
  float mu = s * (1.f / 512.f);
  float var = s2 * (1.f / 512.f) - mu * mu;
  float rs = rsqrtf(var + 1e-5f);
  const float* pg = g + lane * 8;
  const float* pe = be + lane * 8;
  ushort8 o;
  #pragma unroll
  for (int j = 0; j < 8; j++) o[j] = (unsigned short)f2bf((v[j] - mu) * rs * pg[j] + pe[j]);
  *(ushort8*)(out + (size_t)row * 512 + lane * 8) = o;
  if (DUAL) {
    int t = row & (SEQ - 1), bb = row >> 11;
    int frow = (bb << 11) | (SEQ - 1 - t);
    *(ushort8*)(out2 + (size_t)frow * 512 + lane * 8) = o;
  }
}

// =================== depthwise causal conv(K=4)+silu, dual-direction ===================
struct ConvArgs {
  const unsigned short* xz[2];
  const float* w[2];
  const float* cb[2];
  unsigned short* xc[2];
};
__global__ void conv_silu_kernel(ConvArgs a) {
  int dir = blockIdx.y;
  int idx = blockIdx.x * 256 + threadIdx.x;     // over B*S*(DI/8) = 524288
  int dc = (idx & 127) * 8;
  int t  = (idx >> 7) & (SEQ - 1);
  int b  = idx >> 18;
  const float* w = a.w[dir];
  f32x4 wv[8];
  #pragma unroll
  for (int j = 0; j < 8; j++) wv[j] = *(const f32x4*)(w + (dc + j) * 4);
  float acc[8];
  f32x4 cb0 = *(const f32x4*)(a.cb[dir] + dc), cb1 = *(const f32x4*)(a.cb[dir] + dc + 4);
  #pragma unroll
  for (int j = 0; j < 4; j++) { acc[j] = cb0[j]; acc[4 + j] = cb1[j]; }
  const unsigned short* base = a.xz[dir] + ((size_t)b * SEQ) * 2048 + dc;
  #pragma unroll
  for (int k = 0; k < 4; k++) {
    int tt = t - 3 + k;
    if (tt >= 0) {
      ushort8 xv = *(const ushort8*)(base + (size_t)tt * 2048);
      #pragma unroll
      for (int j = 0; j < 8; j++) acc[j] += wv[j][k] * bf2f(xv[j]);
    }
  }
  ushort8 o;
  #pragma unroll
  for (int j = 0; j < 8; j++) {
    float v = acc[j];
    o[j] = (unsigned short)f2bf(v / (1.f + __expf(-v)));
  }
  *(ushort8*)(a.xc[dir] + (size_t)idx * 8) = o;
}

// =================== chunked selective scan, dual-direction (dt inlined, gate+flip fused) ===================
#define CL 32
#define NC 64

struct ScanArgs {
  const unsigned short* xc[2];
  const float* dbl[2];
  const float* A_log[2];
  const float* dt_w[2];
  const float* dt_b[2];
  const float* Dp[2];
  const unsigned short* xz[2];
  float* hend[2];
  float* apr[2];
  float* h0[2];
  unsigned short* ys[2];
};

__device__ __forceinline__ float dt_inline(const float* __restrict__ dr,
                                           const float* __restrict__ dtw, float db) {
  float acc = db;
  #pragma unroll
  for (int q = 0; q < 8; q++) {
    f32x4 v = *(const f32x4*)(dr + q * 4);
    acc += v[0] * dtw[q * 4] + v[1] * dtw[q * 4 + 1] + v[2] * dtw[q * 4 + 2] + v[3] * dtw[q * 4 + 3];
  }
  // softplus
  return fmaxf(acc, 0.f) + log1pf(__expf(-fabsf(acc)));
}

__global__ void scan_p1(ScanArgs s) {
  int dir = blockIdx.y;
  int tid = blockIdx.x * 256 + threadIdx.x;   // B*NC*DI = 131072
  int d = tid & 1023;
  int c = (tid >> 10) & (NC - 1);
  int b = tid >> 16;
  float A[16];
  #pragma unroll
  for (int q = 0; q < 4; q++) {
    f32x4 v = *(const f32x4*)(s.A_log[dir] + d * 16 + q * 4);
    #pragma unroll
    for (int j = 0; j < 4; j++) A[q * 4 + j] = -__expf(v[j]);
  }
  float dtw[32];
  #pragma unroll
  for (int q = 0; q < 8; q++) {
    f32x4 v = *(const f32x4*)(s.dt_w[dir] + d * 32 + q * 4);
    #pragma unroll
    for (int j = 0; j < 4; j++) dtw[q * 4 + j] = v[j];
  }
  const float db = s.dt_b[dir][d];
  float h[16] = {};
  float ap[16];
  #pragma unroll
  for (int n = 0; n < 16; n++) ap[n] = 1.f;
  const unsigned short* xcp = s.xc[dir] + ((size_t)b * SEQ) * 1024 + d;
  const float* dbp = s.dbl[dir] + ((size_t)b * SEQ) * 64;
  const int t0 = c * CL;
  for (int t = t0; t < t0 + CL; t++) {
    const float* dr = dbp + (size_t)t * 64;
    float dtv = dt_inline(dr, dtw, db);
    float dx = dtv * bf2f(xcp[(size_t)t * 1024]);
    float Bv[16];
    #pragma unroll
    for (int q = 0; q < 4; q++) {
      f32x4 v = *(const f32x4*)(dr + 32 + q * 4);
      #pragma unroll
      for (int j = 0; j < 4; j++) Bv[q * 4 + j] = v[j];
    }
    #pragma unroll
    for (int n = 0; n < 16; n++) {
      float e = __expf(dtv * A[n]);
      h[n] = e * h[n] + dx * Bv[n];
      ap[n] *= e;
    }
  }
  size_t o = ((size_t)((b * NC + c) * 1024 + d)) * 16;
  #pragma unroll
  for (int q = 0; q < 4; q++) {
    f32x4 vh = { h[q * 4], h[q * 4 + 1], h[q * 4 + 2], h[q * 4 + 3] };
    f32x4 va = { ap[q * 4], ap[q * 4 + 1], ap[q * 4 + 2], ap[q * 4 + 3] };
    *(f32x4*)(s.hend[dir] + o + q * 4) = vh;
    *(f32x4*)(s.apr[dir] + o + q * 4) = va;
  }
}

__global__ void scan_p2(ScanArgs s) {
  int dir = blockIdx.y;
  int tid = blockIdx.x * 256 + threadIdx.x;   // B*DI*N = 32768
  int n = tid & 15;
  int d = (tid >> 4) & 1023;
  int b = tid >> 14;
  const float* hend = s.hend[dir];
  const float* apr  = s.apr[dir];
  float* h0 = s.h0[dir];
  float h = 0.f;
  for (int c = 0; c < NC; c++) {
    size_t idx = ((size_t)((b * NC + c) * 1024 + d)) * 16 + n;
    h0[idx] = h;
    h = apr[idx] * h + hend[idx];
  }
}

// p3: recompute with h0, emit gated output, write (dir-1 time-flipped)
__global__ void scan_p3(ScanArgs s) {
  int dir = blockIdx.y;
  int tid = blockIdx.x * 256 + threadIdx.x;   // B*NC*DI = 131072
  int d = tid & 1023;
  int c = (tid >> 10) & (NC - 1);
  int b = tid >> 16;
  float A[16];
  #pragma unroll
  for (int q = 0; q < 4; q++) {
    f32x4 v = *(const f32x4*)(s.A_log[dir] + d * 16 + q * 4);
    #pragma unroll
    for (int j = 0; j < 4; j++) A[q * 4 + j] = -__expf(v[j]);
  }
  float dtw[32];
  #pragma unroll
  for (int q = 0; q < 8; q++) {
    f32x4 v = *(const f32x4*)(s.dt_w[dir] + d * 32 + q * 4);
    #pragma unroll
    for (int j = 0; j < 4; j++) dtw[q * 4 + j] = v[j];
  }
  const float db = s.dt_b[dir][d];
  const float Dv = s.Dp[dir][d];
  float h[16];
  size_t o = ((size_t)((b * NC + c) * 1024 + d)) * 16;
  #pragma unroll
  for (int q = 0; q < 4; q++) {
    f32x4 v = *(const f32x4*)(s.h0[dir] + o + q * 4);
    #pragma unroll
    for (int j = 0; j < 4; j++) h[q * 4 + j] = v[j];
  }
  const unsigned short* xcp = s.xc[dir] + ((size_t)b * SEQ) * 1024 + d;
  const unsigned short* zp  = s.xz[dir] + ((size_t)b * SEQ) * 2048 + 1024 + d;
  const float* dbp = s.dbl[dir] + ((size_t)b * SEQ) * 64;
  unsigned short* ysp = s.ys[dir] + ((size_t)b * SEQ) * 1024 + d;
  const int t0 = c * CL;
  for (int t = t0; t < t0 + CL; t++) {
    const float* dr = dbp + (size_t)t * 64;
    float dtv = dt_inline(dr, dtw, db);
    float xcv = bf2f(xcp[(size_t)t * 1024]);
    float dx = dtv * xcv;
    float Bv[16], Cv[16];
    #pragma unroll
    for (int q = 0; q < 4; q++) {
      f32x4 v = *(const f32x4*)(dr + 32 + q * 4);
      f32x4 w = *(const f32x4*)(dr + 48 + q * 4);
      #pragma unroll
      for (int j = 0; j < 4; j++) { Bv[q * 4 + j] = v[j]; Cv[q * 4 + j] = w[j]; }
    }
    float y = 0.f;
    #pragma unroll
    for (int n = 0; n < 16; n++) {
      float e = __expf(dtv * A[n]);
      h[n] = e * h[n] + dx * Bv[n];
      y += h[n] * Cv[n];
    }
    // gate: (y + xc*D) * silu(z)
    float z = bf2f(zp[(size_t)t * 2048]);
    float out = (y + xcv * Dv) * (z / (1.f + __expf(-z)));
    int tw = dir ? (SEQ - 1 - t) : t;
    ysp[(size_t)tw * 1024] = (unsigned short)f2bf(out);
  }
}

extern "C" void kernel_launch(void* const* d_in, const int* in_sizes, int n_in,
                              void* d_out, int out_size, void* d_ws, size_t ws_size,
                              hipStream_t stream) {
  (void)in_sizes; (void)n_in; (void)out_size; (void)ws_size;
  const float* mel        = (const float*)d_in[0];
  const float* mel_w      = (const float*)d_in[1];
  const float* mel_b      = (const float*)d_in[2];
  const float* attn_in_b  = (const float*)d_in[4];
  const float* attn_out_b = (const float*)d_in[6];
  const float* ln1_g = (const float*)d_in[7];
  const float* ln1_b = (const float*)d_in[8];
  const float* ln2_g = (const float*)d_in[9];
  const float* ln2_b = (const float*)d_in[10];
  const float* bim_b = (const float*)d_in[30];
  const float* out_b = (const float*)d_in[32];

  char* wsb = (char*)d_ws;
  char* obb = (char*)d_out;

  // ---- bf16 weights in ws (byte offsets) ----
  unsigned short* w_attn_in  = (unsigned short*)(wsb + 0);          // 786432
  unsigned short* w_attn_out = (unsigned short*)(wsb + 1572864);    // 262144
  unsigned short* w_dir[2][4];
  for (int dir = 0; dir < 2; dir++) {
    size_t base = 2097152 + (size_t)dir * 3342336;
    w_dir[dir][0] = (unsigned short*)(wsb + base);                  // in_w
    w_dir[dir][1] = (unsigned short*)(wsb + base + 2097152);        // x_w
    w_dir[dir][2] = (unsigned short*)(wsb + base + 2228224);        // (spare)
    w_dir[dir][3] = (unsigned short*)(wsb + base + 2293760);        // out_w
  }
  unsigned short* w_bim = (unsigned short*)(wsb + 8781824);         // 524288
  unsigned short* w_out = (unsigned short*)(wsb + 9830400);         // 5120000

  // ---- bf16 activations in ws ----
  unsigned short* x0     = (unsigned short*)(wsb + 20971520);
  unsigned short* x1     = (unsigned short*)(wsb + 25165824);
  unsigned short* x1f    = (unsigned short*)(wsb + 29360128);
  unsigned short* attn_o = (unsigned short*)(wsb + 33554432);
  unsigned short* xc0    = (unsigned short*)(wsb + 37748736);  // 8.39MB
  unsigned short* ysb0   = (unsigned short*)(wsb + 46137344);  // 8.39MB
  unsigned short* mout   = (unsigned short*)(wsb + 62914560);  // 8.39MB
  unsigned short* minter = (unsigned short*)(wsb + 71303168);
  unsigned short* x2     = (unsigned short*)(wsb + 75497472);
  float*          dbl0   = (float*)(wsb + 79691776);           // 1.05MB

  // ---- d_out scratch (dead until final GEMM overwrites all; 163.84MB) ----
  unsigned short* qkv  = (unsigned short*)(obb + 0);           // 12.58MB
  unsigned short* xz0  = (unsigned short*)(obb + 12582912);    // 16.78MB
  unsigned short* xz1  = (unsigned short*)(obb + 29360128);    // 16.78MB
  unsigned short* xc1  = (unsigned short*)(obb + 46137344);    // 8.39MB
  unsigned short* ysb1 = (unsigned short*)(obb + 54525952);    // 8.39MB
  float* hend0 = (float*)(obb + 62914560);                     // 8.39MB
  float* hend1 = (float*)(obb + 71303168);
  float* apr0  = (float*)(obb + 79691776);
  float* apr1  = (float*)(obb + 88080384);
  float* h0s0  = (float*)(obb + 96468992);
  float* h0s1  = (float*)(obb + 104857600);
  float* dbl1  = (float*)(obb + 113246208);                    // 1.05MB -> ends 114.3MB
  float* ob    = (float*)d_out;

  dim3 blk(256);

  // 0. convert weights to bf16
  {
    CvtArgs a;
    const float* srcs[12] = { (const float*)d_in[3], (const float*)d_in[5],
      (const float*)d_in[11], (const float*)d_in[14], (const float*)d_in[15], (const float*)d_in[19],
      (const float*)d_in[20], (const float*)d_in[23], (const float*)d_in[24], (const float*)d_in[28],
      (const float*)d_in[29], (const float*)d_in[31] };
    unsigned short* dsts[12] = { w_attn_in, w_attn_out,
      w_dir[0][0], w_dir[0][1], w_dir[0][2], w_dir[0][3],
      w_dir[1][0], w_dir[1][1], w_dir[1][2], w_dir[1][3],
      w_bim, w_out };
    int ns[12] = { 786432, 262144, 1048576, 65536, 32768, 524288,
                   1048576, 65536, 32768, 524288, 524288, 5120000 };
    for (int i = 0; i < 12; i++) { a.s[i] = srcs[i]; a.d[i] = dsts[i]; a.n[i] = ns[i]; }
    cvt_many<<<dim3(2500, 12), blk, 0, stream>>>(a);
  }

  // 1. x0 = mel @ mel_w.T + mel_b (f32-in path, K=80)
  gemm_f32in<1, 1><<<dim3(4, 32), blk, 0, stream>>>(mel, mel_w, x0, mel_b, 4096, 512, 80, 80, 80, 512);
  // 2. qkv = x0 @ attn_in_w.T + b
  gemm_bf16<1, 1><<<dim3(12 * 32), blk, 0, stream>>>(x0, w_attn_in, qkv, attn_in_b,
      4096, 1536, 512, 512, 512, 1536, 12, nullptr, nullptr, nullptr);
  // 3. attention
  attn_kernel<<<4096, blk, 0, stream>>>(qkv, attn_o);
  // 4. attnproj -> qkv slot
  gemm_bf16<1, 1><<<dim3(4 * 32), blk, 0, stream>>>(attn_o, w_attn_out, qkv, attn_out_b,
      4096, 512, 512, 512, 512, 512, 4, nullptr, nullptr, nullptr);
  // 5. x1 = LN(x0 + attnproj); x1f = flip(x1) fused
  ln_res_kernel<1><<<1024, blk, 0, stream>>>(x0, qkv, ln1_g, ln1_b, x1, x1f);

  // ---- dual-direction mamba pipeline (blockIdx.y = dir) ----
  ScanArgs sa;
  ConvArgs ca;
  for (int dir = 0; dir < 2; dir++) {
    int base = 11 + dir * 9;
    ca.xz[dir] = dir ? xz1 : xz0;
    ca.w[dir]  = (const float*)d_in[base + 1];
    ca.cb[dir] = (const float*)d_in[base + 2];
    ca.xc[dir] = dir ? xc1 : xc0;
    sa.xc[dir]    = dir ? xc1 : xc0;
    sa.dbl[dir]   = dir ? dbl1 : dbl0;
    sa.A_log[dir] = (const float*)d_in[base + 6];
    sa.dt_w[dir]  = (const float*)d_in[base + 4];
    sa.dt_b[dir]  = (const float*)d_in[base + 5];
    sa.Dp[dir]    = (const float*)d_in[base + 7];
    sa.xz[dir]    = dir ? xz1 : xz0;
    sa.hend[dir]  = dir ? hend1 : hend0;
    sa.apr[dir]   = dir ? apr1 : apr0;
    sa.h0[dir]    = dir ? h0s1 : h0s0;
    sa.ys[dir]    = dir ? ysb1 : ysb0;
  }
  // xz = xin @ in_w.T  (dual)
  gemm_bf16<0, 1><<<dim3(16 * 32, 2), blk, 0, stream>>>(x1, w_dir[0][0], xz0, nullptr,
      4096, 2048, 512, 512, 512, 2048, 16, x1f, w_dir[1][0], xz1);
  // conv + silu (dual)
  conv_silu_kernel<<<dim3(2048, 2), blk, 0, stream>>>(ca);
  // dbl = xc @ x_w.T (dual, f32 out for scan numerics)
  gemm_bf16<0, 0><<<dim3(1 * 32, 2), blk, 0, stream>>>(xc0, w_dir[0][1], dbl0, nullptr,
      4096, 64, 1024, 1024, 1024, 64, 1, xc1, w_dir[1][1], dbl1);
  // selective scan (dual; dt inlined; gate + output-flip fused into p3)
  scan_p1<<<dim3(512, 2), blk, 0, stream>>>(sa);
  scan_p2<<<dim3(128, 2), blk, 0, stream>>>(sa);
  scan_p3<<<dim3(512, 2), blk, 0, stream>>>(sa);
  // mamba out proj (dual) -> mout cols [dir*512, +512)
  gemm_bf16<0, 1><<<dim3(4 * 32, 2), blk, 0, stream>>>(ysb0, w_dir[0][3], mout, nullptr,
      4096, 512, 1024, 1024, 1024, 1024, 4, ysb1, w_dir[1][3], mout + 512);

  // m = mout @ bim_w.T + bim_b
  gemm_bf16<1, 1><<<dim3(4 * 32), blk, 0, stream>>>(mout, w_bim, minter, bim_b,
      4096, 512, 1024, 1024, 1024, 512, 4, nullptr, nullptr, nullptr);
  // x2 = LN(x1 + m)
  ln_res_kernel<0><<<1024, blk, 0, stream>>>(x1, minter, ln2_g, ln2_b, x2, nullptr);
  // logits = x2 @ out_w.T + out_b  (overwrites all of d_out; nontemporal f32 stores)
  gemm_bf16<1, 0><<<dim3(79 * 32), blk, 0, stream>>>(x2, w_out, ob, out_b,
      4096, 10000, 512, 512, 512, 10000, 79, nullptr, nullptr, nullptr);
}